// Round 12
// baseline (436.851 us; speedup 1.0000x reference)
//
#include <hip/hip_runtime.h>
#include <hip/hip_bf16.h>
#include <stdint.h>

typedef __attribute__((ext_vector_type(8))) short short8;
typedef __attribute__((ext_vector_type(4))) float f32x4;
typedef __attribute__((ext_vector_type(16))) float f32x16;

constexpr int kDim   = 1536;
constexpr int kHeads = 12;
constexpr int kHd    = 128;
constexpr int kS     = 3072;
constexpr int kB     = 2;
constexpr int kQKV   = 3 * kDim;               // 4608 fused row width
constexpr int kSplit = 3;                      // split-K factor for attention
constexpr int kKeys  = kS / kSplit;            // 1024 keys per split
constexpr float kEps   = 1e-6f;
constexpr float kQMul  = 0.08838834764831845f * 1.44269504089f; // 1/sqrt(128)*log2(e)

__device__ __forceinline__ ushort f2bf(float f) {
    union { float f; uint32_t u; } c; c.f = f;
    uint32_t u = c.u;
    return (ushort)((u + 0x7fffu + ((u >> 16) & 1u)) >> 16);
}
__device__ __forceinline__ float bf2f(uint32_t h) {
    union { uint32_t u; float f; } c; c.u = h << 16;
    return c.f;
}
__device__ __forceinline__ void gload_lds16(const void* g, void* l) {
    __builtin_amdgcn_global_load_lds((const __attribute__((address_space(1))) void*)g,
                                     (__attribute__((address_space(3))) void*)l, 16, 0, 0);
}
__device__ __forceinline__ uint32_t cvtpk_bf16(float lo, float hi) {
    uint32_t r;
    asm("v_cvt_pk_bf16_f32 %0, %1, %2" : "=v"(r) : "v"(lo), "v"(hi));
    return r;
}

// ---------------------------------------------------------------------------
// fp32 -> bf16 convert, 8 elems/thread
// ---------------------------------------------------------------------------
__global__ __launch_bounds__(256)
void cvt_kernel(const float* __restrict__ in, ushort* __restrict__ out, int n8)
{
    int i = blockIdx.x * 256 + threadIdx.x;
    if (i >= n8) return;
    const float4* p = (const float4*)in + (size_t)i * 2;
    float4 a = p[0], b = p[1];
    uint4 r;
    r.x = (uint32_t)f2bf(a.x) | ((uint32_t)f2bf(a.y) << 16);
    r.y = (uint32_t)f2bf(a.z) | ((uint32_t)f2bf(a.w) << 16);
    r.z = (uint32_t)f2bf(b.x) | ((uint32_t)f2bf(b.y) << 16);
    r.w = (uint32_t)f2bf(b.z) | ((uint32_t)f2bf(b.w) << 16);
    ((uint4*)out)[i] = r;
}

// 4 weight tensors in one dispatch (blockIdx.y selects)
__global__ __launch_bounds__(256)
void cvt4_kernel(const float* __restrict__ s0, const float* __restrict__ s1,
                 const float* __restrict__ s2, const float* __restrict__ s3,
                 ushort* __restrict__ d0, ushort* __restrict__ d1,
                 ushort* __restrict__ d2, ushort* __restrict__ d3, int n8)
{
    int i = blockIdx.x * 256 + threadIdx.x;
    if (i >= n8) return;
    const float* in; ushort* out;
    switch (blockIdx.y) {
        case 0: in = s0; out = d0; break;
        case 1: in = s1; out = d1; break;
        case 2: in = s2; out = d2; break;
        default: in = s3; out = d3; break;
    }
    const float4* p = (const float4*)in + (size_t)i * 2;
    float4 a = p[0], b = p[1];
    uint4 r;
    r.x = (uint32_t)f2bf(a.x) | ((uint32_t)f2bf(a.y) << 16);
    r.y = (uint32_t)f2bf(a.z) | ((uint32_t)f2bf(a.w) << 16);
    r.z = (uint32_t)f2bf(b.x) | ((uint32_t)f2bf(b.y) << 16);
    r.w = (uint32_t)f2bf(b.z) | ((uint32_t)f2bf(b.w) << 16);
    ((uint4*)out)[i] = r;
}

// concat bq|bk|bv -> biasqkv[4608]
__global__ __launch_bounds__(256)
void biascat_kernel(const float* __restrict__ bq, const float* __restrict__ bk,
                    const float* __restrict__ bv, float* __restrict__ out)
{
    int i = blockIdx.x * 256 + threadIdx.x;
    if (i >= kQKV) return;
    float v = (i < kDim) ? bq[i] : (i < 2*kDim) ? bk[i - kDim] : bv[i - 2*kDim];
    out[i] = v;
}

// ---------------------------------------------------------------------------
// bf16 MFMA GEMM: C[M][N] = A[M][K] @ B[N][K]^T + bias   (m97-style 128^2, BK=32)
// ---------------------------------------------------------------------------
template<typename OutT>
__global__ __launch_bounds__(256)
void gemm_bf16(const ushort* __restrict__ A, const ushort* __restrict__ B,
               const float* __restrict__ bias, OutT* __restrict__ C,
               int M, int N, int K)
{
    __shared__ ushort As[128 * 32];
    __shared__ ushort Bs[128 * 32];
    const int t    = threadIdx.x;
    const int lane = t & 63;
    const int w    = t >> 6;
    const int wm = (w >> 1) * 64, wn = (w & 1) * 64;
    const int m0 = blockIdx.y * 128, n0 = blockIdx.x * 128;

    const int srow = t >> 2;
    const int skc  = (t & 3) * 8;
    const ushort* Ag = A + (size_t)(m0 + srow) * K + skc;
    const ushort* Bg = B + (size_t)(n0 + srow) * K + skc;
    const size_t half = (size_t)64 * K;

    f32x4 acc[4][4];
    #pragma unroll
    for (int m = 0; m < 4; ++m)
        #pragma unroll
        for (int n = 0; n < 4; ++n)
            #pragma unroll
            for (int i = 0; i < 4; ++i) acc[m][n][i] = 0.f;

    const int kk  = (lane >> 4) * 8;
    const int l15 = lane & 15;

    for (int k0 = 0; k0 < K; k0 += 32) {
        __syncthreads();
        gload_lds16(Ag + k0,        &As[t * 8]);
        gload_lds16(Ag + half + k0, &As[t * 8 + 2048]);
        gload_lds16(Bg + k0,        &Bs[t * 8]);
        gload_lds16(Bg + half + k0, &Bs[t * 8 + 2048]);
        __syncthreads();
        short8 af[4], bf[4];
        #pragma unroll
        for (int m = 0; m < 4; ++m) af[m] = *(const short8*)&As[(wm + m*16 + l15) * 32 + kk];
        #pragma unroll
        for (int n = 0; n < 4; ++n) bf[n] = *(const short8*)&Bs[(wn + n*16 + l15) * 32 + kk];
        #pragma unroll
        for (int m = 0; m < 4; ++m)
            #pragma unroll
            for (int n = 0; n < 4; ++n)
                acc[m][n] = __builtin_amdgcn_mfma_f32_16x16x32_bf16(af[m], bf[n], acc[m][n], 0, 0, 0);
    }

    const int r0 = (lane >> 4) * 4;
    #pragma unroll
    for (int m = 0; m < 4; ++m) {
        #pragma unroll
        for (int r = 0; r < 4; ++r) {
            const size_t row = (size_t)(m0 + wm + m*16 + r0 + r);
            #pragma unroll
            for (int n = 0; n < 4; ++n) {
                const int col = n0 + wn + n*16 + l15;
                float val = acc[m][n][r] + bias[col];
                if constexpr (sizeof(OutT) == 4) C[row * N + col] = val;
                else                             C[row * N + col] = f2bf(val);
            }
        }
    }
}

// ---------------------------------------------------------------------------
// V transpose from fused qkv: vt[b][h][d][s] = qkv[b][s][3072 + h*128 + d]
// ---------------------------------------------------------------------------
__global__ __launch_bounds__(256)
void vtrans_kernel(const ushort* __restrict__ qkv, ushort* __restrict__ vt)
{
    __shared__ ushort Ts[64][72];
    const int t  = threadIdx.x;
    const int s0 = blockIdx.x * 64;
    const int d0 = blockIdx.y * 64;
    const int bh = blockIdx.z;
    const int b = bh / kHeads, h = bh % kHeads;

    const int r = t >> 2, cc = (t & 3) * 16;
    const ushort* src = qkv + ((size_t)(b * kS) + s0 + r) * kQKV + 2*kDim + h * kHd + d0 + cc;
    uint4 a0 = *(const uint4*)src;
    uint4 a1 = *(const uint4*)(src + 8);
    *(uint4*)&Ts[r][cc]     = a0;
    *(uint4*)&Ts[r][cc + 8] = a1;
    __syncthreads();
    ushort tmp[16];
    #pragma unroll
    for (int j = 0; j < 16; ++j) tmp[j] = Ts[cc + j][r];
    ushort* dst = vt + ((size_t)(bh * kHd) + d0 + r) * kS + s0 + cc;
    *(uint4*)dst       = *(uint4*)&tmp[0];
    *(uint4*)(dst + 8) = *(uint4*)&tmp[8];
}

// ---------------------------------------------------------------------------
// RMSNorm + RoPE on q/k sections of fused qkv. 192 thr, 8 elems each.
// ---------------------------------------------------------------------------
__global__ __launch_bounds__(192)
void rmsrope_kernel(ushort* __restrict__ qkv,
                    const float* __restrict__ gq, const float* __restrict__ gk,
                    const float* __restrict__ freqs, const int* __restrict__ grid_sizes)
{
    __shared__ float red[4];
    const int row   = blockIdx.x;
    const int which = blockIdx.y;
    ushort* ptr = qkv + (size_t)row * kQKV + which * kDim;
    const float* g = which ? gk : gq;
    const float outmul = which ? 1.0f : kQMul;
    const int t = threadIdx.x;

    uint4 raw = ((const uint4*)ptr)[t];
    float v[8];
    v[0] = bf2f(raw.x & 0xffff); v[1] = bf2f(raw.x >> 16);
    v[2] = bf2f(raw.y & 0xffff); v[3] = bf2f(raw.y >> 16);
    v[4] = bf2f(raw.z & 0xffff); v[5] = bf2f(raw.z >> 16);
    v[6] = bf2f(raw.w & 0xffff); v[7] = bf2f(raw.w >> 16);

    float ss = 0.f;
    #pragma unroll
    for (int i = 0; i < 8; ++i) ss += v[i] * v[i];
    #pragma unroll
    for (int off = 32; off >= 1; off >>= 1) ss += __shfl_xor(ss, off);
    if ((t & 63) == 0) red[t >> 6] = ss;
    __syncthreads();
    const float scale = rsqrtf((red[0] + red[1] + red[2]) * (1.f / kDim) + kEps);

    const int b = row / kS, s = row % kS;
    const int gh = grid_sizes[b*3 + 1], gw = grid_sizes[b*3 + 2];
    const int hw  = gh * gw;
    const int fi  = s / hw;
    const int rem = s - fi * hw;
    const int hi  = rem / gw;
    const int wi  = rem - hi * gw;

    const float4 g0 = *(const float4*)(g + t*8);
    const float4 g1 = *(const float4*)(g + t*8 + 4);
    const float gv[8] = {g0.x, g0.y, g0.z, g0.w, g1.x, g1.y, g1.z, g1.w};

    uint32_t out[4];
    #pragma unroll
    for (int jj = 0; jj < 4; ++jj) {
        const int p = t*4 + jj;
        const int c = p & 63;
        const int pos = (c < 22) ? fi : (c < 43 ? hi : wi);
        const float ang = freqs[pos * 64 + c];
        float sn, cs;
        sincosf(ang, &sn, &cs);
        const float e0 = v[2*jj]   * scale * gv[2*jj];
        const float e1 = v[2*jj+1] * scale * gv[2*jj+1];
        const float o0 = (e0 * cs - e1 * sn) * outmul;
        const float o1 = (e0 * sn + e1 * cs) * outmul;
        out[jj] = (uint32_t)f2bf(o0) | ((uint32_t)f2bf(o1) << 16);
    }
    uint4 ov; ov.x = out[0]; ov.y = out[1]; ov.z = out[2]; ov.w = out[3];
    ((uint4*)ptr)[t] = ov;
}

// ---------------------------------------------------------------------------
// Flash attention, split-K (3 thirds), swapped-QK^T 32x32x16 MFMA.
// Register-lean two-half processing (r10); P half-exchange via the
// r10-PROVEN shfl_xor(.,32) + hi/lo select (permlane retired after 2 fails).
// ---------------------------------------------------------------------------
__global__ __launch_bounds__(256, 3)
void attn_kernel(const ushort* __restrict__ qkv, const ushort* __restrict__ vtb,
                 ushort* __restrict__ p0, ushort* __restrict__ p1,
                 ushort* __restrict__ p2,
                 float* __restrict__ ml, const int* __restrict__ seq_lens)
{
    __shared__ ushort Ks[64 * 128];
    __shared__ ushort VT[128 * 64];

    // bijective XCD remap: 1728 % 8 == 0 -> L = (lin&7)*216 + (lin>>3).
    const int lin = blockIdx.x;
    const int L   = (lin & 7) * 216 + (lin >> 3);
    const int bh    = L / 72;                 // 72 = kSplit * 24 qtiles
    const int rem   = L - bh * 72;
    const int split = rem / 24;
    const int qtile = rem - split * 24;
    const int h = bh % kHeads, b = bh / kHeads;
    const int seq = seq_lens[b];
    const int kbeg = split * kKeys;

    const int t = threadIdx.x, lane = t & 63, w = t >> 6;
    const int l31 = lane & 31, hi = lane >> 5;
    const int qrow = qtile * 128 + w * 32 + l31;

    const ushort* qbase = qkv + ((size_t)b * kS) * kQKV + h * kHd;
    const ushort* kbase = qkv + ((size_t)b * kS) * kQKV + kDim + h * kHd;
    const ushort* vtbase = vtb + ((size_t)(b * kHeads + h) * kHd) * kS;

    // Q fragments (B-operand): qf[kb][j] = Q[qrow][kb*16 + hi*8 + j]
    short8 qf[8];
    #pragma unroll
    for (int kb = 0; kb < 8; ++kb)
        qf[kb] = *(const short8*)(qbase + (size_t)qrow * kQKV + kb*16 + hi*8);

    f32x16 oacc[4];
    #pragma unroll
    for (int n = 0; n < 4; ++n)
        #pragma unroll
        for (int i = 0; i < 16; ++i) oacc[n][i] = 0.f;

    float m_run = -1e30f, l_run = 0.f;

    const int srow = t >> 4;                      // 0..15
    const int scol = (t & 15) * 8;
    const int kl   = scol ^ ((srow & 7) << 3);    // pre-swizzled K source col
    const int vd0  = t >> 3;                      // 0..31
    const int vscol = ((t & 7) * 8) ^ ((vd0 & 7) << 3);  // pre-swizzled V^T col

    for (int kt = 0; kt < kKeys; kt += 64) {
        const int k0 = kbeg + kt;
        __syncthreads();
        #pragma unroll
        for (int c = 0; c < 4; ++c) {
            gload_lds16(kbase + (size_t)(k0 + srow + c*16) * kQKV + kl, &Ks[t*8 + c*2048]);
            gload_lds16(vtbase + (size_t)(vd0 + c*32) * kS + k0 + vscol, &VT[t*8 + c*2048]);
        }
        __syncthreads();

        // ---- two sequential 32-key halves (register-lean) ----
        #pragma unroll
        for (int hb = 0; hb < 2; ++hb) {
            // S^T = K . Q^T for rows hb*32 + l31; reg r -> key (r&3)+8*(r>>2)+4*hi
            f32x16 s;
            #pragma unroll
            for (int i = 0; i < 16; ++i) s[i] = 0.f;
            __builtin_amdgcn_s_setprio(1);
            #pragma unroll
            for (int kb = 0; kb < 8; ++kb) {
                const int col = (kb*16 + hi*8) ^ ((l31 & 7) << 3);
                short8 kf = *(const short8*)&Ks[(hb*32 + l31) * 128 + col];
                s = __builtin_amdgcn_mfma_f32_32x32x16_bf16(kf, qf[kb], s, 0, 0, 0);
            }
            __builtin_amdgcn_s_setprio(0);

            // mask + half max (scores already in log2 domain via kQMul)
            const int kb0 = k0 + hb*32;
            float mx = -1e30f;
            if (kb0 + 32 > seq) {
                #pragma unroll
                for (int r = 0; r < 16; ++r) {
                    if (kb0 + (r&3) + 8*(r>>2) + 4*hi >= seq) s[r] = -1e30f;
                    mx = fmaxf(mx, s[r]);
                }
            } else {
                #pragma unroll
                for (int r = 0; r < 16; ++r) mx = fmaxf(mx, s[r]);
            }
            mx = fmaxf(mx, __shfl_xor(mx, 32));

            // defer-max online softmax (T13)
            const bool skip = (mx <= m_run + 11.0f);
            if (!__all(skip)) {
                const float mnew = fmaxf(m_run, mx);
                const float alpha = exp2f(m_run - mnew);
                m_run = mnew;
                l_run *= alpha;
                #pragma unroll
                for (int r = 0; r < 16; ++r) {
                    const float ar = __shfl(alpha, (r&3) + 8*(r>>2) + 4*hi);
                    #pragma unroll
                    for (int n = 0; n < 4; ++n) oacc[n][r] *= ar;
                }
            }

            float rs = 0.f;
            #pragma unroll
            for (int r = 0; r < 16; ++r) {
                s[r] = exp2f(s[r] - m_run);
                rs += s[r];
            }
            rs += __shfl_xor(rs, 32);
            l_run += rs;

            // pack P -> bf16 dwords (cvt_pk); half-exchange via shfl_xor + select
            uint32_t u[8], wv[8];
            #pragma unroll
            for (int i = 0; i < 8; ++i) u[i] = cvtpk_bf16(s[2*i], s[2*i+1]);
            #pragma unroll
            for (int i = 0; i < 8; ++i) wv[i] = __shfl_xor(u[i], 32);
            union PF { uint32_t d[4]; short8 s8; };
            PF pa0, pa1;
            pa0.d[0] = hi ? wv[2] : u[0];  pa0.d[1] = hi ? wv[3] : u[1];
            pa0.d[2] = hi ? u[2] : wv[0];  pa0.d[3] = hi ? u[3] : wv[1];
            pa1.d[0] = hi ? wv[6] : u[4];  pa1.d[1] = hi ? wv[7] : u[5];
            pa1.d[2] = hi ? u[6] : wv[4];  pa1.d[3] = hi ? u[7] : wv[5];

            // PV for this half: k-slots hb*2 + {0,1}
            __builtin_amdgcn_s_setprio(1);
            #pragma unroll
            for (int kss = 0; kss < 2; ++kss) {
                const int ks = hb*2 + kss;
                #pragma unroll
                for (int n = 0; n < 4; ++n) {
                    const int d = n*32 + l31;
                    const int colv = (ks*16 + hi*8) ^ ((l31 & 7) << 3);
                    short8 vf = *(const short8*)&VT[d * 64 + colv];
                    oacc[n] = __builtin_amdgcn_mfma_f32_32x32x16_bf16(
                        (kss ? pa1 : pa0).s8, vf, oacc[n], 0, 0, 0);
                }
            }
            __builtin_amdgcn_s_setprio(0);
        }
    }

    // ---- epilogue: partial O' = O~/l (bf16) + per-row (m,l) ----
    ushort* pOut = (split == 0) ? p0 : (split == 1 ? p1 : p2);
    const float linv = 1.f / l_run;
    #pragma unroll
    for (int r = 0; r < 16; ++r) {
        const int qr = (r&3) + 8*(r>>2) + 4*hi;
        const float lr = __shfl(linv, qr);
        const size_t row = (size_t)(b * kS) + qtile * 128 + w * 32 + qr;
        #pragma unroll
        for (int n = 0; n < 4; ++n)
            pOut[row * kDim + h * kHd + n*32 + l31] = f2bf(oacc[n][r] * lr);
    }
    if (lane < 32) {
        const int s = qtile * 128 + w * 32 + l31;
        const size_t idx = ((((size_t)(b * kHeads + h)) * kSplit + split) * kS + s) * 2;
        ml[idx]     = m_run;
        ml[idx + 1] = l_run;
    }
}

// ---------------------------------------------------------------------------
// Combine 3 split-K partials in place into p0:
// O = sum_i a_i*O'_i / sum_i a_i,  a_i = l_i * 2^(m_i - m).
// Elementwise read-then-write of p0[i] -> in-place safe & deterministic.
// ---------------------------------------------------------------------------
__global__ __launch_bounds__(256)
void combine3_kernel(ushort* __restrict__ p0, const ushort* __restrict__ p1,
                     const ushort* __restrict__ p2,
                     const float* __restrict__ ml, int n8)
{
    int i = blockIdx.x * 256 + threadIdx.x;
    if (i >= n8) return;
    const int row = i / 192;               // 192 = kDim/8
    const int within = (i - row * 192) * 8;
    const int h = within >> 7;
    const int b = row / kS;
    const int s = row - b * kS;
    const size_t base = (size_t)(b * kHeads + h) * kSplit * kS;
    const float m0 = ml[(base + s) * 2],          l0 = ml[(base + s) * 2 + 1];
    const float m1 = ml[(base + kS + s) * 2],     l1 = ml[(base + kS + s) * 2 + 1];
    const float m2 = ml[(base + 2*kS + s) * 2],   l2 = ml[(base + 2*kS + s) * 2 + 1];
    const float m  = fmaxf(fmaxf(m0, m1), m2);
    const float a0 = l0 * exp2f(m0 - m);
    const float a1 = l1 * exp2f(m1 - m);
    const float a2 = l2 * exp2f(m2 - m);
    const float inv = 1.f / (a0 + a1 + a2);
    const float f0 = a0 * inv, f1 = a1 * inv, f2 = a2 * inv;

    uint4 ua = ((const uint4*)p0)[i];
    uint4 ub = ((const uint4*)p1)[i];
    uint4 uc = ((const uint4*)p2)[i];
    const uint32_t* da = (const uint32_t*)&ua;
    const uint32_t* db = (const uint32_t*)&ub;
    const uint32_t* dc = (const uint32_t*)&uc;
    uint32_t rv[4];
    #pragma unroll
    for (int j = 0; j < 4; ++j) {
        float o0 = f0 * bf2f(da[j] & 0xffff) + f1 * bf2f(db[j] & 0xffff) + f2 * bf2f(dc[j] & 0xffff);
        float o1 = f0 * bf2f(da[j] >> 16)    + f1 * bf2f(db[j] >> 16)    + f2 * bf2f(dc[j] >> 16);
        rv[j] = (uint32_t)f2bf(o0) | ((uint32_t)f2bf(o1) << 16);
    }
    uint4 r; r.x = rv[0]; r.y = rv[1]; r.z = rv[2]; r.w = rv[3];
    ((uint4*)p0)[i] = r;
}

// ---------------------------------------------------------------------------
extern "C" void kernel_launch(void* const* d_in, const int* in_sizes, int n_in,
                              void* d_out, int out_size, void* d_ws, size_t ws_size,
                              hipStream_t stream)
{
    (void)in_sizes; (void)n_in; (void)out_size; (void)ws_size;
    const float* x          = (const float*)d_in[0];
    const int*   seq_lens   = (const int*)  d_in[1];
    const int*   grid_sizes = (const int*)  d_in[2];
    const float* freqs      = (const float*)d_in[3];
    const float* Wq = (const float*)d_in[4];
    const float* bq = (const float*)d_in[5];
    const float* Wk = (const float*)d_in[6];
    const float* bk = (const float*)d_in[7];
    const float* Wv = (const float*)d_in[8];
    const float* bv = (const float*)d_in[9];
    const float* Wo = (const float*)d_in[10];
    const float* bo = (const float*)d_in[11];
    const float* gq = (const float*)d_in[12];
    const float* gk = (const float*)d_in[13];
    float* out = (float*)d_out;

    const int M = kB * kS;                       // 6144
    const size_t szX = (size_t)M * kDim;         // 9.44M elems
    const size_t szW = (size_t)kDim * kDim;

    ushort* xb   = (ushort*)d_ws;                // GEMM-A input, then partial 0 + combined O
    ushort* wqb  = xb   + szX;                   // wq|wk|wv contiguous = fused B
    ushort* wkb  = wqb  + szW;
    ushort* wvb  = wkb  + szW;
    ushort* wob  = wvb  + szW;
    ushort* qkvb = wob  + szW;                   // [6144][4608]
    ushort* ab   = qkvb + 3*szX;                 // partial 1
    ushort* vtb  = ab   + szX;
    ushort* pBuf = vtb  + szX;                   // partial 2
    float*  biasqkv = (float*)(pBuf + szX);      // 4608 f32
    float*  ml   = biasqkv + kQKV;               // 24*3*3072*2 f32

    dim3 blk(256);
    cvt_kernel<<<dim3((int)(szX/8/256)), blk, 0, stream>>>(x, xb, (int)(szX/8));
    cvt4_kernel<<<dim3((int)(szW/8/256), 4), blk, 0, stream>>>(
        Wq, Wk, Wv, Wo, wqb, wkb, wvb, wob, (int)(szW/8));
    biascat_kernel<<<dim3(18), blk, 0, stream>>>(bq, bk, bv, biasqkv);

    // fused QKV projection: N = 4608
    gemm_bf16<ushort><<<dim3(kQKV/128, M/128), blk, 0, stream>>>(
        xb, wqb, biasqkv, qkvb, M, kQKV, kDim);

    rmsrope_kernel<<<dim3(M, 2), dim3(192), 0, stream>>>(qkvb, gq, gk, freqs, grid_sizes);
    vtrans_kernel<<<dim3(kS/64, 2, kB*kHeads), blk, 0, stream>>>(qkvb, vtb);

    // split-K flash attention: 24 bh x 3 splits x 24 qtiles = 1728 blocks
    attn_kernel<<<dim3(1728), blk, 0, stream>>>(
        qkvb, vtb, xb, ab, pBuf, ml, seq_lens);
    combine3_kernel<<<dim3((int)(szX/8/256)), blk, 0, stream>>>(
        xb, ab, pBuf, ml, (int)(szX/8));

    gemm_bf16<float><<<dim3(kDim/128, M/128), blk, 0, stream>>>(
        xb, wob, bo, out, M, kDim, kDim);
}

// Round 13
// 421.844 us; speedup vs baseline: 1.0356x; 1.0356x over previous
//
#include <hip/hip_runtime.h>
#include <hip/hip_bf16.h>
#include <stdint.h>

typedef __attribute__((ext_vector_type(8))) short short8;
typedef __attribute__((ext_vector_type(4))) float f32x4;
typedef __attribute__((ext_vector_type(16))) float f32x16;

constexpr int kDim   = 1536;
constexpr int kHeads = 12;
constexpr int kHd    = 128;
constexpr int kS     = 3072;
constexpr int kB     = 2;
constexpr int kQKV   = 3 * kDim;               // 4608 fused row width
constexpr float kEps   = 1e-6f;
constexpr float kQMul  = 0.08838834764831845f * 1.44269504089f; // 1/sqrt(128)*log2(e)

__device__ __forceinline__ ushort f2bf(float f) {
    union { float f; uint32_t u; } c; c.f = f;
    uint32_t u = c.u;
    return (ushort)((u + 0x7fffu + ((u >> 16) & 1u)) >> 16);
}
__device__ __forceinline__ float bf2f(uint32_t h) {
    union { uint32_t u; float f; } c; c.u = h << 16;
    return c.f;
}
__device__ __forceinline__ void gload_lds16(const void* g, void* l) {
    __builtin_amdgcn_global_load_lds((const __attribute__((address_space(1))) void*)g,
                                     (__attribute__((address_space(3))) void*)l, 16, 0, 0);
}
__device__ __forceinline__ uint32_t cvtpk_bf16(float lo, float hi) {
    uint32_t r;
    asm("v_cvt_pk_bf16_f32 %0, %1, %2" : "=v"(r) : "v"(lo), "v"(hi));
    return r;
}

// ---------------------------------------------------------------------------
// fp32 -> bf16 convert, 8 elems/thread
// ---------------------------------------------------------------------------
__global__ __launch_bounds__(256)
void cvt_kernel(const float* __restrict__ in, ushort* __restrict__ out, int n8)
{
    int i = blockIdx.x * 256 + threadIdx.x;
    if (i >= n8) return;
    const float4* p = (const float4*)in + (size_t)i * 2;
    float4 a = p[0], b = p[1];
    uint4 r;
    r.x = (uint32_t)f2bf(a.x) | ((uint32_t)f2bf(a.y) << 16);
    r.y = (uint32_t)f2bf(a.z) | ((uint32_t)f2bf(a.w) << 16);
    r.z = (uint32_t)f2bf(b.x) | ((uint32_t)f2bf(b.y) << 16);
    r.w = (uint32_t)f2bf(b.z) | ((uint32_t)f2bf(b.w) << 16);
    ((uint4*)out)[i] = r;
}

// 4 weight tensors in one dispatch (blockIdx.y selects)
__global__ __launch_bounds__(256)
void cvt4_kernel(const float* __restrict__ s0, const float* __restrict__ s1,
                 const float* __restrict__ s2, const float* __restrict__ s3,
                 ushort* __restrict__ d0, ushort* __restrict__ d1,
                 ushort* __restrict__ d2, ushort* __restrict__ d3, int n8)
{
    int i = blockIdx.x * 256 + threadIdx.x;
    if (i >= n8) return;
    const float* in; ushort* out;
    switch (blockIdx.y) {
        case 0: in = s0; out = d0; break;
        case 1: in = s1; out = d1; break;
        case 2: in = s2; out = d2; break;
        default: in = s3; out = d3; break;
    }
    const float4* p = (const float4*)in + (size_t)i * 2;
    float4 a = p[0], b = p[1];
    uint4 r;
    r.x = (uint32_t)f2bf(a.x) | ((uint32_t)f2bf(a.y) << 16);
    r.y = (uint32_t)f2bf(a.z) | ((uint32_t)f2bf(a.w) << 16);
    r.z = (uint32_t)f2bf(b.x) | ((uint32_t)f2bf(b.y) << 16);
    r.w = (uint32_t)f2bf(b.z) | ((uint32_t)f2bf(b.w) << 16);
    ((uint4*)out)[i] = r;
}

// concat bq|bk|bv -> biasqkv[4608]
__global__ __launch_bounds__(256)
void biascat_kernel(const float* __restrict__ bq, const float* __restrict__ bk,
                    const float* __restrict__ bv, float* __restrict__ out)
{
    int i = blockIdx.x * 256 + threadIdx.x;
    if (i >= kQKV) return;
    float v = (i < kDim) ? bq[i] : (i < 2*kDim) ? bk[i - kDim] : bv[i - 2*kDim];
    out[i] = v;
}

// ---------------------------------------------------------------------------
// bf16 MFMA GEMM: C[M][N] = A[M][K] @ B[N][K]^T + bias   (m97-style 128^2, BK=32)
// ---------------------------------------------------------------------------
template<typename OutT>
__global__ __launch_bounds__(256)
void gemm_bf16(const ushort* __restrict__ A, const ushort* __restrict__ B,
               const float* __restrict__ bias, OutT* __restrict__ C,
               int M, int N, int K)
{
    __shared__ ushort As[128 * 32];
    __shared__ ushort Bs[128 * 32];
    const int t    = threadIdx.x;
    const int lane = t & 63;
    const int w    = t >> 6;
    const int wm = (w >> 1) * 64, wn = (w & 1) * 64;
    const int m0 = blockIdx.y * 128, n0 = blockIdx.x * 128;

    const int srow = t >> 2;
    const int skc  = (t & 3) * 8;
    const ushort* Ag = A + (size_t)(m0 + srow) * K + skc;
    const ushort* Bg = B + (size_t)(n0 + srow) * K + skc;
    const size_t half = (size_t)64 * K;

    f32x4 acc[4][4];
    #pragma unroll
    for (int m = 0; m < 4; ++m)
        #pragma unroll
        for (int n = 0; n < 4; ++n)
            #pragma unroll
            for (int i = 0; i < 4; ++i) acc[m][n][i] = 0.f;

    const int kk  = (lane >> 4) * 8;
    const int l15 = lane & 15;

    for (int k0 = 0; k0 < K; k0 += 32) {
        __syncthreads();
        gload_lds16(Ag + k0,        &As[t * 8]);
        gload_lds16(Ag + half + k0, &As[t * 8 + 2048]);
        gload_lds16(Bg + k0,        &Bs[t * 8]);
        gload_lds16(Bg + half + k0, &Bs[t * 8 + 2048]);
        __syncthreads();
        short8 af[4], bf[4];
        #pragma unroll
        for (int m = 0; m < 4; ++m) af[m] = *(const short8*)&As[(wm + m*16 + l15) * 32 + kk];
        #pragma unroll
        for (int n = 0; n < 4; ++n) bf[n] = *(const short8*)&Bs[(wn + n*16 + l15) * 32 + kk];
        #pragma unroll
        for (int m = 0; m < 4; ++m)
            #pragma unroll
            for (int n = 0; n < 4; ++n)
                acc[m][n] = __builtin_amdgcn_mfma_f32_16x16x32_bf16(af[m], bf[n], acc[m][n], 0, 0, 0);
    }

    const int r0 = (lane >> 4) * 4;
    #pragma unroll
    for (int m = 0; m < 4; ++m) {
        #pragma unroll
        for (int r = 0; r < 4; ++r) {
            const size_t row = (size_t)(m0 + wm + m*16 + r0 + r);
            #pragma unroll
            for (int n = 0; n < 4; ++n) {
                const int col = n0 + wn + n*16 + l15;
                float val = acc[m][n][r] + bias[col];
                if constexpr (sizeof(OutT) == 4) C[row * N + col] = val;
                else                             C[row * N + col] = f2bf(val);
            }
        }
    }
}

// ---------------------------------------------------------------------------
// V transpose from fused qkv: vt[b][h][d][s] = qkv[b][s][3072 + h*128 + d]
// ---------------------------------------------------------------------------
__global__ __launch_bounds__(256)
void vtrans_kernel(const ushort* __restrict__ qkv, ushort* __restrict__ vt)
{
    __shared__ ushort Ts[64][72];
    const int t  = threadIdx.x;
    const int s0 = blockIdx.x * 64;
    const int d0 = blockIdx.y * 64;
    const int bh = blockIdx.z;
    const int b = bh / kHeads, h = bh % kHeads;

    const int r = t >> 2, cc = (t & 3) * 16;
    const ushort* src = qkv + ((size_t)(b * kS) + s0 + r) * kQKV + 2*kDim + h * kHd + d0 + cc;
    uint4 a0 = *(const uint4*)src;
    uint4 a1 = *(const uint4*)(src + 8);
    *(uint4*)&Ts[r][cc]     = a0;
    *(uint4*)&Ts[r][cc + 8] = a1;
    __syncthreads();
    ushort tmp[16];
    #pragma unroll
    for (int j = 0; j < 16; ++j) tmp[j] = Ts[cc + j][r];
    ushort* dst = vt + ((size_t)(bh * kHd) + d0 + r) * kS + s0 + cc;
    *(uint4*)dst       = *(uint4*)&tmp[0];
    *(uint4*)(dst + 8) = *(uint4*)&tmp[8];
}

// ---------------------------------------------------------------------------
// RMSNorm + RoPE on q/k sections of fused qkv. 192 thr, 8 elems each.
// ---------------------------------------------------------------------------
__global__ __launch_bounds__(192)
void rmsrope_kernel(ushort* __restrict__ qkv,
                    const float* __restrict__ gq, const float* __restrict__ gk,
                    const float* __restrict__ freqs, const int* __restrict__ grid_sizes)
{
    __shared__ float red[4];
    const int row   = blockIdx.x;
    const int which = blockIdx.y;
    ushort* ptr = qkv + (size_t)row * kQKV + which * kDim;
    const float* g = which ? gk : gq;
    const float outmul = which ? 1.0f : kQMul;
    const int t = threadIdx.x;

    uint4 raw = ((const uint4*)ptr)[t];
    float v[8];
    v[0] = bf2f(raw.x & 0xffff); v[1] = bf2f(raw.x >> 16);
    v[2] = bf2f(raw.y & 0xffff); v[3] = bf2f(raw.y >> 16);
    v[4] = bf2f(raw.z & 0xffff); v[5] = bf2f(raw.z >> 16);
    v[6] = bf2f(raw.w & 0xffff); v[7] = bf2f(raw.w >> 16);

    float ss = 0.f;
    #pragma unroll
    for (int i = 0; i < 8; ++i) ss += v[i] * v[i];
    #pragma unroll
    for (int off = 32; off >= 1; off >>= 1) ss += __shfl_xor(ss, off);
    if ((t & 63) == 0) red[t >> 6] = ss;
    __syncthreads();
    const float scale = rsqrtf((red[0] + red[1] + red[2]) * (1.f / kDim) + kEps);

    const int b = row / kS, s = row % kS;
    const int gh = grid_sizes[b*3 + 1], gw = grid_sizes[b*3 + 2];
    const int hw  = gh * gw;
    const int fi  = s / hw;
    const int rem = s - fi * hw;
    const int hi  = rem / gw;
    const int wi  = rem - hi * gw;

    const float4 g0 = *(const float4*)(g + t*8);
    const float4 g1 = *(const float4*)(g + t*8 + 4);
    const float gv[8] = {g0.x, g0.y, g0.z, g0.w, g1.x, g1.y, g1.z, g1.w};

    uint32_t out[4];
    #pragma unroll
    for (int jj = 0; jj < 4; ++jj) {
        const int p = t*4 + jj;
        const int c = p & 63;
        const int pos = (c < 22) ? fi : (c < 43 ? hi : wi);
        const float ang = freqs[pos * 64 + c];
        float sn, cs;
        sincosf(ang, &sn, &cs);
        const float e0 = v[2*jj]   * scale * gv[2*jj];
        const float e1 = v[2*jj+1] * scale * gv[2*jj+1];
        const float o0 = (e0 * cs - e1 * sn) * outmul;
        const float o1 = (e0 * sn + e1 * cs) * outmul;
        out[jj] = (uint32_t)f2bf(o0) | ((uint32_t)f2bf(o1) << 16);
    }
    uint4 ov; ov.x = out[0]; ov.y = out[1]; ov.z = out[2]; ov.w = out[3];
    ((uint4*)ptr)[t] = ov;
}

// ---------------------------------------------------------------------------
// Flash attention, split-K (2 halves), swapped-QK^T 32x32x16 MFMA.
// Register-lean: the 64-key tile is processed as two sequential 32-key
// halves so only one f32x16 score block + one pack set is live at a time
// -> launch_bounds(256,3) gives 3 waves/SIMD without spilling.
// P half-exchange via shfl_xor(.,32) + hi/lo select (proven r5/r10).
// ---------------------------------------------------------------------------
__global__ __launch_bounds__(256, 3)
void attn_kernel(const ushort* __restrict__ qkv, const ushort* __restrict__ vtb,
                 ushort* __restrict__ pA, ushort* __restrict__ pB,
                 float* __restrict__ ml, const int* __restrict__ seq_lens)
{
    __shared__ ushort Ks[64 * 128];
    __shared__ ushort VT[128 * 64];

    // bijective XCD remap: consecutive logical ids (sharing (h,b) K/V) land on
    // the same XCD's L2.  1152 % 8 == 0 -> L = (lin&7)*144 + (lin>>3).
    const int lin = blockIdx.x;
    const int L   = (lin & 7) * 144 + (lin >> 3);
    const int bh   = L / 48;
    const int rem  = L - bh * 48;
    const int half = rem / 24;
    const int qtile= rem - half * 24;
    const int h = bh % kHeads, b = bh / kHeads;
    const int seq = seq_lens[b];
    const int kbeg = half * (kS / 2);

    const int t = threadIdx.x, lane = t & 63, w = t >> 6;
    const int l31 = lane & 31, hi = lane >> 5;
    const int qrow = qtile * 128 + w * 32 + l31;

    const ushort* qbase = qkv + ((size_t)b * kS) * kQKV + h * kHd;
    const ushort* kbase = qkv + ((size_t)b * kS) * kQKV + kDim + h * kHd;
    const ushort* vtbase = vtb + ((size_t)(b * kHeads + h) * kHd) * kS;

    // Q fragments (B-operand): qf[kb][j] = Q[qrow][kb*16 + hi*8 + j]
    short8 qf[8];
    #pragma unroll
    for (int kb = 0; kb < 8; ++kb)
        qf[kb] = *(const short8*)(qbase + (size_t)qrow * kQKV + kb*16 + hi*8);

    f32x16 oacc[4];
    #pragma unroll
    for (int n = 0; n < 4; ++n)
        #pragma unroll
        for (int i = 0; i < 16; ++i) oacc[n][i] = 0.f;

    float m_run = -1e30f, l_run = 0.f;

    const int srow = t >> 4;                      // 0..15
    const int scol = (t & 15) * 8;
    const int kl   = scol ^ ((srow & 7) << 3);    // pre-swizzled K source col
    const int vd0  = t >> 3;                      // 0..31
    const int vscol = ((t & 7) * 8) ^ ((vd0 & 7) << 3);  // pre-swizzled V^T col

    for (int kt = 0; kt < kS/2; kt += 64) {
        const int k0 = kbeg + kt;
        __syncthreads();
        #pragma unroll
        for (int c = 0; c < 4; ++c) {
            gload_lds16(kbase + (size_t)(k0 + srow + c*16) * kQKV + kl, &Ks[t*8 + c*2048]);
            gload_lds16(vtbase + (size_t)(vd0 + c*32) * kS + k0 + vscol, &VT[t*8 + c*2048]);
        }
        __syncthreads();

        // ---- two sequential 32-key halves (register-lean) ----
        #pragma unroll
        for (int hb = 0; hb < 2; ++hb) {
            // S^T = K . Q^T for rows hb*32 + l31; reg r -> key (r&3)+8*(r>>2)+4*hi
            f32x16 s;
            #pragma unroll
            for (int i = 0; i < 16; ++i) s[i] = 0.f;
            __builtin_amdgcn_s_setprio(1);
            #pragma unroll
            for (int kb = 0; kb < 8; ++kb) {
                const int col = (kb*16 + hi*8) ^ ((l31 & 7) << 3);
                short8 kf = *(const short8*)&Ks[(hb*32 + l31) * 128 + col];
                s = __builtin_amdgcn_mfma_f32_32x32x16_bf16(kf, qf[kb], s, 0, 0, 0);
            }
            __builtin_amdgcn_s_setprio(0);

            // mask + half max (scores already in log2 domain via kQMul)
            const int kb0 = k0 + hb*32;
            float mx = -1e30f;
            if (kb0 + 32 > seq) {
                #pragma unroll
                for (int r = 0; r < 16; ++r) {
                    if (kb0 + (r&3) + 8*(r>>2) + 4*hi >= seq) s[r] = -1e30f;
                    mx = fmaxf(mx, s[r]);
                }
            } else {
                #pragma unroll
                for (int r = 0; r < 16; ++r) mx = fmaxf(mx, s[r]);
            }
            mx = fmaxf(mx, __shfl_xor(mx, 32));

            // defer-max online softmax (T13)
            const bool skip = (mx <= m_run + 11.0f);
            if (!__all(skip)) {
                const float mnew = fmaxf(m_run, mx);
                const float alpha = exp2f(m_run - mnew);
                m_run = mnew;
                l_run *= alpha;
                #pragma unroll
                for (int r = 0; r < 16; ++r) {
                    const float ar = __shfl(alpha, (r&3) + 8*(r>>2) + 4*hi);
                    #pragma unroll
                    for (int n = 0; n < 4; ++n) oacc[n][r] *= ar;
                }
            }

            float rs = 0.f;
            #pragma unroll
            for (int r = 0; r < 16; ++r) {
                s[r] = exp2f(s[r] - m_run);
                rs += s[r];
            }
            rs += __shfl_xor(rs, 32);
            l_run += rs;

            // pack P -> bf16 dwords (cvt_pk); half-exchange via shfl_xor + select
            uint32_t u[8], wv[8];
            #pragma unroll
            for (int i = 0; i < 8; ++i) u[i] = cvtpk_bf16(s[2*i], s[2*i+1]);
            #pragma unroll
            for (int i = 0; i < 8; ++i) wv[i] = __shfl_xor(u[i], 32);
            union PF { uint32_t d[4]; short8 s8; };
            PF pa0, pa1;
            pa0.d[0] = hi ? wv[2] : u[0];  pa0.d[1] = hi ? wv[3] : u[1];
            pa0.d[2] = hi ? u[2] : wv[0];  pa0.d[3] = hi ? u[3] : wv[1];
            pa1.d[0] = hi ? wv[6] : u[4];  pa1.d[1] = hi ? wv[7] : u[5];
            pa1.d[2] = hi ? u[6] : wv[4];  pa1.d[3] = hi ? u[7] : wv[5];

            // PV for this half: k-slots hb*2 + {0,1}
            __builtin_amdgcn_s_setprio(1);
            #pragma unroll
            for (int kss = 0; kss < 2; ++kss) {
                const int ks = hb*2 + kss;
                #pragma unroll
                for (int n = 0; n < 4; ++n) {
                    const int d = n*32 + l31;
                    const int colv = (ks*16 + hi*8) ^ ((l31 & 7) << 3);
                    short8 vf = *(const short8*)&VT[d * 64 + colv];
                    oacc[n] = __builtin_amdgcn_mfma_f32_32x32x16_bf16(
                        (kss ? pa1 : pa0).s8, vf, oacc[n], 0, 0, 0);
                }
            }
            __builtin_amdgcn_s_setprio(0);
        }
    }

    // ---- epilogue: partial O' = O~/l (bf16) + per-row (m,l) ----
    ushort* pOut = half ? pB : pA;
    const float linv = 1.f / l_run;
    #pragma unroll
    for (int r = 0; r < 16; ++r) {
        const int qr = (r&3) + 8*(r>>2) + 4*hi;
        const float lr = __shfl(linv, qr);
        const size_t row = (size_t)(b * kS) + qtile * 128 + w * 32 + qr;
        #pragma unroll
        for (int n = 0; n < 4; ++n)
            pOut[row * kDim + h * kHd + n*32 + l31] = f2bf(oacc[n][r] * lr);
    }
    if (lane < 32) {
        const int s = qtile * 128 + w * 32 + l31;
        const size_t idx = ((((size_t)(b * kHeads + h)) * 2 + half) * kS + s) * 2;
        ml[idx]     = m_run;
        ml[idx + 1] = l_run;
    }
}

// ---------------------------------------------------------------------------
// Combine split-K partials: O = (a0*O'0 + a1*O'1)/(a0+a1), a_i = l_i*2^(m_i-m)
// ---------------------------------------------------------------------------
__global__ __launch_bounds__(256)
void combine_kernel(const ushort* __restrict__ pA, const ushort* __restrict__ pB,
                    const float* __restrict__ ml, ushort* __restrict__ out, int n8)
{
    int i = blockIdx.x * 256 + threadIdx.x;
    if (i >= n8) return;
    const int row = i / 192;               // 192 = kDim/8
    const int within = (i - row * 192) * 8;
    const int h = within >> 7;
    const int b = row / kS;
    const int s = row - b * kS;
    const size_t base = (((size_t)(b * kHeads + h)) * 2) * kS;
    const float m0 = ml[(base + s) * 2],        l0 = ml[(base + s) * 2 + 1];
    const float m1 = ml[(base + kS + s) * 2],   l1 = ml[(base + kS + s) * 2 + 1];
    const float m  = fmaxf(m0, m1);
    const float a0 = l0 * exp2f(m0 - m);
    const float a1 = l1 * exp2f(m1 - m);
    const float inv = 1.f / (a0 + a1);
    const float f0 = a0 * inv, f1 = a1 * inv;

    uint4 ua = ((const uint4*)pA)[i];
    uint4 ub = ((const uint4*)pB)[i];
    const uint32_t* da = (const uint32_t*)&ua;
    const uint32_t* db = (const uint32_t*)&ub;
    uint32_t rv[4];
    #pragma unroll
    for (int j = 0; j < 4; ++j) {
        float o0 = f0 * bf2f(da[j] & 0xffff) + f1 * bf2f(db[j] & 0xffff);
        float o1 = f0 * bf2f(da[j] >> 16)    + f1 * bf2f(db[j] >> 16);
        rv[j] = (uint32_t)f2bf(o0) | ((uint32_t)f2bf(o1) << 16);
    }
    uint4 r; r.x = rv[0]; r.y = rv[1]; r.z = rv[2]; r.w = rv[3];
    ((uint4*)out)[i] = r;
}

// ---------------------------------------------------------------------------
extern "C" void kernel_launch(void* const* d_in, const int* in_sizes, int n_in,
                              void* d_out, int out_size, void* d_ws, size_t ws_size,
                              hipStream_t stream)
{
    (void)in_sizes; (void)n_in; (void)out_size; (void)ws_size;
    const float* x          = (const float*)d_in[0];
    const int*   seq_lens   = (const int*)  d_in[1];
    const int*   grid_sizes = (const int*)  d_in[2];
    const float* freqs      = (const float*)d_in[3];
    const float* Wq = (const float*)d_in[4];
    const float* bq = (const float*)d_in[5];
    const float* Wk = (const float*)d_in[6];
    const float* bk = (const float*)d_in[7];
    const float* Wv = (const float*)d_in[8];
    const float* bv = (const float*)d_in[9];
    const float* Wo = (const float*)d_in[10];
    const float* bo = (const float*)d_in[11];
    const float* gq = (const float*)d_in[12];
    const float* gk = (const float*)d_in[13];
    float* out = (float*)d_out;

    const int M = kB * kS;                       // 6144
    const size_t szX = (size_t)M * kDim;         // 9.44M elems
    const size_t szW = (size_t)kDim * kDim;

    ushort* xb   = (ushort*)d_ws;                // GEMM-A input, then partial A
    ushort* wqb  = xb   + szX;                   // wq|wk|wv contiguous = fused B
    ushort* wkb  = wqb  + szW;
    ushort* wvb  = wkb  + szW;
    ushort* wob  = wvb  + szW;
    ushort* qkvb = wob  + szW;                   // [6144][4608]
    ushort* ab   = qkvb + 3*szX;
    ushort* vtb  = ab   + szX;
    ushort* pBuf = vtb  + szX;                   // partial B (bf16, szX)
    float*  biasqkv = (float*)(pBuf + szX);      // 4608 f32
    float*  ml   = biasqkv + kQKV;               // 2*12*2*3072*2 f32

    dim3 blk(256);
    cvt_kernel<<<dim3((int)(szX/8/256)), blk, 0, stream>>>(x, xb, (int)(szX/8));
    cvt4_kernel<<<dim3((int)(szW/8/256), 4), blk, 0, stream>>>(
        Wq, Wk, Wv, Wo, wqb, wkb, wvb, wob, (int)(szW/8));
    biascat_kernel<<<dim3(18), blk, 0, stream>>>(bq, bk, bv, biasqkv);

    // fused QKV projection: N = 4608
    gemm_bf16<ushort><<<dim3(kQKV/128, M/128), blk, 0, stream>>>(
        xb, wqb, biasqkv, qkvb, M, kQKV, kDim);

    rmsrope_kernel<<<dim3(M, 2), dim3(192), 0, stream>>>(qkvb, gq, gk, freqs, grid_sizes);
    vtrans_kernel<<<dim3(kS/64, 2, kB*kHeads), blk, 0, stream>>>(qkvb, vtb);

    // split-K flash attention: 48 x 24 = 1152 blocks (xb reused as partial A)
    attn_kernel<<<dim3(48 * kHeads * kB), blk, 0, stream>>>(
        qkvb, vtb, xb, pBuf, ml, seq_lens);
    combine_kernel<<<dim3((int)(szX/8/256)), blk, 0, stream>>>(
        xb, pBuf, ml, ab, (int)(szX/8));

    gemm_bf16<float><<<dim3(kDim/128, M/128), blk, 0, stream>>>(
        ab, wob, bo, out, M, kDim, kDim);
}

// Round 14
// 418.438 us; speedup vs baseline: 1.0440x; 1.0081x over previous
//
#include <hip/hip_runtime.h>
#include <hip/hip_bf16.h>
#include <stdint.h>

typedef __attribute__((ext_vector_type(8))) short short8;
typedef __attribute__((ext_vector_type(4))) float f32x4;
typedef __attribute__((ext_vector_type(16))) float f32x16;

constexpr int kDim   = 1536;
constexpr int kHeads = 12;
constexpr int kHd    = 128;
constexpr int kS     = 3072;
constexpr int kB     = 2;
constexpr int kQKV   = 3 * kDim;               // 4608 fused row width
constexpr float kEps   = 1e-6f;
constexpr float kQMul  = 0.08838834764831845f * 1.44269504089f; // 1/sqrt(128)*log2(e)

__device__ __forceinline__ ushort f2bf(float f) {
    union { float f; uint32_t u; } c; c.f = f;
    uint32_t u = c.u;
    return (ushort)((u + 0x7fffu + ((u >> 16) & 1u)) >> 16);
}
__device__ __forceinline__ float bf2f(uint32_t h) {
    union { uint32_t u; float f; } c; c.u = h << 16;
    return c.f;
}
__device__ __forceinline__ void gload_lds16(const void* g, void* l) {
    __builtin_amdgcn_global_load_lds((const __attribute__((address_space(1))) void*)g,
                                     (__attribute__((address_space(3))) void*)l, 16, 0, 0);
}
__device__ __forceinline__ uint32_t cvtpk_bf16(float lo, float hi) {
    uint32_t r;
    asm("v_cvt_pk_bf16_f32 %0, %1, %2" : "=v"(r) : "v"(lo), "v"(hi));
    return r;
}

// ---------------------------------------------------------------------------
// fp32 -> bf16 convert, 8 elems/thread
// ---------------------------------------------------------------------------
__global__ __launch_bounds__(256)
void cvt_kernel(const float* __restrict__ in, ushort* __restrict__ out, int n8)
{
    int i = blockIdx.x * 256 + threadIdx.x;
    if (i >= n8) return;
    const float4* p = (const float4*)in + (size_t)i * 2;
    float4 a = p[0], b = p[1];
    uint4 r;
    r.x = (uint32_t)f2bf(a.x) | ((uint32_t)f2bf(a.y) << 16);
    r.y = (uint32_t)f2bf(a.z) | ((uint32_t)f2bf(a.w) << 16);
    r.z = (uint32_t)f2bf(b.x) | ((uint32_t)f2bf(b.y) << 16);
    r.w = (uint32_t)f2bf(b.z) | ((uint32_t)f2bf(b.w) << 16);
    ((uint4*)out)[i] = r;
}

// 4 weight tensors in one dispatch (blockIdx.y selects)
__global__ __launch_bounds__(256)
void cvt4_kernel(const float* __restrict__ s0, const float* __restrict__ s1,
                 const float* __restrict__ s2, const float* __restrict__ s3,
                 ushort* __restrict__ d0, ushort* __restrict__ d1,
                 ushort* __restrict__ d2, ushort* __restrict__ d3, int n8)
{
    int i = blockIdx.x * 256 + threadIdx.x;
    if (i >= n8) return;
    const float* in; ushort* out;
    switch (blockIdx.y) {
        case 0: in = s0; out = d0; break;
        case 1: in = s1; out = d1; break;
        case 2: in = s2; out = d2; break;
        default: in = s3; out = d3; break;
    }
    const float4* p = (const float4*)in + (size_t)i * 2;
    float4 a = p[0], b = p[1];
    uint4 r;
    r.x = (uint32_t)f2bf(a.x) | ((uint32_t)f2bf(a.y) << 16);
    r.y = (uint32_t)f2bf(a.z) | ((uint32_t)f2bf(a.w) << 16);
    r.z = (uint32_t)f2bf(b.x) | ((uint32_t)f2bf(b.y) << 16);
    r.w = (uint32_t)f2bf(b.z) | ((uint32_t)f2bf(b.w) << 16);
    ((uint4*)out)[i] = r;
}

// concat bq|bk|bv -> biasqkv[4608]
__global__ __launch_bounds__(256)
void biascat_kernel(const float* __restrict__ bq, const float* __restrict__ bk,
                    const float* __restrict__ bv, float* __restrict__ out)
{
    int i = blockIdx.x * 256 + threadIdx.x;
    if (i >= kQKV) return;
    float v = (i < kDim) ? bq[i] : (i < 2*kDim) ? bk[i - kDim] : bv[i - 2*kDim];
    out[i] = v;
}

// ---------------------------------------------------------------------------
// bf16 MFMA GEMM: C[M][N] = A[M][K] @ B[N][K]^T + bias   (m97-style 128^2, BK=32)
// ---------------------------------------------------------------------------
template<typename OutT>
__global__ __launch_bounds__(256)
void gemm_bf16(const ushort* __restrict__ A, const ushort* __restrict__ B,
               const float* __restrict__ bias, OutT* __restrict__ C,
               int M, int N, int K)
{
    __shared__ ushort As[128 * 32];
    __shared__ ushort Bs[128 * 32];
    const int t    = threadIdx.x;
    const int lane = t & 63;
    const int w    = t >> 6;
    const int wm = (w >> 1) * 64, wn = (w & 1) * 64;
    const int m0 = blockIdx.y * 128, n0 = blockIdx.x * 128;

    const int srow = t >> 2;
    const int skc  = (t & 3) * 8;
    const ushort* Ag = A + (size_t)(m0 + srow) * K + skc;
    const ushort* Bg = B + (size_t)(n0 + srow) * K + skc;
    const size_t half = (size_t)64 * K;

    f32x4 acc[4][4];
    #pragma unroll
    for (int m = 0; m < 4; ++m)
        #pragma unroll
        for (int n = 0; n < 4; ++n)
            #pragma unroll
            for (int i = 0; i < 4; ++i) acc[m][n][i] = 0.f;

    const int kk  = (lane >> 4) * 8;
    const int l15 = lane & 15;

    for (int k0 = 0; k0 < K; k0 += 32) {
        __syncthreads();
        gload_lds16(Ag + k0,        &As[t * 8]);
        gload_lds16(Ag + half + k0, &As[t * 8 + 2048]);
        gload_lds16(Bg + k0,        &Bs[t * 8]);
        gload_lds16(Bg + half + k0, &Bs[t * 8 + 2048]);
        __syncthreads();
        short8 af[4], bf[4];
        #pragma unroll
        for (int m = 0; m < 4; ++m) af[m] = *(const short8*)&As[(wm + m*16 + l15) * 32 + kk];
        #pragma unroll
        for (int n = 0; n < 4; ++n) bf[n] = *(const short8*)&Bs[(wn + n*16 + l15) * 32 + kk];
        #pragma unroll
        for (int m = 0; m < 4; ++m)
            #pragma unroll
            for (int n = 0; n < 4; ++n)
                acc[m][n] = __builtin_amdgcn_mfma_f32_16x16x32_bf16(af[m], bf[n], acc[m][n], 0, 0, 0);
    }

    const int r0 = (lane >> 4) * 4;
    #pragma unroll
    for (int m = 0; m < 4; ++m) {
        #pragma unroll
        for (int r = 0; r < 4; ++r) {
            const size_t row = (size_t)(m0 + wm + m*16 + r0 + r);
            #pragma unroll
            for (int n = 0; n < 4; ++n) {
                const int col = n0 + wn + n*16 + l15;
                float val = acc[m][n][r] + bias[col];
                if constexpr (sizeof(OutT) == 4) C[row * N + col] = val;
                else                             C[row * N + col] = f2bf(val);
            }
        }
    }
}

// ---------------------------------------------------------------------------
// V transpose from fused qkv: vt[b][h][d][s] = qkv[b][s][3072 + h*128 + d]
// ---------------------------------------------------------------------------
__global__ __launch_bounds__(256)
void vtrans_kernel(const ushort* __restrict__ qkv, ushort* __restrict__ vt)
{
    __shared__ ushort Ts[64][72];
    const int t  = threadIdx.x;
    const int s0 = blockIdx.x * 64;
    const int d0 = blockIdx.y * 64;
    const int bh = blockIdx.z;
    const int b = bh / kHeads, h = bh % kHeads;

    const int r = t >> 2, cc = (t & 3) * 16;
    const ushort* src = qkv + ((size_t)(b * kS) + s0 + r) * kQKV + 2*kDim + h * kHd + d0 + cc;
    uint4 a0 = *(const uint4*)src;
    uint4 a1 = *(const uint4*)(src + 8);
    *(uint4*)&Ts[r][cc]     = a0;
    *(uint4*)&Ts[r][cc + 8] = a1;
    __syncthreads();
    ushort tmp[16];
    #pragma unroll
    for (int j = 0; j < 16; ++j) tmp[j] = Ts[cc + j][r];
    ushort* dst = vt + ((size_t)(bh * kHd) + d0 + r) * kS + s0 + cc;
    *(uint4*)dst       = *(uint4*)&tmp[0];
    *(uint4*)(dst + 8) = *(uint4*)&tmp[8];
}

// ---------------------------------------------------------------------------
// RMSNorm + RoPE on q/k sections of fused qkv. 192 thr, 8 elems each.
// ---------------------------------------------------------------------------
__global__ __launch_bounds__(192)
void rmsrope_kernel(ushort* __restrict__ qkv,
                    const float* __restrict__ gq, const float* __restrict__ gk,
                    const float* __restrict__ freqs, const int* __restrict__ grid_sizes)
{
    __shared__ float red[4];
    const int row   = blockIdx.x;
    const int which = blockIdx.y;
    ushort* ptr = qkv + (size_t)row * kQKV + which * kDim;
    const float* g = which ? gk : gq;
    const float outmul = which ? 1.0f : kQMul;
    const int t = threadIdx.x;

    uint4 raw = ((const uint4*)ptr)[t];
    float v[8];
    v[0] = bf2f(raw.x & 0xffff); v[1] = bf2f(raw.x >> 16);
    v[2] = bf2f(raw.y & 0xffff); v[3] = bf2f(raw.y >> 16);
    v[4] = bf2f(raw.z & 0xffff); v[5] = bf2f(raw.z >> 16);
    v[6] = bf2f(raw.w & 0xffff); v[7] = bf2f(raw.w >> 16);

    float ss = 0.f;
    #pragma unroll
    for (int i = 0; i < 8; ++i) ss += v[i] * v[i];
    #pragma unroll
    for (int off = 32; off >= 1; off >>= 1) ss += __shfl_xor(ss, off);
    if ((t & 63) == 0) red[t >> 6] = ss;
    __syncthreads();
    const float scale = rsqrtf((red[0] + red[1] + red[2]) * (1.f / kDim) + kEps);

    const int b = row / kS, s = row % kS;
    const int gh = grid_sizes[b*3 + 1], gw = grid_sizes[b*3 + 2];
    const int hw  = gh * gw;
    const int fi  = s / hw;
    const int rem = s - fi * hw;
    const int hi  = rem / gw;
    const int wi  = rem - hi * gw;

    const float4 g0 = *(const float4*)(g + t*8);
    const float4 g1 = *(const float4*)(g + t*8 + 4);
    const float gv[8] = {g0.x, g0.y, g0.z, g0.w, g1.x, g1.y, g1.z, g1.w};

    uint32_t out[4];
    #pragma unroll
    for (int jj = 0; jj < 4; ++jj) {
        const int p = t*4 + jj;
        const int c = p & 63;
        const int pos = (c < 22) ? fi : (c < 43 ? hi : wi);
        const float ang = freqs[pos * 64 + c];
        float sn, cs;
        sincosf(ang, &sn, &cs);
        const float e0 = v[2*jj]   * scale * gv[2*jj];
        const float e1 = v[2*jj+1] * scale * gv[2*jj+1];
        const float o0 = (e0 * cs - e1 * sn) * outmul;
        const float o1 = (e0 * sn + e1 * cs) * outmul;
        out[jj] = (uint32_t)f2bf(o0) | ((uint32_t)f2bf(o1) << 16);
    }
    uint4 ov; ov.x = out[0]; ov.y = out[1]; ov.z = out[2]; ov.w = out[3];
    ((uint4*)ptr)[t] = ov;
}

// ---------------------------------------------------------------------------
// Flash attention, split-K (2 halves), swapped-QK^T 32x32x16 MFMA.
// r14 deltas vs r10 (both derivation-locked, math-identical):
//  * K LDS swizzle widened to 4 row bits: col ^ ((row&15)<<3). Bijective on
//    128-elem rows (staging rows srow+16c have row&15==srow; read rows
//    hb*32+l31 have row&15==l31&15). Kills the {x,x+8,x+16,x+24} 4-way
//    bank aliasing of the 3-bit form -> 2-way (free).
//  * Merged P-exchange: each lane needs only 4 partner words, so send
//    m = hi ? u[low-pair] : u[high-pair]; one shfl serves both halves.
//    8 shfl -> 4 shfl + 4 cndmask per 32-key half (verified vs the
//    r5-proven select table for both hi cases).
// ---------------------------------------------------------------------------
__global__ __launch_bounds__(256, 3)
void attn_kernel(const ushort* __restrict__ qkv, const ushort* __restrict__ vtb,
                 ushort* __restrict__ pA, ushort* __restrict__ pB,
                 float* __restrict__ ml, const int* __restrict__ seq_lens)
{
    __shared__ ushort Ks[64 * 128];
    __shared__ ushort VT[128 * 64];

    // bijective XCD remap: consecutive logical ids (sharing (h,b) K/V) land on
    // the same XCD's L2.  1152 % 8 == 0 -> L = (lin&7)*144 + (lin>>3).
    const int lin = blockIdx.x;
    const int L   = (lin & 7) * 144 + (lin >> 3);
    const int bh   = L / 48;
    const int rem  = L - bh * 48;
    const int half = rem / 24;
    const int qtile= rem - half * 24;
    const int h = bh % kHeads, b = bh / kHeads;
    const int seq = seq_lens[b];
    const int kbeg = half * (kS / 2);

    const int t = threadIdx.x, lane = t & 63, w = t >> 6;
    const int l31 = lane & 31, hi = lane >> 5;
    const int qrow = qtile * 128 + w * 32 + l31;

    const ushort* qbase = qkv + ((size_t)b * kS) * kQKV + h * kHd;
    const ushort* kbase = qkv + ((size_t)b * kS) * kQKV + kDim + h * kHd;
    const ushort* vtbase = vtb + ((size_t)(b * kHeads + h) * kHd) * kS;

    // Q fragments (B-operand): qf[kb][j] = Q[qrow][kb*16 + hi*8 + j]
    short8 qf[8];
    #pragma unroll
    for (int kb = 0; kb < 8; ++kb)
        qf[kb] = *(const short8*)(qbase + (size_t)qrow * kQKV + kb*16 + hi*8);

    f32x16 oacc[4];
    #pragma unroll
    for (int n = 0; n < 4; ++n)
        #pragma unroll
        for (int i = 0; i < 16; ++i) oacc[n][i] = 0.f;

    float m_run = -1e30f, l_run = 0.f;

    const int srow = t >> 4;                      // 0..15
    const int scol = (t & 15) * 8;
    const int kl   = scol ^ (srow << 3);          // 4-bit pre-swizzled K source col
    const int vd0  = t >> 3;                      // 0..31
    const int vscol = ((t & 7) * 8) ^ ((vd0 & 7) << 3);  // pre-swizzled V^T col (3-bit, 64-wide rows)

    for (int kt = 0; kt < kS/2; kt += 64) {
        const int k0 = kbeg + kt;
        __syncthreads();
        #pragma unroll
        for (int c = 0; c < 4; ++c) {
            gload_lds16(kbase + (size_t)(k0 + srow + c*16) * kQKV + kl, &Ks[t*8 + c*2048]);
            gload_lds16(vtbase + (size_t)(vd0 + c*32) * kS + k0 + vscol, &VT[t*8 + c*2048]);
        }
        __syncthreads();

        // ---- two sequential 32-key halves (register-lean) ----
        #pragma unroll
        for (int hb = 0; hb < 2; ++hb) {
            // S^T = K . Q^T for rows hb*32 + l31; reg r -> key (r&3)+8*(r>>2)+4*hi
            f32x16 s;
            #pragma unroll
            for (int i = 0; i < 16; ++i) s[i] = 0.f;
            __builtin_amdgcn_s_setprio(1);
            #pragma unroll
            for (int kb = 0; kb < 8; ++kb) {
                const int col = (kb*16 + hi*8) ^ ((l31 & 15) << 3);
                short8 kf = *(const short8*)&Ks[(hb*32 + l31) * 128 + col];
                s = __builtin_amdgcn_mfma_f32_32x32x16_bf16(kf, qf[kb], s, 0, 0, 0);
            }
            __builtin_amdgcn_s_setprio(0);

            // mask + half max (scores already in log2 domain via kQMul)
            const int kb0 = k0 + hb*32;
            float mx = -1e30f;
            if (kb0 + 32 > seq) {
                #pragma unroll
                for (int r = 0; r < 16; ++r) {
                    if (kb0 + (r&3) + 8*(r>>2) + 4*hi >= seq) s[r] = -1e30f;
                    mx = fmaxf(mx, s[r]);
                }
            } else {
                #pragma unroll
                for (int r = 0; r < 16; ++r) mx = fmaxf(mx, s[r]);
            }
            mx = fmaxf(mx, __shfl_xor(mx, 32));

            // defer-max online softmax (T13)
            const bool skip = (mx <= m_run + 11.0f);
            if (!__all(skip)) {
                const float mnew = fmaxf(m_run, mx);
                const float alpha = exp2f(m_run - mnew);
                m_run = mnew;
                l_run *= alpha;
                #pragma unroll
                for (int r = 0; r < 16; ++r) {
                    const float ar = __shfl(alpha, (r&3) + 8*(r>>2) + 4*hi);
                    #pragma unroll
                    for (int n = 0; n < 4; ++n) oacc[n][r] *= ar;
                }
            }

            float rs = 0.f;
            #pragma unroll
            for (int r = 0; r < 16; ++r) {
                s[r] = exp2f(s[r] - m_run);
                rs += s[r];
            }
            rs += __shfl_xor(rs, 32);
            l_run += rs;

            // pack P -> bf16 dwords (cvt_pk); merged half-exchange:
            // send what the partner needs -> 4 shfl instead of 8.
            uint32_t u[8];
            #pragma unroll
            for (int i = 0; i < 8; ++i) u[i] = cvtpk_bf16(s[2*i], s[2*i+1]);
            uint32_t m0 = hi ? u[0] : u[2];
            uint32_t m1 = hi ? u[1] : u[3];
            uint32_t m2 = hi ? u[4] : u[6];
            uint32_t m3 = hi ? u[5] : u[7];
            const uint32_t wm0 = __shfl_xor(m0, 32);
            const uint32_t wm1 = __shfl_xor(m1, 32);
            const uint32_t wm2 = __shfl_xor(m2, 32);
            const uint32_t wm3 = __shfl_xor(m3, 32);
            union PF { uint32_t d[4]; short8 s8; };
            PF pa0, pa1;
            pa0.d[0] = hi ? wm0 : u[0];  pa0.d[1] = hi ? wm1 : u[1];
            pa0.d[2] = hi ? u[2] : wm0;  pa0.d[3] = hi ? u[3] : wm1;
            pa1.d[0] = hi ? wm2 : u[4];  pa1.d[1] = hi ? wm3 : u[5];
            pa1.d[2] = hi ? u[6] : wm2;  pa1.d[3] = hi ? u[7] : wm3;

            // PV for this half: k-slots hb*2 + {0,1}
            __builtin_amdgcn_s_setprio(1);
            #pragma unroll
            for (int kss = 0; kss < 2; ++kss) {
                const int ks = hb*2 + kss;
                #pragma unroll
                for (int n = 0; n < 4; ++n) {
                    const int d = n*32 + l31;
                    const int colv = (ks*16 + hi*8) ^ ((l31 & 7) << 3);
                    short8 vf = *(const short8*)&VT[d * 64 + colv];
                    oacc[n] = __builtin_amdgcn_mfma_f32_32x32x16_bf16(
                        (kss ? pa1 : pa0).s8, vf, oacc[n], 0, 0, 0);
                }
            }
            __builtin_amdgcn_s_setprio(0);
        }
    }

    // ---- epilogue: partial O' = O~/l (bf16) + per-row (m,l) ----
    ushort* pOut = half ? pB : pA;
    const float linv = 1.f / l_run;
    #pragma unroll
    for (int r = 0; r < 16; ++r) {
        const int qr = (r&3) + 8*(r>>2) + 4*hi;
        const float lr = __shfl(linv, qr);
        const size_t row = (size_t)(b * kS) + qtile * 128 + w * 32 + qr;
        #pragma unroll
        for (int n = 0; n < 4; ++n)
            pOut[row * kDim + h * kHd + n*32 + l31] = f2bf(oacc[n][r] * lr);
    }
    if (lane < 32) {
        const int s = qtile * 128 + w * 32 + l31;
        const size_t idx = ((((size_t)(b * kHeads + h)) * 2 + half) * kS + s) * 2;
        ml[idx]     = m_run;
        ml[idx + 1] = l_run;
    }
}

// ---------------------------------------------------------------------------
// Combine split-K partials: O = (a0*O'0 + a1*O'1)/(a0+a1), a_i = l_i*2^(m_i-m)
// ---------------------------------------------------------------------------
__global__ __launch_bounds__(256)
void combine_kernel(const ushort* __restrict__ pA, const ushort* __restrict__ pB,
                    const float* __restrict__ ml, ushort* __restrict__ out, int n8)
{
    int i = blockIdx.x * 256 + threadIdx.x;
    if (i >= n8) return;
    const int row = i / 192;               // 192 = kDim/8
    const int within = (i - row * 192) * 8;
    const int h = within >> 7;
    const int b = row / kS;
    const int s = row - b * kS;
    const size_t base = (((size_t)(b * kHeads + h)) * 2) * kS;
    const float m0 = ml[(base + s) * 2],        l0 = ml[(base + s) * 2 + 1];
    const float m1 = ml[(base + kS + s) * 2],   l1 = ml[(base + kS + s) * 2 + 1];
    const float m  = fmaxf(m0, m1);
    const float a0 = l0 * exp2f(m0 - m);
    const float a1 = l1 * exp2f(m1 - m);
    const float inv = 1.f / (a0 + a1);
    const float f0 = a0 * inv, f1 = a1 * inv;

    uint4 ua = ((const uint4*)pA)[i];
    uint4 ub = ((const uint4*)pB)[i];
    const uint32_t* da = (const uint32_t*)&ua;
    const uint32_t* db = (const uint32_t*)&ub;
    uint32_t rv[4];
    #pragma unroll
    for (int j = 0; j < 4; ++j) {
        float o0 = f0 * bf2f(da[j] & 0xffff) + f1 * bf2f(db[j] & 0xffff);
        float o1 = f0 * bf2f(da[j] >> 16)    + f1 * bf2f(db[j] >> 16);
        rv[j] = (uint32_t)f2bf(o0) | ((uint32_t)f2bf(o1) << 16);
    }
    uint4 r; r.x = rv[0]; r.y = rv[1]; r.z = rv[2]; r.w = rv[3];
    ((uint4*)out)[i] = r;
}

// ---------------------------------------------------------------------------
extern "C" void kernel_launch(void* const* d_in, const int* in_sizes, int n_in,
                              void* d_out, int out_size, void* d_ws, size_t ws_size,
                              hipStream_t stream)
{
    (void)in_sizes; (void)n_in; (void)out_size; (void)ws_size;
    const float* x          = (const float*)d_in[0];
    const int*   seq_lens   = (const int*)  d_in[1];
    const int*   grid_sizes = (const int*)  d_in[2];
    const float* freqs      = (const float*)d_in[3];
    const float* Wq = (const float*)d_in[4];
    const float* bq = (const float*)d_in[5];
    const float* Wk = (const float*)d_in[6];
    const float* bk = (const float*)d_in[7];
    const float* Wv = (const float*)d_in[8];
    const float* bv = (const float*)d_in[9];
    const float* Wo = (const float*)d_in[10];
    const float* bo = (const float*)d_in[11];
    const float* gq = (const float*)d_in[12];
    const float* gk = (const float*)d_in[13];
    float* out = (float*)d_out;

    const int M = kB * kS;                       // 6144
    const size_t szX = (size_t)M * kDim;         // 9.44M elems
    const size_t szW = (size_t)kDim * kDim;

    ushort* xb   = (ushort*)d_ws;                // GEMM-A input, then partial A
    ushort* wqb  = xb   + szX;                   // wq|wk|wv contiguous = fused B
    ushort* wkb  = wqb  + szW;
    ushort* wvb  = wkb  + szW;
    ushort* wob  = wvb  + szW;
    ushort* qkvb = wob  + szW;                   // [6144][4608]
    ushort* ab   = qkvb + 3*szX;
    ushort* vtb  = ab   + szX;
    ushort* pBuf = vtb  + szX;                   // partial B (bf16, szX)
    float*  biasqkv = (float*)(pBuf + szX);      // 4608 f32
    float*  ml   = biasqkv + kQKV;               // 2*12*2*3072*2 f32

    dim3 blk(256);
    cvt_kernel<<<dim3((int)(szX/8/256)), blk, 0, stream>>>(x, xb, (int)(szX/8));
    cvt4_kernel<<<dim3((int)(szW/8/256), 4), blk, 0, stream>>>(
        Wq, Wk, Wv, Wo, wqb, wkb, wvb, wob, (int)(szW/8));
    biascat_kernel<<<dim3(18), blk, 0, stream>>>(bq, bk, bv, biasqkv);

    // fused QKV projection: N = 4608
    gemm_bf16<ushort><<<dim3(kQKV/128, M/128), blk, 0, stream>>>(
        xb, wqb, biasqkv, qkvb, M, kQKV, kDim);

    rmsrope_kernel<<<dim3(M, 2), dim3(192), 0, stream>>>(qkvb, gq, gk, freqs, grid_sizes);
    vtrans_kernel<<<dim3(kS/64, 2, kB*kHeads), blk, 0, stream>>>(qkvb, vtb);

    // split-K flash attention: 48 x 24 = 1152 blocks (xb reused as partial A)
    attn_kernel<<<dim3(48 * kHeads * kB), blk, 0, stream>>>(
        qkvb, vtb, xb, pBuf, ml, seq_lens);
    combine_kernel<<<dim3((int)(szX/8/256)), blk, 0, stream>>>(
        xb, pBuf, ml, ab, (int)(szX/8));

    gemm_bf16<float><<<dim3(kDim/128, M/128), blk, 0, stream>>>(
        ab, wob, bo, out, M, kDim, kDim);
}

// Round 15
// 414.989 us; speedup vs baseline: 1.0527x; 1.0083x over previous
//
#include <hip/hip_runtime.h>
#include <hip/hip_bf16.h>
#include <stdint.h>

typedef __attribute__((ext_vector_type(8))) short short8;
typedef __attribute__((ext_vector_type(4))) float f32x4;
typedef __attribute__((ext_vector_type(16))) float f32x16;

constexpr int kDim   = 1536;
constexpr int kHeads = 12;
constexpr int kHd    = 128;
constexpr int kS     = 3072;
constexpr int kB     = 2;
constexpr int kQKV   = 3 * kDim;               // 4608 fused row width
constexpr float kEps   = 1e-6f;
constexpr float kQMul  = 0.08838834764831845f * 1.44269504089f; // 1/sqrt(128)*log2(e)

__device__ __forceinline__ ushort f2bf(float f) {
    union { float f; uint32_t u; } c; c.f = f;
    uint32_t u = c.u;
    return (ushort)((u + 0x7fffu + ((u >> 16) & 1u)) >> 16);
}
__device__ __forceinline__ float bf2f(uint32_t h) {
    union { uint32_t u; float f; } c; c.u = h << 16;
    return c.f;
}
__device__ __forceinline__ void gload_lds16(const void* g, void* l) {
    __builtin_amdgcn_global_load_lds((const __attribute__((address_space(1))) void*)g,
                                     (__attribute__((address_space(3))) void*)l, 16, 0, 0);
}
__device__ __forceinline__ uint32_t cvtpk_bf16(float lo, float hi) {
    uint32_t r;
    asm("v_cvt_pk_bf16_f32 %0, %1, %2" : "=v"(r) : "v"(lo), "v"(hi));
    return r;
}

// ---------------------------------------------------------------------------
// fp32 -> bf16 convert, 8 elems/thread
// ---------------------------------------------------------------------------
__global__ __launch_bounds__(256)
void cvt_kernel(const float* __restrict__ in, ushort* __restrict__ out, int n8)
{
    int i = blockIdx.x * 256 + threadIdx.x;
    if (i >= n8) return;
    const float4* p = (const float4*)in + (size_t)i * 2;
    float4 a = p[0], b = p[1];
    uint4 r;
    r.x = (uint32_t)f2bf(a.x) | ((uint32_t)f2bf(a.y) << 16);
    r.y = (uint32_t)f2bf(a.z) | ((uint32_t)f2bf(a.w) << 16);
    r.z = (uint32_t)f2bf(b.x) | ((uint32_t)f2bf(b.y) << 16);
    r.w = (uint32_t)f2bf(b.z) | ((uint32_t)f2bf(b.w) << 16);
    ((uint4*)out)[i] = r;
}

// 4 weight tensors in one dispatch (blockIdx.y selects)
__global__ __launch_bounds__(256)
void cvt4_kernel(const float* __restrict__ s0, const float* __restrict__ s1,
                 const float* __restrict__ s2, const float* __restrict__ s3,
                 ushort* __restrict__ d0, ushort* __restrict__ d1,
                 ushort* __restrict__ d2, ushort* __restrict__ d3, int n8)
{
    int i = blockIdx.x * 256 + threadIdx.x;
    if (i >= n8) return;
    const float* in; ushort* out;
    switch (blockIdx.y) {
        case 0: in = s0; out = d0; break;
        case 1: in = s1; out = d1; break;
        case 2: in = s2; out = d2; break;
        default: in = s3; out = d3; break;
    }
    const float4* p = (const float4*)in + (size_t)i * 2;
    float4 a = p[0], b = p[1];
    uint4 r;
    r.x = (uint32_t)f2bf(a.x) | ((uint32_t)f2bf(a.y) << 16);
    r.y = (uint32_t)f2bf(a.z) | ((uint32_t)f2bf(a.w) << 16);
    r.z = (uint32_t)f2bf(b.x) | ((uint32_t)f2bf(b.y) << 16);
    r.w = (uint32_t)f2bf(b.z) | ((uint32_t)f2bf(b.w) << 16);
    ((uint4*)out)[i] = r;
}

// concat bq|bk|bv -> biasqkv[4608]
__global__ __launch_bounds__(256)
void biascat_kernel(const float* __restrict__ bq, const float* __restrict__ bk,
                    const float* __restrict__ bv, float* __restrict__ out)
{
    int i = blockIdx.x * 256 + threadIdx.x;
    if (i >= kQKV) return;
    float v = (i < kDim) ? bq[i] : (i < 2*kDim) ? bk[i - kDim] : bv[i - 2*kDim];
    out[i] = v;
}

// ---------------------------------------------------------------------------
// bf16 MFMA GEMM: C[M][N] = A[M][K] @ B[N][K]^T + bias   (m97-style 128^2, BK=32)
// ---------------------------------------------------------------------------
template<typename OutT>
__global__ __launch_bounds__(256)
void gemm_bf16(const ushort* __restrict__ A, const ushort* __restrict__ B,
               const float* __restrict__ bias, OutT* __restrict__ C,
               int M, int N, int K)
{
    __shared__ ushort As[128 * 32];
    __shared__ ushort Bs[128 * 32];
    const int t    = threadIdx.x;
    const int lane = t & 63;
    const int w    = t >> 6;
    const int wm = (w >> 1) * 64, wn = (w & 1) * 64;
    const int m0 = blockIdx.y * 128, n0 = blockIdx.x * 128;

    const int srow = t >> 2;
    const int skc  = (t & 3) * 8;
    const ushort* Ag = A + (size_t)(m0 + srow) * K + skc;
    const ushort* Bg = B + (size_t)(n0 + srow) * K + skc;
    const size_t half = (size_t)64 * K;

    f32x4 acc[4][4];
    #pragma unroll
    for (int m = 0; m < 4; ++m)
        #pragma unroll
        for (int n = 0; n < 4; ++n)
            #pragma unroll
            for (int i = 0; i < 4; ++i) acc[m][n][i] = 0.f;

    const int kk  = (lane >> 4) * 8;
    const int l15 = lane & 15;

    for (int k0 = 0; k0 < K; k0 += 32) {
        __syncthreads();
        gload_lds16(Ag + k0,        &As[t * 8]);
        gload_lds16(Ag + half + k0, &As[t * 8 + 2048]);
        gload_lds16(Bg + k0,        &Bs[t * 8]);
        gload_lds16(Bg + half + k0, &Bs[t * 8 + 2048]);
        __syncthreads();
        short8 af[4], bf[4];
        #pragma unroll
        for (int m = 0; m < 4; ++m) af[m] = *(const short8*)&As[(wm + m*16 + l15) * 32 + kk];
        #pragma unroll
        for (int n = 0; n < 4; ++n) bf[n] = *(const short8*)&Bs[(wn + n*16 + l15) * 32 + kk];
        #pragma unroll
        for (int m = 0; m < 4; ++m)
            #pragma unroll
            for (int n = 0; n < 4; ++n)
                acc[m][n] = __builtin_amdgcn_mfma_f32_16x16x32_bf16(af[m], bf[n], acc[m][n], 0, 0, 0);
    }

    const int r0 = (lane >> 4) * 4;
    #pragma unroll
    for (int m = 0; m < 4; ++m) {
        #pragma unroll
        for (int r = 0; r < 4; ++r) {
            const size_t row = (size_t)(m0 + wm + m*16 + r0 + r);
            #pragma unroll
            for (int n = 0; n < 4; ++n) {
                const int col = n0 + wn + n*16 + l15;
                float val = acc[m][n][r] + bias[col];
                if constexpr (sizeof(OutT) == 4) C[row * N + col] = val;
                else                             C[row * N + col] = f2bf(val);
            }
        }
    }
}

// ---------------------------------------------------------------------------
// V transpose from fused qkv: vt[b][h][d][s] = qkv[b][s][3072 + h*128 + d]
// ---------------------------------------------------------------------------
__global__ __launch_bounds__(256)
void vtrans_kernel(const ushort* __restrict__ qkv, ushort* __restrict__ vt)
{
    __shared__ ushort Ts[64][72];
    const int t  = threadIdx.x;
    const int s0 = blockIdx.x * 64;
    const int d0 = blockIdx.y * 64;
    const int bh = blockIdx.z;
    const int b = bh / kHeads, h = bh % kHeads;

    const int r = t >> 2, cc = (t & 3) * 16;
    const ushort* src = qkv + ((size_t)(b * kS) + s0 + r) * kQKV + 2*kDim + h * kHd + d0 + cc;
    uint4 a0 = *(const uint4*)src;
    uint4 a1 = *(const uint4*)(src + 8);
    *(uint4*)&Ts[r][cc]     = a0;
    *(uint4*)&Ts[r][cc + 8] = a1;
    __syncthreads();
    ushort tmp[16];
    #pragma unroll
    for (int j = 0; j < 16; ++j) tmp[j] = Ts[cc + j][r];
    ushort* dst = vt + ((size_t)(bh * kHd) + d0 + r) * kS + s0 + cc;
    *(uint4*)dst       = *(uint4*)&tmp[0];
    *(uint4*)(dst + 8) = *(uint4*)&tmp[8];
}

// ---------------------------------------------------------------------------
// RMSNorm + RoPE on q/k sections of fused qkv. 192 thr, 8 elems each.
// ---------------------------------------------------------------------------
__global__ __launch_bounds__(192)
void rmsrope_kernel(ushort* __restrict__ qkv,
                    const float* __restrict__ gq, const float* __restrict__ gk,
                    const float* __restrict__ freqs, const int* __restrict__ grid_sizes)
{
    __shared__ float red[4];
    const int row   = blockIdx.x;
    const int which = blockIdx.y;
    ushort* ptr = qkv + (size_t)row * kQKV + which * kDim;
    const float* g = which ? gk : gq;
    const float outmul = which ? 1.0f : kQMul;
    const int t = threadIdx.x;

    uint4 raw = ((const uint4*)ptr)[t];
    float v[8];
    v[0] = bf2f(raw.x & 0xffff); v[1] = bf2f(raw.x >> 16);
    v[2] = bf2f(raw.y & 0xffff); v[3] = bf2f(raw.y >> 16);
    v[4] = bf2f(raw.z & 0xffff); v[5] = bf2f(raw.z >> 16);
    v[6] = bf2f(raw.w & 0xffff); v[7] = bf2f(raw.w >> 16);

    float ss = 0.f;
    #pragma unroll
    for (int i = 0; i < 8; ++i) ss += v[i] * v[i];
    #pragma unroll
    for (int off = 32; off >= 1; off >>= 1) ss += __shfl_xor(ss, off);
    if ((t & 63) == 0) red[t >> 6] = ss;
    __syncthreads();
    const float scale = rsqrtf((red[0] + red[1] + red[2]) * (1.f / kDim) + kEps);

    const int b = row / kS, s = row % kS;
    const int gh = grid_sizes[b*3 + 1], gw = grid_sizes[b*3 + 2];
    const int hw  = gh * gw;
    const int fi  = s / hw;
    const int rem = s - fi * hw;
    const int hi  = rem / gw;
    const int wi  = rem - hi * gw;

    const float4 g0 = *(const float4*)(g + t*8);
    const float4 g1 = *(const float4*)(g + t*8 + 4);
    const float gv[8] = {g0.x, g0.y, g0.z, g0.w, g1.x, g1.y, g1.z, g1.w};

    uint32_t out[4];
    #pragma unroll
    for (int jj = 0; jj < 4; ++jj) {
        const int p = t*4 + jj;
        const int c = p & 63;
        const int pos = (c < 22) ? fi : (c < 43 ? hi : wi);
        const float ang = freqs[pos * 64 + c];
        float sn, cs;
        sincosf(ang, &sn, &cs);
        const float e0 = v[2*jj]   * scale * gv[2*jj];
        const float e1 = v[2*jj+1] * scale * gv[2*jj+1];
        const float o0 = (e0 * cs - e1 * sn) * outmul;
        const float o1 = (e0 * sn + e1 * cs) * outmul;
        out[jj] = (uint32_t)f2bf(o0) | ((uint32_t)f2bf(o1) << 16);
    }
    uint4 ov; ov.x = out[0]; ov.y = out[1]; ov.z = out[2]; ov.w = out[3];
    ((uint4*)ptr)[t] = ov;
}

// ---------------------------------------------------------------------------
// Flash attention, split-K (2 halves), swapped-QK^T 32x32x16 MFMA.
// r15 delta vs r14: tree-structured mx (v_max3-fusable triples, depth 3-4
// vs serial 16) and rs (pairwise add tree, depth 4 vs serial 16) — both on
// the softmax critical path before __all(skip)/pack.
// ---------------------------------------------------------------------------
__global__ __launch_bounds__(256, 3)
void attn_kernel(const ushort* __restrict__ qkv, const ushort* __restrict__ vtb,
                 ushort* __restrict__ pA, ushort* __restrict__ pB,
                 float* __restrict__ ml, const int* __restrict__ seq_lens)
{
    __shared__ ushort Ks[64 * 128];
    __shared__ ushort VT[128 * 64];

    // bijective XCD remap: consecutive logical ids (sharing (h,b) K/V) land on
    // the same XCD's L2.  1152 % 8 == 0 -> L = (lin&7)*144 + (lin>>3).
    const int lin = blockIdx.x;
    const int L   = (lin & 7) * 144 + (lin >> 3);
    const int bh   = L / 48;
    const int rem  = L - bh * 48;
    const int half = rem / 24;
    const int qtile= rem - half * 24;
    const int h = bh % kHeads, b = bh / kHeads;
    const int seq = seq_lens[b];
    const int kbeg = half * (kS / 2);

    const int t = threadIdx.x, lane = t & 63, w = t >> 6;
    const int l31 = lane & 31, hi = lane >> 5;
    const int qrow = qtile * 128 + w * 32 + l31;

    const ushort* qbase = qkv + ((size_t)b * kS) * kQKV + h * kHd;
    const ushort* kbase = qkv + ((size_t)b * kS) * kQKV + kDim + h * kHd;
    const ushort* vtbase = vtb + ((size_t)(b * kHeads + h) * kHd) * kS;

    // Q fragments (B-operand): qf[kb][j] = Q[qrow][kb*16 + hi*8 + j]
    short8 qf[8];
    #pragma unroll
    for (int kb = 0; kb < 8; ++kb)
        qf[kb] = *(const short8*)(qbase + (size_t)qrow * kQKV + kb*16 + hi*8);

    f32x16 oacc[4];
    #pragma unroll
    for (int n = 0; n < 4; ++n)
        #pragma unroll
        for (int i = 0; i < 16; ++i) oacc[n][i] = 0.f;

    float m_run = -1e30f, l_run = 0.f;

    const int srow = t >> 4;                      // 0..15
    const int scol = (t & 15) * 8;
    const int kl   = scol ^ (srow << 3);          // 4-bit pre-swizzled K source col
    const int vd0  = t >> 3;                      // 0..31
    const int vscol = ((t & 7) * 8) ^ ((vd0 & 7) << 3);  // pre-swizzled V^T col (3-bit, 64-wide rows)

    for (int kt = 0; kt < kS/2; kt += 64) {
        const int k0 = kbeg + kt;
        __syncthreads();
        #pragma unroll
        for (int c = 0; c < 4; ++c) {
            gload_lds16(kbase + (size_t)(k0 + srow + c*16) * kQKV + kl, &Ks[t*8 + c*2048]);
            gload_lds16(vtbase + (size_t)(vd0 + c*32) * kS + k0 + vscol, &VT[t*8 + c*2048]);
        }
        __syncthreads();

        // ---- two sequential 32-key halves (register-lean) ----
        #pragma unroll
        for (int hb = 0; hb < 2; ++hb) {
            // S^T = K . Q^T for rows hb*32 + l31; reg r -> key (r&3)+8*(r>>2)+4*hi
            f32x16 s;
            #pragma unroll
            for (int i = 0; i < 16; ++i) s[i] = 0.f;
            __builtin_amdgcn_s_setprio(1);
            #pragma unroll
            for (int kb = 0; kb < 8; ++kb) {
                const int col = (kb*16 + hi*8) ^ ((l31 & 15) << 3);
                short8 kf = *(const short8*)&Ks[(hb*32 + l31) * 128 + col];
                s = __builtin_amdgcn_mfma_f32_32x32x16_bf16(kf, qf[kb], s, 0, 0, 0);
            }
            __builtin_amdgcn_s_setprio(0);

            // mask (scores already in log2 domain via kQMul)
            const int kb0 = k0 + hb*32;
            if (kb0 + 32 > seq) {
                #pragma unroll
                for (int r = 0; r < 16; ++r)
                    if (kb0 + (r&3) + 8*(r>>2) + 4*hi >= seq) s[r] = -1e30f;
            }
            // tree max (v_max3-fusable triples, depth 3-4)
            const float a0 = fmaxf(fmaxf(s[0],  s[1]),  s[2]);
            const float a1 = fmaxf(fmaxf(s[3],  s[4]),  s[5]);
            const float a2 = fmaxf(fmaxf(s[6],  s[7]),  s[8]);
            const float a3 = fmaxf(fmaxf(s[9],  s[10]), s[11]);
            const float a4 = fmaxf(fmaxf(s[12], s[13]), s[14]);
            const float b0 = fmaxf(fmaxf(a0, a1), a2);
            const float b1 = fmaxf(fmaxf(a3, a4), s[15]);
            float mx = fmaxf(b0, b1);
            mx = fmaxf(mx, __shfl_xor(mx, 32));

            // defer-max online softmax (T13)
            const bool skip = (mx <= m_run + 11.0f);
            if (!__all(skip)) {
                const float mnew = fmaxf(m_run, mx);
                const float alpha = exp2f(m_run - mnew);
                m_run = mnew;
                l_run *= alpha;
                #pragma unroll
                for (int r = 0; r < 16; ++r) {
                    const float ar = __shfl(alpha, (r&3) + 8*(r>>2) + 4*hi);
                    #pragma unroll
                    for (int n = 0; n < 4; ++n) oacc[n][r] *= ar;
                }
            }

            #pragma unroll
            for (int r = 0; r < 16; ++r) s[r] = exp2f(s[r] - m_run);
            // pairwise add tree (depth 4)
            const float t0 = (s[0] + s[1]) + (s[2]  + s[3]);
            const float t1 = (s[4] + s[5]) + (s[6]  + s[7]);
            const float t2 = (s[8] + s[9]) + (s[10] + s[11]);
            const float t3 = (s[12]+ s[13])+ (s[14] + s[15]);
            float rs = (t0 + t1) + (t2 + t3);
            rs += __shfl_xor(rs, 32);
            l_run += rs;

            // pack P -> bf16 dwords (cvt_pk); merged half-exchange:
            // send what the partner needs -> 4 shfl instead of 8.
            uint32_t u[8];
            #pragma unroll
            for (int i = 0; i < 8; ++i) u[i] = cvtpk_bf16(s[2*i], s[2*i+1]);
            uint32_t m0 = hi ? u[0] : u[2];
            uint32_t m1 = hi ? u[1] : u[3];
            uint32_t m2 = hi ? u[4] : u[6];
            uint32_t m3 = hi ? u[5] : u[7];
            const uint32_t wm0 = __shfl_xor(m0, 32);
            const uint32_t wm1 = __shfl_xor(m1, 32);
            const uint32_t wm2 = __shfl_xor(m2, 32);
            const uint32_t wm3 = __shfl_xor(m3, 32);
            union PF { uint32_t d[4]; short8 s8; };
            PF pa0, pa1;
            pa0.d[0] = hi ? wm0 : u[0];  pa0.d[1] = hi ? wm1 : u[1];
            pa0.d[2] = hi ? u[2] : wm0;  pa0.d[3] = hi ? u[3] : wm1;
            pa1.d[0] = hi ? wm2 : u[4];  pa1.d[1] = hi ? wm3 : u[5];
            pa1.d[2] = hi ? u[6] : wm2;  pa1.d[3] = hi ? u[7] : wm3;

            // PV for this half: k-slots hb*2 + {0,1}
            __builtin_amdgcn_s_setprio(1);
            #pragma unroll
            for (int kss = 0; kss < 2; ++kss) {
                const int ks = hb*2 + kss;
                #pragma unroll
                for (int n = 0; n < 4; ++n) {
                    const int d = n*32 + l31;
                    const int colv = (ks*16 + hi*8) ^ ((l31 & 7) << 3);
                    short8 vf = *(const short8*)&VT[d * 64 + colv];
                    oacc[n] = __builtin_amdgcn_mfma_f32_32x32x16_bf16(
                        (kss ? pa1 : pa0).s8, vf, oacc[n], 0, 0, 0);
                }
            }
            __builtin_amdgcn_s_setprio(0);
        }
    }

    // ---- epilogue: partial O' = O~/l (bf16) + per-row (m,l) ----
    ushort* pOut = half ? pB : pA;
    const float linv = 1.f / l_run;
    #pragma unroll
    for (int r = 0; r < 16; ++r) {
        const int qr = (r&3) + 8*(r>>2) + 4*hi;
        const float lr = __shfl(linv, qr);
        const size_t row = (size_t)(b * kS) + qtile * 128 + w * 32 + qr;
        #pragma unroll
        for (int n = 0; n < 4; ++n)
            pOut[row * kDim + h * kHd + n*32 + l31] = f2bf(oacc[n][r] * lr);
    }
    if (lane < 32) {
        const int s = qtile * 128 + w * 32 + l31;
        const size_t idx = ((((size_t)(b * kHeads + h)) * 2 + half) * kS + s) * 2;
        ml[idx]     = m_run;
        ml[idx + 1] = l_run;
    }
}

// ---------------------------------------------------------------------------
// Combine split-K partials: O = (a0*O'0 + a1*O'1)/(a0+a1), a_i = l_i*2^(m_i-m)
// ---------------------------------------------------------------------------
__global__ __launch_bounds__(256)
void combine_kernel(const ushort* __restrict__ pA, const ushort* __restrict__ pB,
                    const float* __restrict__ ml, ushort* __restrict__ out, int n8)
{
    int i = blockIdx.x * 256 + threadIdx.x;
    if (i >= n8) return;
    const int row = i / 192;               // 192 = kDim/8
    const int within = (i - row * 192) * 8;
    const int h = within >> 7;
    const int b = row / kS;
    const int s = row - b * kS;
    const size_t base = (((size_t)(b * kHeads + h)) * 2) * kS;
    const float m0 = ml[(base + s) * 2],        l0 = ml[(base + s) * 2 + 1];
    const float m1 = ml[(base + kS + s) * 2],   l1 = ml[(base + kS + s) * 2 + 1];
    const float m  = fmaxf(m0, m1);
    const float a0 = l0 * exp2f(m0 - m);
    const float a1 = l1 * exp2f(m1 - m);
    const float inv = 1.f / (a0 + a1);
    const float f0 = a0 * inv, f1 = a1 * inv;

    uint4 ua = ((const uint4*)pA)[i];
    uint4 ub = ((const uint4*)pB)[i];
    const uint32_t* da = (const uint32_t*)&ua;
    const uint32_t* db = (const uint32_t*)&ub;
    uint32_t rv[4];
    #pragma unroll
    for (int j = 0; j < 4; ++j) {
        float o0 = f0 * bf2f(da[j] & 0xffff) + f1 * bf2f(db[j] & 0xffff);
        float o1 = f0 * bf2f(da[j] >> 16)    + f1 * bf2f(db[j] >> 16);
        rv[j] = (uint32_t)f2bf(o0) | ((uint32_t)f2bf(o1) << 16);
    }
    uint4 r; r.x = rv[0]; r.y = rv[1]; r.z = rv[2]; r.w = rv[3];
    ((uint4*)out)[i] = r;
}

// ---------------------------------------------------------------------------
extern "C" void kernel_launch(void* const* d_in, const int* in_sizes, int n_in,
                              void* d_out, int out_size, void* d_ws, size_t ws_size,
                              hipStream_t stream)
{
    (void)in_sizes; (void)n_in; (void)out_size; (void)ws_size;
    const float* x          = (const float*)d_in[0];
    const int*   seq_lens   = (const int*)  d_in[1];
    const int*   grid_sizes = (const int*)  d_in[2];
    const float* freqs      = (const float*)d_in[3];
    const float* Wq = (const float*)d_in[4];
    const float* bq = (const float*)d_in[5];
    const float* Wk = (const float*)d_in[6];
    const float* bk = (const float*)d_in[7];
    const float* Wv = (const float*)d_in[8];
    const float* bv = (const float*)d_in[9];
    const float* Wo = (const float*)d_in[10];
    const float* bo = (const float*)d_in[11];
    const float* gq = (const float*)d_in[12];
    const float* gk = (const float*)d_in[13];
    float* out = (float*)d_out;

    const int M = kB * kS;                       // 6144
    const size_t szX = (size_t)M * kDim;         // 9.44M elems
    const size_t szW = (size_t)kDim * kDim;

    ushort* xb   = (ushort*)d_ws;                // GEMM-A input, then partial A
    ushort* wqb  = xb   + szX;                   // wq|wk|wv contiguous = fused B
    ushort* wkb  = wqb  + szW;
    ushort* wvb  = wkb  + szW;
    ushort* wob  = wvb  + szW;
    ushort* qkvb = wob  + szW;                   // [6144][4608]
    ushort* ab   = qkvb + 3*szX;
    ushort* vtb  = ab   + szX;
    ushort* pBuf = vtb  + szX;                   // partial B (bf16, szX)
    float*  biasqkv = (float*)(pBuf + szX);      // 4608 f32
    float*  ml   = biasqkv + kQKV;               // 2*12*2*3072*2 f32

    dim3 blk(256);
    cvt_kernel<<<dim3((int)(szX/8/256)), blk, 0, stream>>>(x, xb, (int)(szX/8));
    cvt4_kernel<<<dim3((int)(szW/8/256), 4), blk, 0, stream>>>(
        Wq, Wk, Wv, Wo, wqb, wkb, wvb, wob, (int)(szW/8));
    biascat_kernel<<<dim3(18), blk, 0, stream>>>(bq, bk, bv, biasqkv);

    // fused QKV projection: N = 4608
    gemm_bf16<ushort><<<dim3(kQKV/128, M/128), blk, 0, stream>>>(
        xb, wqb, biasqkv, qkvb, M, kQKV, kDim);

    rmsrope_kernel<<<dim3(M, 2), dim3(192), 0, stream>>>(qkvb, gq, gk, freqs, grid_sizes);
    vtrans_kernel<<<dim3(kS/64, 2, kB*kHeads), blk, 0, stream>>>(qkvb, vtb);

    // split-K flash attention: 48 x 24 = 1152 blocks (xb reused as partial A)
    attn_kernel<<<dim3(48 * kHeads * kB), blk, 0, stream>>>(
        qkvb, vtb, xb, pBuf, ml, seq_lens);
    combine_kernel<<<dim3((int)(szX/8/256)), blk, 0, stream>>>(
        xb, pBuf, ml, ab, (int)(szX/8));

    gemm_bf16<float><<<dim3(kDim/128, M/128), blk, 0, stream>>>(
        ab, wob, bo, out, M, kDim, kDim);
}

// Round 16
// 408.982 us; speedup vs baseline: 1.0681x; 1.0147x over previous
//
#include <hip/hip_runtime.h>
#include <hip/hip_bf16.h>
#include <stdint.h>

typedef __attribute__((ext_vector_type(8))) short short8;
typedef __attribute__((ext_vector_type(4))) float f32x4;
typedef __attribute__((ext_vector_type(16))) float f32x16;

constexpr int kDim   = 1536;
constexpr int kHeads = 12;
constexpr int kHd    = 128;
constexpr int kS     = 3072;
constexpr int kB     = 2;
constexpr int kQKV   = 3 * kDim;               // 4608 fused row width
constexpr int kTabRows = 64;                   // cos/sin table rows (>= max grid dim)
constexpr float kEps   = 1e-6f;
constexpr float kQMul  = 0.08838834764831845f * 1.44269504089f; // 1/sqrt(128)*log2(e)

__device__ __forceinline__ ushort f2bf(float f) {
    union { float f; uint32_t u; } c; c.f = f;
    uint32_t u = c.u;
    return (ushort)((u + 0x7fffu + ((u >> 16) & 1u)) >> 16);
}
__device__ __forceinline__ float bf2f(uint32_t h) {
    union { uint32_t u; float f; } c; c.u = h << 16;
    return c.f;
}
__device__ __forceinline__ void gload_lds16(const void* g, void* l) {
    __builtin_amdgcn_global_load_lds((const __attribute__((address_space(1))) void*)g,
                                     (__attribute__((address_space(3))) void*)l, 16, 0, 0);
}
__device__ __forceinline__ uint32_t cvtpk_bf16(float lo, float hi) {
    uint32_t r;
    asm("v_cvt_pk_bf16_f32 %0, %1, %2" : "=v"(r) : "v"(lo), "v"(hi));
    return r;
}

// ---------------------------------------------------------------------------
// fp32 -> bf16 convert, 8 elems/thread
// ---------------------------------------------------------------------------
__global__ __launch_bounds__(256)
void cvt_kernel(const float* __restrict__ in, ushort* __restrict__ out, int n8)
{
    int i = blockIdx.x * 256 + threadIdx.x;
    if (i >= n8) return;
    const float4* p = (const float4*)in + (size_t)i * 2;
    float4 a = p[0], b = p[1];
    uint4 r;
    r.x = (uint32_t)f2bf(a.x) | ((uint32_t)f2bf(a.y) << 16);
    r.y = (uint32_t)f2bf(a.z) | ((uint32_t)f2bf(a.w) << 16);
    r.z = (uint32_t)f2bf(b.x) | ((uint32_t)f2bf(b.y) << 16);
    r.w = (uint32_t)f2bf(b.z) | ((uint32_t)f2bf(b.w) << 16);
    ((uint4*)out)[i] = r;
}

// 4 weight tensors in one dispatch (blockIdx.y selects)
__global__ __launch_bounds__(256)
void cvt4_kernel(const float* __restrict__ s0, const float* __restrict__ s1,
                 const float* __restrict__ s2, const float* __restrict__ s3,
                 ushort* __restrict__ d0, ushort* __restrict__ d1,
                 ushort* __restrict__ d2, ushort* __restrict__ d3, int n8)
{
    int i = blockIdx.x * 256 + threadIdx.x;
    if (i >= n8) return;
    const float* in; ushort* out;
    switch (blockIdx.y) {
        case 0: in = s0; out = d0; break;
        case 1: in = s1; out = d1; break;
        case 2: in = s2; out = d2; break;
        default: in = s3; out = d3; break;
    }
    const float4* p = (const float4*)in + (size_t)i * 2;
    float4 a = p[0], b = p[1];
    uint4 r;
    r.x = (uint32_t)f2bf(a.x) | ((uint32_t)f2bf(a.y) << 16);
    r.y = (uint32_t)f2bf(a.z) | ((uint32_t)f2bf(a.w) << 16);
    r.z = (uint32_t)f2bf(b.x) | ((uint32_t)f2bf(b.y) << 16);
    r.w = (uint32_t)f2bf(b.z) | ((uint32_t)f2bf(b.w) << 16);
    ((uint4*)out)[i] = r;
}

// concat bq|bk|bv -> biasqkv[4608]; also precompute cos/sin table for RoPE:
// cstab[pos*64+c] = {cos, sin}(freqs[pos*64+c]) for pos < 64 (grid dims <= 24
// here). Same sincosf on same inputs as before -> bit-identical results.
__global__ __launch_bounds__(256)
void prep_kernel(const float* __restrict__ bq, const float* __restrict__ bk,
                 const float* __restrict__ bv, const float* __restrict__ freqs,
                 float* __restrict__ biasqkv, float2* __restrict__ cstab)
{
    int i = blockIdx.x * 256 + threadIdx.x;
    if (i < kQKV) {
        float v = (i < kDim) ? bq[i] : (i < 2*kDim) ? bk[i - kDim] : bv[i - 2*kDim];
        biasqkv[i] = v;
    }
    if (i < kTabRows * 64) {
        float sn, cs;
        sincosf(freqs[i], &sn, &cs);   // freqs is [1024][64]; first 64 rows
        cstab[i] = make_float2(cs, sn);
    }
}

// ---------------------------------------------------------------------------
// bf16 MFMA GEMM: C[M][N] = A[M][K] @ B[N][K]^T + bias   (m97-style 128^2, BK=32)
// ---------------------------------------------------------------------------
template<typename OutT>
__global__ __launch_bounds__(256)
void gemm_bf16(const ushort* __restrict__ A, const ushort* __restrict__ B,
               const float* __restrict__ bias, OutT* __restrict__ C,
               int M, int N, int K)
{
    __shared__ ushort As[128 * 32];
    __shared__ ushort Bs[128 * 32];
    const int t    = threadIdx.x;
    const int lane = t & 63;
    const int w    = t >> 6;
    const int wm = (w >> 1) * 64, wn = (w & 1) * 64;
    const int m0 = blockIdx.y * 128, n0 = blockIdx.x * 128;

    const int srow = t >> 2;
    const int skc  = (t & 3) * 8;
    const ushort* Ag = A + (size_t)(m0 + srow) * K + skc;
    const ushort* Bg = B + (size_t)(n0 + srow) * K + skc;
    const size_t half = (size_t)64 * K;

    f32x4 acc[4][4];
    #pragma unroll
    for (int m = 0; m < 4; ++m)
        #pragma unroll
        for (int n = 0; n < 4; ++n)
            #pragma unroll
            for (int i = 0; i < 4; ++i) acc[m][n][i] = 0.f;

    const int kk  = (lane >> 4) * 8;
    const int l15 = lane & 15;

    for (int k0 = 0; k0 < K; k0 += 32) {
        __syncthreads();
        gload_lds16(Ag + k0,        &As[t * 8]);
        gload_lds16(Ag + half + k0, &As[t * 8 + 2048]);
        gload_lds16(Bg + k0,        &Bs[t * 8]);
        gload_lds16(Bg + half + k0, &Bs[t * 8 + 2048]);
        __syncthreads();
        short8 af[4], bf[4];
        #pragma unroll
        for (int m = 0; m < 4; ++m) af[m] = *(const short8*)&As[(wm + m*16 + l15) * 32 + kk];
        #pragma unroll
        for (int n = 0; n < 4; ++n) bf[n] = *(const short8*)&Bs[(wn + n*16 + l15) * 32 + kk];
        #pragma unroll
        for (int m = 0; m < 4; ++m)
            #pragma unroll
            for (int n = 0; n < 4; ++n)
                acc[m][n] = __builtin_amdgcn_mfma_f32_16x16x32_bf16(af[m], bf[n], acc[m][n], 0, 0, 0);
    }

    const int r0 = (lane >> 4) * 4;
    #pragma unroll
    for (int m = 0; m < 4; ++m) {
        #pragma unroll
        for (int r = 0; r < 4; ++r) {
            const size_t row = (size_t)(m0 + wm + m*16 + r0 + r);
            #pragma unroll
            for (int n = 0; n < 4; ++n) {
                const int col = n0 + wn + n*16 + l15;
                float val = acc[m][n][r] + bias[col];
                if constexpr (sizeof(OutT) == 4) C[row * N + col] = val;
                else                             C[row * N + col] = f2bf(val);
            }
        }
    }
}

// ---------------------------------------------------------------------------
// V transpose from fused qkv: vt[b][h][d][s] = qkv[b][s][3072 + h*128 + d]
// ---------------------------------------------------------------------------
__global__ __launch_bounds__(256)
void vtrans_kernel(const ushort* __restrict__ qkv, ushort* __restrict__ vt)
{
    __shared__ ushort Ts[64][72];
    const int t  = threadIdx.x;
    const int s0 = blockIdx.x * 64;
    const int d0 = blockIdx.y * 64;
    const int bh = blockIdx.z;
    const int b = bh / kHeads, h = bh % kHeads;

    const int r = t >> 2, cc = (t & 3) * 16;
    const ushort* src = qkv + ((size_t)(b * kS) + s0 + r) * kQKV + 2*kDim + h * kHd + d0 + cc;
    uint4 a0 = *(const uint4*)src;
    uint4 a1 = *(const uint4*)(src + 8);
    *(uint4*)&Ts[r][cc]     = a0;
    *(uint4*)&Ts[r][cc + 8] = a1;
    __syncthreads();
    ushort tmp[16];
    #pragma unroll
    for (int j = 0; j < 16; ++j) tmp[j] = Ts[cc + j][r];
    ushort* dst = vt + ((size_t)(bh * kHd) + d0 + r) * kS + s0 + cc;
    *(uint4*)dst       = *(uint4*)&tmp[0];
    *(uint4*)(dst + 8) = *(uint4*)&tmp[8];
}

// ---------------------------------------------------------------------------
// RMSNorm + RoPE on q/k sections of fused qkv. 192 thr, 8 elems each.
// cos/sin from precomputed table (r16) instead of 4x sincosf per thread.
// ---------------------------------------------------------------------------
__global__ __launch_bounds__(192)
void rmsrope_kernel(ushort* __restrict__ qkv,
                    const float* __restrict__ gq, const float* __restrict__ gk,
                    const float2* __restrict__ cstab, const int* __restrict__ grid_sizes)
{
    __shared__ float red[4];
    const int row   = blockIdx.x;
    const int which = blockIdx.y;
    ushort* ptr = qkv + (size_t)row * kQKV + which * kDim;
    const float* g = which ? gk : gq;
    const float outmul = which ? 1.0f : kQMul;
    const int t = threadIdx.x;

    uint4 raw = ((const uint4*)ptr)[t];
    float v[8];
    v[0] = bf2f(raw.x & 0xffff); v[1] = bf2f(raw.x >> 16);
    v[2] = bf2f(raw.y & 0xffff); v[3] = bf2f(raw.y >> 16);
    v[4] = bf2f(raw.z & 0xffff); v[5] = bf2f(raw.z >> 16);
    v[6] = bf2f(raw.w & 0xffff); v[7] = bf2f(raw.w >> 16);

    float ss = 0.f;
    #pragma unroll
    for (int i = 0; i < 8; ++i) ss += v[i] * v[i];
    #pragma unroll
    for (int off = 32; off >= 1; off >>= 1) ss += __shfl_xor(ss, off);
    if ((t & 63) == 0) red[t >> 6] = ss;
    __syncthreads();
    const float scale = rsqrtf((red[0] + red[1] + red[2]) * (1.f / kDim) + kEps);

    const int b = row / kS, s = row % kS;
    const int gh = grid_sizes[b*3 + 1], gw = grid_sizes[b*3 + 2];
    const int hw  = gh * gw;
    const int fi  = s / hw;
    const int rem = s - fi * hw;
    const int hi  = rem / gw;
    const int wi  = rem - hi * gw;

    const float4 g0 = *(const float4*)(g + t*8);
    const float4 g1 = *(const float4*)(g + t*8 + 4);
    const float gv[8] = {g0.x, g0.y, g0.z, g0.w, g1.x, g1.y, g1.z, g1.w};

    uint32_t out[4];
    #pragma unroll
    for (int jj = 0; jj < 4; ++jj) {
        const int p = t*4 + jj;
        const int c = p & 63;
        const int pos = (c < 22) ? fi : (c < 43 ? hi : wi);
        const float2 cs2 = cstab[pos * 64 + c];
        const float cs = cs2.x, sn = cs2.y;
        const float e0 = v[2*jj]   * scale * gv[2*jj];
        const float e1 = v[2*jj+1] * scale * gv[2*jj+1];
        const float o0 = (e0 * cs - e1 * sn) * outmul;
        const float o1 = (e0 * sn + e1 * cs) * outmul;
        out[jj] = (uint32_t)f2bf(o0) | ((uint32_t)f2bf(o1) << 16);
    }
    uint4 ov; ov.x = out[0]; ov.y = out[1]; ov.z = out[2]; ov.w = out[3];
    ((uint4*)ptr)[t] = ov;
}

// ---------------------------------------------------------------------------
// Flash attention, split-K (2 halves), swapped-QK^T 32x32x16 MFMA.
// (r15 structure: register-lean two-half processing, 4-bit K swizzle,
// merged P-exchange, tree max/sum reductions.)
// ---------------------------------------------------------------------------
__global__ __launch_bounds__(256, 3)
void attn_kernel(const ushort* __restrict__ qkv, const ushort* __restrict__ vtb,
                 ushort* __restrict__ pA, ushort* __restrict__ pB,
                 float* __restrict__ ml, const int* __restrict__ seq_lens)
{
    __shared__ ushort Ks[64 * 128];
    __shared__ ushort VT[128 * 64];

    // bijective XCD remap: consecutive logical ids (sharing (h,b) K/V) land on
    // the same XCD's L2.  1152 % 8 == 0 -> L = (lin&7)*144 + (lin>>3).
    const int lin = blockIdx.x;
    const int L   = (lin & 7) * 144 + (lin >> 3);
    const int bh   = L / 48;
    const int rem  = L - bh * 48;
    const int half = rem / 24;
    const int qtile= rem - half * 24;
    const int h = bh % kHeads, b = bh / kHeads;
    const int seq = seq_lens[b];
    const int kbeg = half * (kS / 2);

    const int t = threadIdx.x, lane = t & 63, w = t >> 6;
    const int l31 = lane & 31, hi = lane >> 5;
    const int qrow = qtile * 128 + w * 32 + l31;

    const ushort* qbase = qkv + ((size_t)b * kS) * kQKV + h * kHd;
    const ushort* kbase = qkv + ((size_t)b * kS) * kQKV + kDim + h * kHd;
    const ushort* vtbase = vtb + ((size_t)(b * kHeads + h) * kHd) * kS;

    // Q fragments (B-operand): qf[kb][j] = Q[qrow][kb*16 + hi*8 + j]
    short8 qf[8];
    #pragma unroll
    for (int kb = 0; kb < 8; ++kb)
        qf[kb] = *(const short8*)(qbase + (size_t)qrow * kQKV + kb*16 + hi*8);

    f32x16 oacc[4];
    #pragma unroll
    for (int n = 0; n < 4; ++n)
        #pragma unroll
        for (int i = 0; i < 16; ++i) oacc[n][i] = 0.f;

    float m_run = -1e30f, l_run = 0.f;

    const int srow = t >> 4;                      // 0..15
    const int scol = (t & 15) * 8;
    const int kl   = scol ^ (srow << 3);          // 4-bit pre-swizzled K source col
    const int vd0  = t >> 3;                      // 0..31
    const int vscol = ((t & 7) * 8) ^ ((vd0 & 7) << 3);  // pre-swizzled V^T col (3-bit, 64-wide rows)

    for (int kt = 0; kt < kS/2; kt += 64) {
        const int k0 = kbeg + kt;
        __syncthreads();
        #pragma unroll
        for (int c = 0; c < 4; ++c) {
            gload_lds16(kbase + (size_t)(k0 + srow + c*16) * kQKV + kl, &Ks[t*8 + c*2048]);
            gload_lds16(vtbase + (size_t)(vd0 + c*32) * kS + k0 + vscol, &VT[t*8 + c*2048]);
        }
        __syncthreads();

        // ---- two sequential 32-key halves (register-lean) ----
        #pragma unroll
        for (int hb = 0; hb < 2; ++hb) {
            // S^T = K . Q^T for rows hb*32 + l31; reg r -> key (r&3)+8*(r>>2)+4*hi
            f32x16 s;
            #pragma unroll
            for (int i = 0; i < 16; ++i) s[i] = 0.f;
            __builtin_amdgcn_s_setprio(1);
            #pragma unroll
            for (int kb = 0; kb < 8; ++kb) {
                const int col = (kb*16 + hi*8) ^ ((l31 & 15) << 3);
                short8 kf = *(const short8*)&Ks[(hb*32 + l31) * 128 + col];
                s = __builtin_amdgcn_mfma_f32_32x32x16_bf16(kf, qf[kb], s, 0, 0, 0);
            }
            __builtin_amdgcn_s_setprio(0);

            // mask (scores already in log2 domain via kQMul)
            const int kb0 = k0 + hb*32;
            if (kb0 + 32 > seq) {
                #pragma unroll
                for (int r = 0; r < 16; ++r)
                    if (kb0 + (r&3) + 8*(r>>2) + 4*hi >= seq) s[r] = -1e30f;
            }
            // tree max (v_max3-fusable triples, depth 3-4)
            const float a0 = fmaxf(fmaxf(s[0],  s[1]),  s[2]);
            const float a1 = fmaxf(fmaxf(s[3],  s[4]),  s[5]);
            const float a2 = fmaxf(fmaxf(s[6],  s[7]),  s[8]);
            const float a3 = fmaxf(fmaxf(s[9],  s[10]), s[11]);
            const float a4 = fmaxf(fmaxf(s[12], s[13]), s[14]);
            const float b0 = fmaxf(fmaxf(a0, a1), a2);
            const float b1 = fmaxf(fmaxf(a3, a4), s[15]);
            float mx = fmaxf(b0, b1);
            mx = fmaxf(mx, __shfl_xor(mx, 32));

            // defer-max online softmax (T13)
            const bool skip = (mx <= m_run + 11.0f);
            if (!__all(skip)) {
                const float mnew = fmaxf(m_run, mx);
                const float alpha = exp2f(m_run - mnew);
                m_run = mnew;
                l_run *= alpha;
                #pragma unroll
                for (int r = 0; r < 16; ++r) {
                    const float ar = __shfl(alpha, (r&3) + 8*(r>>2) + 4*hi);
                    #pragma unroll
                    for (int n = 0; n < 4; ++n) oacc[n][r] *= ar;
                }
            }

            #pragma unroll
            for (int r = 0; r < 16; ++r) s[r] = exp2f(s[r] - m_run);
            // pairwise add tree (depth 4)
            const float t0 = (s[0] + s[1]) + (s[2]  + s[3]);
            const float t1 = (s[4] + s[5]) + (s[6]  + s[7]);
            const float t2 = (s[8] + s[9]) + (s[10] + s[11]);
            const float t3 = (s[12]+ s[13])+ (s[14] + s[15]);
            float rs = (t0 + t1) + (t2 + t3);
            rs += __shfl_xor(rs, 32);
            l_run += rs;

            // pack P -> bf16 dwords (cvt_pk); merged half-exchange:
            // send what the partner needs -> 4 shfl instead of 8.
            uint32_t u[8];
            #pragma unroll
            for (int i = 0; i < 8; ++i) u[i] = cvtpk_bf16(s[2*i], s[2*i+1]);
            uint32_t m0 = hi ? u[0] : u[2];
            uint32_t m1 = hi ? u[1] : u[3];
            uint32_t m2 = hi ? u[4] : u[6];
            uint32_t m3 = hi ? u[5] : u[7];
            const uint32_t wm0 = __shfl_xor(m0, 32);
            const uint32_t wm1 = __shfl_xor(m1, 32);
            const uint32_t wm2 = __shfl_xor(m2, 32);
            const uint32_t wm3 = __shfl_xor(m3, 32);
            union PF { uint32_t d[4]; short8 s8; };
            PF pa0, pa1;
            pa0.d[0] = hi ? wm0 : u[0];  pa0.d[1] = hi ? wm1 : u[1];
            pa0.d[2] = hi ? u[2] : wm0;  pa0.d[3] = hi ? u[3] : wm1;
            pa1.d[0] = hi ? wm2 : u[4];  pa1.d[1] = hi ? wm3 : u[5];
            pa1.d[2] = hi ? u[6] : wm2;  pa1.d[3] = hi ? u[7] : wm3;

            // PV for this half: k-slots hb*2 + {0,1}
            __builtin_amdgcn_s_setprio(1);
            #pragma unroll
            for (int kss = 0; kss < 2; ++kss) {
                const int ks = hb*2 + kss;
                #pragma unroll
                for (int n = 0; n < 4; ++n) {
                    const int d = n*32 + l31;
                    const int colv = (ks*16 + hi*8) ^ ((l31 & 7) << 3);
                    short8 vf = *(const short8*)&VT[d * 64 + colv];
                    oacc[n] = __builtin_amdgcn_mfma_f32_32x32x16_bf16(
                        (kss ? pa1 : pa0).s8, vf, oacc[n], 0, 0, 0);
                }
            }
            __builtin_amdgcn_s_setprio(0);
        }
    }

    // ---- epilogue: partial O' = O~/l (bf16) + per-row (m,l) ----
    ushort* pOut = half ? pB : pA;
    const float linv = 1.f / l_run;
    #pragma unroll
    for (int r = 0; r < 16; ++r) {
        const int qr = (r&3) + 8*(r>>2) + 4*hi;
        const float lr = __shfl(linv, qr);
        const size_t row = (size_t)(b * kS) + qtile * 128 + w * 32 + qr;
        #pragma unroll
        for (int n = 0; n < 4; ++n)
            pOut[row * kDim + h * kHd + n*32 + l31] = f2bf(oacc[n][r] * lr);
    }
    if (lane < 32) {
        const int s = qtile * 128 + w * 32 + l31;
        const size_t idx = ((((size_t)(b * kHeads + h)) * 2 + half) * kS + s) * 2;
        ml[idx]     = m_run;
        ml[idx + 1] = l_run;
    }
}

// ---------------------------------------------------------------------------
// Combine split-K partials: O = (a0*O'0 + a1*O'1)/(a0+a1), a_i = l_i*2^(m_i-m)
// ---------------------------------------------------------------------------
__global__ __launch_bounds__(256)
void combine_kernel(const ushort* __restrict__ pA, const ushort* __restrict__ pB,
                    const float* __restrict__ ml, ushort* __restrict__ out, int n8)
{
    int i = blockIdx.x * 256 + threadIdx.x;
    if (i >= n8) return;
    const int row = i / 192;               // 192 = kDim/8
    const int within = (i - row * 192) * 8;
    const int h = within >> 7;
    const int b = row / kS;
    const int s = row - b * kS;
    const size_t base = (((size_t)(b * kHeads + h)) * 2) * kS;
    const float m0 = ml[(base + s) * 2],        l0 = ml[(base + s) * 2 + 1];
    const float m1 = ml[(base + kS + s) * 2],   l1 = ml[(base + kS + s) * 2 + 1];
    const float m  = fmaxf(m0, m1);
    const float a0 = l0 * exp2f(m0 - m);
    const float a1 = l1 * exp2f(m1 - m);
    const float inv = 1.f / (a0 + a1);
    const float f0 = a0 * inv, f1 = a1 * inv;

    uint4 ua = ((const uint4*)pA)[i];
    uint4 ub = ((const uint4*)pB)[i];
    const uint32_t* da = (const uint32_t*)&ua;
    const uint32_t* db = (const uint32_t*)&ub;
    uint32_t rv[4];
    #pragma unroll
    for (int j = 0; j < 4; ++j) {
        float o0 = f0 * bf2f(da[j] & 0xffff) + f1 * bf2f(db[j] & 0xffff);
        float o1 = f0 * bf2f(da[j] >> 16)    + f1 * bf2f(db[j] >> 16);
        rv[j] = (uint32_t)f2bf(o0) | ((uint32_t)f2bf(o1) << 16);
    }
    uint4 r; r.x = rv[0]; r.y = rv[1]; r.z = rv[2]; r.w = rv[3];
    ((uint4*)out)[i] = r;
}

// ---------------------------------------------------------------------------
extern "C" void kernel_launch(void* const* d_in, const int* in_sizes, int n_in,
                              void* d_out, int out_size, void* d_ws, size_t ws_size,
                              hipStream_t stream)
{
    (void)in_sizes; (void)n_in; (void)out_size; (void)ws_size;
    const float* x          = (const float*)d_in[0];
    const int*   seq_lens   = (const int*)  d_in[1];
    const int*   grid_sizes = (const int*)  d_in[2];
    const float* freqs      = (const float*)d_in[3];
    const float* Wq = (const float*)d_in[4];
    const float* bq = (const float*)d_in[5];
    const float* Wk = (const float*)d_in[6];
    const float* bk = (const float*)d_in[7];
    const float* Wv = (const float*)d_in[8];
    const float* bv = (const float*)d_in[9];
    const float* Wo = (const float*)d_in[10];
    const float* bo = (const float*)d_in[11];
    const float* gq = (const float*)d_in[12];
    const float* gk = (const float*)d_in[13];
    float* out = (float*)d_out;

    const int M = kB * kS;                       // 6144
    const size_t szX = (size_t)M * kDim;         // 9.44M elems
    const size_t szW = (size_t)kDim * kDim;

    ushort* xb   = (ushort*)d_ws;                // GEMM-A input, then partial A
    ushort* wqb  = xb   + szX;                   // wq|wk|wv contiguous = fused B
    ushort* wkb  = wqb  + szW;
    ushort* wvb  = wkb  + szW;
    ushort* wob  = wvb  + szW;
    ushort* qkvb = wob  + szW;                   // [6144][4608]
    ushort* ab   = qkvb + 3*szX;
    ushort* vtb  = ab   + szX;
    ushort* pBuf = vtb  + szX;                   // partial B (bf16, szX)
    float*  biasqkv = (float*)(pBuf + szX);      // 4608 f32
    float*  ml   = biasqkv + kQKV;               // 2*12*2*3072*2 f32
    float2* cstab = (float2*)(ml + (size_t)2 * kHeads * 2 * kS * 2);  // 4096 float2

    dim3 blk(256);
    cvt_kernel<<<dim3((int)(szX/8/256)), blk, 0, stream>>>(x, xb, (int)(szX/8));
    cvt4_kernel<<<dim3((int)(szW/8/256), 4), blk, 0, stream>>>(
        Wq, Wk, Wv, Wo, wqb, wkb, wvb, wob, (int)(szW/8));
    prep_kernel<<<dim3(18), blk, 0, stream>>>(bq, bk, bv, freqs, biasqkv, cstab);

    // fused QKV projection: N = 4608
    gemm_bf16<ushort><<<dim3(kQKV/128, M/128), blk, 0, stream>>>(
        xb, wqb, biasqkv, qkvb, M, kQKV, kDim);

    rmsrope_kernel<<<dim3(M, 2), dim3(192), 0, stream>>>(qkvb, gq, gk, cstab, grid_sizes);
    vtrans_kernel<<<dim3(kS/64, 2, kB*kHeads), blk, 0, stream>>>(qkvb, vtb);

    // split-K flash attention: 48 x 24 = 1152 blocks (xb reused as partial A)
    attn_kernel<<<dim3(48 * kHeads * kB), blk, 0, stream>>>(
        qkvb, vtb, xb, pBuf, ml, seq_lens);
    combine_kernel<<<dim3((int)(szX/8/256)), blk, 0, stream>>>(
        xb, pBuf, ml, ab, (int)(szX/8));

    gemm_bf16<float><<<dim3(kDim/128, M/128), blk, 0, stream>>>(
        ab, wob, bo, out, M, kDim, kDim);
}

// Round 17
// 407.556 us; speedup vs baseline: 1.0719x; 1.0035x over previous
//
#include <hip/hip_runtime.h>
#include <hip/hip_bf16.h>
#include <stdint.h>

typedef __attribute__((ext_vector_type(8))) short short8;
typedef __attribute__((ext_vector_type(4))) float f32x4;
typedef __attribute__((ext_vector_type(16))) float f32x16;

constexpr int kDim   = 1536;
constexpr int kHeads = 12;
constexpr int kHd    = 128;
constexpr int kS     = 3072;
constexpr int kB     = 2;
constexpr int kQKV   = 3 * kDim;               // 4608 fused row width
constexpr int kTabRows = 64;                   // cos/sin table rows (>= max grid dim)
constexpr float kEps   = 1e-6f;
constexpr float kQMul  = 0.08838834764831845f * 1.44269504089f; // 1/sqrt(128)*log2(e)

__device__ __forceinline__ ushort f2bf(float f) {
    union { float f; uint32_t u; } c; c.f = f;
    uint32_t u = c.u;
    return (ushort)((u + 0x7fffu + ((u >> 16) & 1u)) >> 16);
}
__device__ __forceinline__ float bf2f(uint32_t h) {
    union { uint32_t u; float f; } c; c.u = h << 16;
    return c.f;
}
__device__ __forceinline__ void gload_lds16(const void* g, void* l) {
    __builtin_amdgcn_global_load_lds((const __attribute__((address_space(1))) void*)g,
                                     (__attribute__((address_space(3))) void*)l, 16, 0, 0);
}
__device__ __forceinline__ uint32_t cvtpk_bf16(float lo, float hi) {
    uint32_t r;
    asm("v_cvt_pk_bf16_f32 %0, %1, %2" : "=v"(r) : "v"(lo), "v"(hi));
    return r;
}

// ---------------------------------------------------------------------------
// fp32 -> bf16 convert, 8 elems/thread
// ---------------------------------------------------------------------------
__global__ __launch_bounds__(256)
void cvt_kernel(const float* __restrict__ in, ushort* __restrict__ out, int n8)
{
    int i = blockIdx.x * 256 + threadIdx.x;
    if (i >= n8) return;
    const float4* p = (const float4*)in + (size_t)i * 2;
    float4 a = p[0], b = p[1];
    uint4 r;
    r.x = (uint32_t)f2bf(a.x) | ((uint32_t)f2bf(a.y) << 16);
    r.y = (uint32_t)f2bf(a.z) | ((uint32_t)f2bf(a.w) << 16);
    r.z = (uint32_t)f2bf(b.x) | ((uint32_t)f2bf(b.y) << 16);
    r.w = (uint32_t)f2bf(b.z) | ((uint32_t)f2bf(b.w) << 16);
    ((uint4*)out)[i] = r;
}

// 4 weight tensors in one dispatch (blockIdx.y selects)
__global__ __launch_bounds__(256)
void cvt4_kernel(const float* __restrict__ s0, const float* __restrict__ s1,
                 const float* __restrict__ s2, const float* __restrict__ s3,
                 ushort* __restrict__ d0, ushort* __restrict__ d1,
                 ushort* __restrict__ d2, ushort* __restrict__ d3, int n8)
{
    int i = blockIdx.x * 256 + threadIdx.x;
    if (i >= n8) return;
    const float* in; ushort* out;
    switch (blockIdx.y) {
        case 0: in = s0; out = d0; break;
        case 1: in = s1; out = d1; break;
        case 2: in = s2; out = d2; break;
        default: in = s3; out = d3; break;
    }
    const float4* p = (const float4*)in + (size_t)i * 2;
    float4 a = p[0], b = p[1];
    uint4 r;
    r.x = (uint32_t)f2bf(a.x) | ((uint32_t)f2bf(a.y) << 16);
    r.y = (uint32_t)f2bf(a.z) | ((uint32_t)f2bf(a.w) << 16);
    r.z = (uint32_t)f2bf(b.x) | ((uint32_t)f2bf(b.y) << 16);
    r.w = (uint32_t)f2bf(b.z) | ((uint32_t)f2bf(b.w) << 16);
    ((uint4*)out)[i] = r;
}

// concat bq|bk|bv -> biasqkv[4608]; also precompute cos/sin table for RoPE:
// cstab[pos*64+c] = {cos, sin}(freqs[pos*64+c]) for pos < 64.
__global__ __launch_bounds__(256)
void prep_kernel(const float* __restrict__ bq, const float* __restrict__ bk,
                 const float* __restrict__ bv, const float* __restrict__ freqs,
                 float* __restrict__ biasqkv, float2* __restrict__ cstab)
{
    int i = blockIdx.x * 256 + threadIdx.x;
    if (i < kQKV) {
        float v = (i < kDim) ? bq[i] : (i < 2*kDim) ? bk[i - kDim] : bv[i - 2*kDim];
        biasqkv[i] = v;
    }
    if (i < kTabRows * 64) {
        float sn, cs;
        sincosf(freqs[i], &sn, &cs);
        cstab[i] = make_float2(cs, sn);
    }
}

// ---------------------------------------------------------------------------
// bf16 MFMA GEMM: C[M][N] = A[M][K] @ B[N][K]^T + bias   (m97-style 128^2, BK=32)
// ---------------------------------------------------------------------------
template<typename OutT>
__global__ __launch_bounds__(256)
void gemm_bf16(const ushort* __restrict__ A, const ushort* __restrict__ B,
               const float* __restrict__ bias, OutT* __restrict__ C,
               int M, int N, int K)
{
    __shared__ ushort As[128 * 32];
    __shared__ ushort Bs[128 * 32];
    const int t    = threadIdx.x;
    const int lane = t & 63;
    const int w    = t >> 6;
    const int wm = (w >> 1) * 64, wn = (w & 1) * 64;
    const int m0 = blockIdx.y * 128, n0 = blockIdx.x * 128;

    const int srow = t >> 2;
    const int skc  = (t & 3) * 8;
    const ushort* Ag = A + (size_t)(m0 + srow) * K + skc;
    const ushort* Bg = B + (size_t)(n0 + srow) * K + skc;
    const size_t half = (size_t)64 * K;

    f32x4 acc[4][4];
    #pragma unroll
    for (int m = 0; m < 4; ++m)
        #pragma unroll
        for (int n = 0; n < 4; ++n)
            #pragma unroll
            for (int i = 0; i < 4; ++i) acc[m][n][i] = 0.f;

    const int kk  = (lane >> 4) * 8;
    const int l15 = lane & 15;

    for (int k0 = 0; k0 < K; k0 += 32) {
        __syncthreads();
        gload_lds16(Ag + k0,        &As[t * 8]);
        gload_lds16(Ag + half + k0, &As[t * 8 + 2048]);
        gload_lds16(Bg + k0,        &Bs[t * 8]);
        gload_lds16(Bg + half + k0, &Bs[t * 8 + 2048]);
        __syncthreads();
        short8 af[4], bf[4];
        #pragma unroll
        for (int m = 0; m < 4; ++m) af[m] = *(const short8*)&As[(wm + m*16 + l15) * 32 + kk];
        #pragma unroll
        for (int n = 0; n < 4; ++n) bf[n] = *(const short8*)&Bs[(wn + n*16 + l15) * 32 + kk];
        #pragma unroll
        for (int m = 0; m < 4; ++m)
            #pragma unroll
            for (int n = 0; n < 4; ++n)
                acc[m][n] = __builtin_amdgcn_mfma_f32_16x16x32_bf16(af[m], bf[n], acc[m][n], 0, 0, 0);
    }

    const int r0 = (lane >> 4) * 4;
    #pragma unroll
    for (int m = 0; m < 4; ++m) {
        #pragma unroll
        for (int r = 0; r < 4; ++r) {
            const size_t row = (size_t)(m0 + wm + m*16 + r0 + r);
            #pragma unroll
            for (int n = 0; n < 4; ++n) {
                const int col = n0 + wn + n*16 + l15;
                float val = acc[m][n][r] + bias[col];
                if constexpr (sizeof(OutT) == 4) C[row * N + col] = val;
                else                             C[row * N + col] = f2bf(val);
            }
        }
    }
}

// ---------------------------------------------------------------------------
// V transpose from fused qkv: vt[b][h][d][s] = qkv[b][s][3072 + h*128 + d]
// LDS layout swizzled: phys_col = d ^ ((s>>4 & 3)<<4).  Writes (s fixed per
// wave-quarter) keep 16B contiguity & their free bank pattern; column reads
// drop from 8-way to 2-way conflicts (bank = 8g + 36j + r/2 covers all 32).
// ---------------------------------------------------------------------------
__global__ __launch_bounds__(256)
void vtrans_kernel(const ushort* __restrict__ qkv, ushort* __restrict__ vt)
{
    __shared__ ushort Ts[64][72];
    const int t  = threadIdx.x;
    const int s0 = blockIdx.x * 64;
    const int d0 = blockIdx.y * 64;
    const int bh = blockIdx.z;
    const int b = bh / kHeads, h = bh % kHeads;

    const int r = t >> 2, cc = (t & 3) * 16;
    const int wsw = ((r >> 4) & 3) << 4;           // swizzle key of this thread's s-row
    const ushort* src = qkv + ((size_t)(b * kS) + s0 + r) * kQKV + 2*kDim + h * kHd + d0 + cc;
    uint4 a0 = *(const uint4*)src;
    uint4 a1 = *(const uint4*)(src + 8);
    *(uint4*)&Ts[r][(cc ^ wsw)]     = a0;
    *(uint4*)&Ts[r][(cc ^ wsw) + 8] = a1;
    __syncthreads();
    const int rsw = (t & 3) << 4;                  // = ((cc+j)>>4)<<4 for j<16
    ushort tmp[16];
    #pragma unroll
    for (int j = 0; j < 16; ++j) tmp[j] = Ts[cc + j][r ^ rsw];
    ushort* dst = vt + ((size_t)(bh * kHd) + d0 + r) * kS + s0 + cc;
    *(uint4*)dst       = *(uint4*)&tmp[0];
    *(uint4*)(dst + 8) = *(uint4*)&tmp[8];
}

// ---------------------------------------------------------------------------
// RMSNorm + RoPE on q/k sections of fused qkv. 192 thr, 8 elems each.
// cos/sin from precomputed table instead of 4x sincosf per thread.
// ---------------------------------------------------------------------------
__global__ __launch_bounds__(192)
void rmsrope_kernel(ushort* __restrict__ qkv,
                    const float* __restrict__ gq, const float* __restrict__ gk,
                    const float2* __restrict__ cstab, const int* __restrict__ grid_sizes)
{
    __shared__ float red[4];
    const int row   = blockIdx.x;
    const int which = blockIdx.y;
    ushort* ptr = qkv + (size_t)row * kQKV + which * kDim;
    const float* g = which ? gk : gq;
    const float outmul = which ? 1.0f : kQMul;
    const int t = threadIdx.x;

    uint4 raw = ((const uint4*)ptr)[t];
    float v[8];
    v[0] = bf2f(raw.x & 0xffff); v[1] = bf2f(raw.x >> 16);
    v[2] = bf2f(raw.y & 0xffff); v[3] = bf2f(raw.y >> 16);
    v[4] = bf2f(raw.z & 0xffff); v[5] = bf2f(raw.z >> 16);
    v[6] = bf2f(raw.w & 0xffff); v[7] = bf2f(raw.w >> 16);

    float ss = 0.f;
    #pragma unroll
    for (int i = 0; i < 8; ++i) ss += v[i] * v[i];
    #pragma unroll
    for (int off = 32; off >= 1; off >>= 1) ss += __shfl_xor(ss, off);
    if ((t & 63) == 0) red[t >> 6] = ss;
    __syncthreads();
    const float scale = rsqrtf((red[0] + red[1] + red[2]) * (1.f / kDim) + kEps);

    const int b = row / kS, s = row % kS;
    const int gh = grid_sizes[b*3 + 1], gw = grid_sizes[b*3 + 2];
    const int hw  = gh * gw;
    const int fi  = s / hw;
    const int rem = s - fi * hw;
    const int hi  = rem / gw;
    const int wi  = rem - hi * gw;

    const float4 g0 = *(const float4*)(g + t*8);
    const float4 g1 = *(const float4*)(g + t*8 + 4);
    const float gv[8] = {g0.x, g0.y, g0.z, g0.w, g1.x, g1.y, g1.z, g1.w};

    uint32_t out[4];
    #pragma unroll
    for (int jj = 0; jj < 4; ++jj) {
        const int p = t*4 + jj;
        const int c = p & 63;
        const int pos = (c < 22) ? fi : (c < 43 ? hi : wi);
        const float2 cs2 = cstab[pos * 64 + c];
        const float cs = cs2.x, sn = cs2.y;
        const float e0 = v[2*jj]   * scale * gv[2*jj];
        const float e1 = v[2*jj+1] * scale * gv[2*jj+1];
        const float o0 = (e0 * cs - e1 * sn) * outmul;
        const float o1 = (e0 * sn + e1 * cs) * outmul;
        out[jj] = (uint32_t)f2bf(o0) | ((uint32_t)f2bf(o1) << 16);
    }
    uint4 ov; ov.x = out[0]; ov.y = out[1]; ov.z = out[2]; ov.w = out[3];
    ((uint4*)ptr)[t] = ov;
}

// ---------------------------------------------------------------------------
// Flash attention, split-K (2 halves), swapped-QK^T 32x32x16 MFMA.
// (register-lean two-half processing, 4-bit K swizzle, merged P-exchange,
//  tree max/sum reductions.)
// ---------------------------------------------------------------------------
__global__ __launch_bounds__(256, 3)
void attn_kernel(const ushort* __restrict__ qkv, const ushort* __restrict__ vtb,
                 ushort* __restrict__ pA, ushort* __restrict__ pB,
                 float* __restrict__ ml, const int* __restrict__ seq_lens)
{
    __shared__ ushort Ks[64 * 128];
    __shared__ ushort VT[128 * 64];

    // bijective XCD remap: consecutive logical ids (sharing (h,b) K/V) land on
    // the same XCD's L2.  1152 % 8 == 0 -> L = (lin&7)*144 + (lin>>3).
    const int lin = blockIdx.x;
    const int L   = (lin & 7) * 144 + (lin >> 3);
    const int bh   = L / 48;
    const int rem  = L - bh * 48;
    const int half = rem / 24;
    const int qtile= rem - half * 24;
    const int h = bh % kHeads, b = bh / kHeads;
    const int seq = seq_lens[b];
    const int kbeg = half * (kS / 2);

    const int t = threadIdx.x, lane = t & 63, w = t >> 6;
    const int l31 = lane & 31, hi = lane >> 5;
    const int qrow = qtile * 128 + w * 32 + l31;

    const ushort* qbase = qkv + ((size_t)b * kS) * kQKV + h * kHd;
    const ushort* kbase = qkv + ((size_t)b * kS) * kQKV + kDim + h * kHd;
    const ushort* vtbase = vtb + ((size_t)(b * kHeads + h) * kHd) * kS;

    // Q fragments (B-operand): qf[kb][j] = Q[qrow][kb*16 + hi*8 + j]
    short8 qf[8];
    #pragma unroll
    for (int kb = 0; kb < 8; ++kb)
        qf[kb] = *(const short8*)(qbase + (size_t)qrow * kQKV + kb*16 + hi*8);

    f32x16 oacc[4];
    #pragma unroll
    for (int n = 0; n < 4; ++n)
        #pragma unroll
        for (int i = 0; i < 16; ++i) oacc[n][i] = 0.f;

    float m_run = -1e30f, l_run = 0.f;

    const int srow = t >> 4;                      // 0..15
    const int scol = (t & 15) * 8;
    const int kl   = scol ^ (srow << 3);          // 4-bit pre-swizzled K source col
    const int vd0  = t >> 3;                      // 0..31
    const int vscol = ((t & 7) * 8) ^ ((vd0 & 7) << 3);  // pre-swizzled V^T col (3-bit, 64-wide rows)

    for (int kt = 0; kt < kS/2; kt += 64) {
        const int k0 = kbeg + kt;
        __syncthreads();
        #pragma unroll
        for (int c = 0; c < 4; ++c) {
            gload_lds16(kbase + (size_t)(k0 + srow + c*16) * kQKV + kl, &Ks[t*8 + c*2048]);
            gload_lds16(vtbase + (size_t)(vd0 + c*32) * kS + k0 + vscol, &VT[t*8 + c*2048]);
        }
        __syncthreads();

        // ---- two sequential 32-key halves (register-lean) ----
        #pragma unroll
        for (int hb = 0; hb < 2; ++hb) {
            // S^T = K . Q^T for rows hb*32 + l31; reg r -> key (r&3)+8*(r>>2)+4*hi
            f32x16 s;
            #pragma unroll
            for (int i = 0; i < 16; ++i) s[i] = 0.f;
            __builtin_amdgcn_s_setprio(1);
            #pragma unroll
            for (int kb = 0; kb < 8; ++kb) {
                const int col = (kb*16 + hi*8) ^ ((l31 & 15) << 3);
                short8 kf = *(const short8*)&Ks[(hb*32 + l31) * 128 + col];
                s = __builtin_amdgcn_mfma_f32_32x32x16_bf16(kf, qf[kb], s, 0, 0, 0);
            }
            __builtin_amdgcn_s_setprio(0);

            // mask (scores already in log2 domain via kQMul)
            const int kb0 = k0 + hb*32;
            if (kb0 + 32 > seq) {
                #pragma unroll
                for (int r = 0; r < 16; ++r)
                    if (kb0 + (r&3) + 8*(r>>2) + 4*hi >= seq) s[r] = -1e30f;
            }
            // tree max (v_max3-fusable triples, depth 3-4)
            const float a0 = fmaxf(fmaxf(s[0],  s[1]),  s[2]);
            const float a1 = fmaxf(fmaxf(s[3],  s[4]),  s[5]);
            const float a2 = fmaxf(fmaxf(s[6],  s[7]),  s[8]);
            const float a3 = fmaxf(fmaxf(s[9],  s[10]), s[11]);
            const float a4 = fmaxf(fmaxf(s[12], s[13]), s[14]);
            const float b0 = fmaxf(fmaxf(a0, a1), a2);
            const float b1 = fmaxf(fmaxf(a3, a4), s[15]);
            float mx = fmaxf(b0, b1);
            mx = fmaxf(mx, __shfl_xor(mx, 32));

            // defer-max online softmax (T13)
            const bool skip = (mx <= m_run + 11.0f);
            if (!__all(skip)) {
                const float mnew = fmaxf(m_run, mx);
                const float alpha = exp2f(m_run - mnew);
                m_run = mnew;
                l_run *= alpha;
                #pragma unroll
                for (int r = 0; r < 16; ++r) {
                    const float ar = __shfl(alpha, (r&3) + 8*(r>>2) + 4*hi);
                    #pragma unroll
                    for (int n = 0; n < 4; ++n) oacc[n][r] *= ar;
                }
            }

            #pragma unroll
            for (int r = 0; r < 16; ++r) s[r] = exp2f(s[r] - m_run);
            // pairwise add tree (depth 4)
            const float t0 = (s[0] + s[1]) + (s[2]  + s[3]);
            const float t1 = (s[4] + s[5]) + (s[6]  + s[7]);
            const float t2 = (s[8] + s[9]) + (s[10] + s[11]);
            const float t3 = (s[12]+ s[13])+ (s[14] + s[15]);
            float rs = (t0 + t1) + (t2 + t3);
            rs += __shfl_xor(rs, 32);
            l_run += rs;

            // pack P -> bf16 dwords (cvt_pk); merged half-exchange:
            // send what the partner needs -> 4 shfl instead of 8.
            uint32_t u[8];
            #pragma unroll
            for (int i = 0; i < 8; ++i) u[i] = cvtpk_bf16(s[2*i], s[2*i+1]);
            uint32_t m0 = hi ? u[0] : u[2];
            uint32_t m1 = hi ? u[1] : u[3];
            uint32_t m2 = hi ? u[4] : u[6];
            uint32_t m3 = hi ? u[5] : u[7];
            const uint32_t wm0 = __shfl_xor(m0, 32);
            const uint32_t wm1 = __shfl_xor(m1, 32);
            const uint32_t wm2 = __shfl_xor(m2, 32);
            const uint32_t wm3 = __shfl_xor(m3, 32);
            union PF { uint32_t d[4]; short8 s8; };
            PF pa0, pa1;
            pa0.d[0] = hi ? wm0 : u[0];  pa0.d[1] = hi ? wm1 : u[1];
            pa0.d[2] = hi ? u[2] : wm0;  pa0.d[3] = hi ? u[3] : wm1;
            pa1.d[0] = hi ? wm2 : u[4];  pa1.d[1] = hi ? wm3 : u[5];
            pa1.d[2] = hi ? u[6] : wm2;  pa1.d[3] = hi ? u[7] : wm3;

            // PV for this half: k-slots hb*2 + {0,1}
            __builtin_amdgcn_s_setprio(1);
            #pragma unroll
            for (int kss = 0; kss < 2; ++kss) {
                const int ks = hb*2 + kss;
                #pragma unroll
                for (int n = 0; n < 4; ++n) {
                    const int d = n*32 + l31;
                    const int colv = (ks*16 + hi*8) ^ ((l31 & 7) << 3);
                    short8 vf = *(const short8*)&VT[d * 64 + colv];
                    oacc[n] = __builtin_amdgcn_mfma_f32_32x32x16_bf16(
                        (kss ? pa1 : pa0).s8, vf, oacc[n], 0, 0, 0);
                }
            }
            __builtin_amdgcn_s_setprio(0);
        }
    }

    // ---- epilogue: partial O' = O~/l (bf16) + per-row (m,l) ----
    ushort* pOut = half ? pB : pA;
    const float linv = 1.f / l_run;
    #pragma unroll
    for (int r = 0; r < 16; ++r) {
        const int qr = (r&3) + 8*(r>>2) + 4*hi;
        const float lr = __shfl(linv, qr);
        const size_t row = (size_t)(b * kS) + qtile * 128 + w * 32 + qr;
        #pragma unroll
        for (int n = 0; n < 4; ++n)
            pOut[row * kDim + h * kHd + n*32 + l31] = f2bf(oacc[n][r] * lr);
    }
    if (lane < 32) {
        const int s = qtile * 128 + w * 32 + l31;
        const size_t idx = ((((size_t)(b * kHeads + h)) * 2 + half) * kS + s) * 2;
        ml[idx]     = m_run;
        ml[idx + 1] = l_run;
    }
}

// ---------------------------------------------------------------------------
// Combine split-K partials: O = (a0*O'0 + a1*O'1)/(a0+a1), a_i = l_i*2^(m_i-m)
// ---------------------------------------------------------------------------
__global__ __launch_bounds__(256)
void combine_kernel(const ushort* __restrict__ pA, const ushort* __restrict__ pB,
                    const float* __restrict__ ml, ushort* __restrict__ out, int n8)
{
    int i = blockIdx.x * 256 + threadIdx.x;
    if (i >= n8) return;
    const int row = i / 192;               // 192 = kDim/8
    const int within = (i - row * 192) * 8;
    const int h = within >> 7;
    const int b = row / kS;
    const int s = row - b * kS;
    const size_t base = (((size_t)(b * kHeads + h)) * 2) * kS;
    const float m0 = ml[(base + s) * 2],        l0 = ml[(base + s) * 2 + 1];
    const float m1 = ml[(base + kS + s) * 2],   l1 = ml[(base + kS + s) * 2 + 1];
    const float m  = fmaxf(m0, m1);
    const float a0 = l0 * exp2f(m0 - m);
    const float a1 = l1 * exp2f(m1 - m);
    const float inv = 1.f / (a0 + a1);
    const float f0 = a0 * inv, f1 = a1 * inv;

    uint4 ua = ((const uint4*)pA)[i];
    uint4 ub = ((const uint4*)pB)[i];
    const uint32_t* da = (const uint32_t*)&ua;
    const uint32_t* db = (const uint32_t*)&ub;
    uint32_t rv[4];
    #pragma unroll
    for (int j = 0; j < 4; ++j) {
        float o0 = f0 * bf2f(da[j] & 0xffff) + f1 * bf2f(db[j] & 0xffff);
        float o1 = f0 * bf2f(da[j] >> 16)    + f1 * bf2f(db[j] >> 16);
        rv[j] = (uint32_t)f2bf(o0) | ((uint32_t)f2bf(o1) << 16);
    }
    uint4 r; r.x = rv[0]; r.y = rv[1]; r.z = rv[2]; r.w = rv[3];
    ((uint4*)out)[i] = r;
}

// ---------------------------------------------------------------------------
extern "C" void kernel_launch(void* const* d_in, const int* in_sizes, int n_in,
                              void* d_out, int out_size, void* d_ws, size_t ws_size,
                              hipStream_t stream)
{
    (void)in_sizes; (void)n_in; (void)out_size; (void)ws_size;
    const float* x          = (const float*)d_in[0];
    const int*   seq_lens   = (const int*)  d_in[1];
    const int*   grid_sizes = (const int*)  d_in[2];
    const float* freqs      = (const float*)d_in[3];
    const float* Wq = (const float*)d_in[4];
    const float* bq = (const float*)d_in[5];
    const float* Wk = (const float*)d_in[6];
    const float* bk = (const float*)d_in[7];
    const float* Wv = (const float*)d_in[8];
    const float* bv = (const float*)d_in[9];
    const float* Wo = (const float*)d_in[10];
    const float* bo = (const float*)d_in[11];
    const float* gq = (const float*)d_in[12];
    const float* gk = (const float*)d_in[13];
    float* out = (float*)d_out;

    const int M = kB * kS;                       // 6144
    const size_t szX = (size_t)M * kDim;         // 9.44M elems
    const size_t szW = (size_t)kDim * kDim;

    ushort* xb   = (ushort*)d_ws;                // GEMM-A input, then partial A
    ushort* wqb  = xb   + szX;                   // wq|wk|wv contiguous = fused B
    ushort* wkb  = wqb  + szW;
    ushort* wvb  = wkb  + szW;
    ushort* wob  = wvb  + szW;
    ushort* qkvb = wob  + szW;                   // [6144][4608]
    ushort* ab   = qkvb + 3*szX;
    ushort* vtb  = ab   + szX;
    ushort* pBuf = vtb  + szX;                   // partial B (bf16, szX)
    float*  biasqkv = (float*)(pBuf + szX);      // 4608 f32
    float*  ml   = biasqkv + kQKV;               // 2*12*2*3072*2 f32
    float2* cstab = (float2*)(ml + (size_t)2 * kHeads * 2 * kS * 2);  // 4096 float2

    dim3 blk(256);
    cvt_kernel<<<dim3((int)(szX/8/256)), blk, 0, stream>>>(x, xb, (int)(szX/8));
    cvt4_kernel<<<dim3((int)(szW/8/256), 4), blk, 0, stream>>>(
        Wq, Wk, Wv, Wo, wqb, wkb, wvb, wob, (int)(szW/8));
    prep_kernel<<<dim3(18), blk, 0, stream>>>(bq, bk, bv, freqs, biasqkv, cstab);

    // fused QKV projection: N = 4608
    gemm_bf16<ushort><<<dim3(kQKV/128, M/128), blk, 0, stream>>>(
        xb, wqb, biasqkv, qkvb, M, kQKV, kDim);

    rmsrope_kernel<<<dim3(M, 2), dim3(192), 0, stream>>>(qkvb, gq, gk, cstab, grid_sizes);
    vtrans_kernel<<<dim3(kS/64, 2, kB*kHeads), blk, 0, stream>>>(qkvb, vtb);

    // split-K flash attention: 48 x 24 = 1152 blocks (xb reused as partial A)
    attn_kernel<<<dim3(48 * kHeads * kB), blk, 0, stream>>>(
        qkvb, vtb, xb, pBuf, ml, seq_lens);
    combine_kernel<<<dim3((int)(szX/8/256)), blk, 0, stream>>>(
        xb, pBuf, ml, ab, (int)(szX/8));

    gemm_bf16<float><<<dim3(kDim/128, M/128), blk, 0, stream>>>(
        ab, wob, bo, out, M, kDim, kDim);
}

// Round 18
// 404.015 us; speedup vs baseline: 1.0813x; 1.0088x over previous
//
#include <hip/hip_runtime.h>
#include <hip/hip_bf16.h>
#include <stdint.h>

typedef __attribute__((ext_vector_type(8))) short short8;
typedef __attribute__((ext_vector_type(4))) float f32x4;
typedef __attribute__((ext_vector_type(16))) float f32x16;

constexpr int kDim   = 1536;
constexpr int kHeads = 12;
constexpr int kHd    = 128;
constexpr int kS     = 3072;
constexpr int kB     = 2;
constexpr int kQKV   = 3 * kDim;               // 4608 fused row width
constexpr int kTabRows = 64;                   // cos/sin table rows (>= max grid dim)
constexpr float kEps   = 1e-6f;
constexpr float kQMul  = 0.08838834764831845f * 1.44269504089f; // 1/sqrt(128)*log2(e)

__device__ __forceinline__ ushort f2bf(float f) {
    union { float f; uint32_t u; } c; c.f = f;
    uint32_t u = c.u;
    return (ushort)((u + 0x7fffu + ((u >> 16) & 1u)) >> 16);
}
__device__ __forceinline__ float bf2f(uint32_t h) {
    union { uint32_t u; float f; } c; c.u = h << 16;
    return c.f;
}
__device__ __forceinline__ void gload_lds16(const void* g, void* l) {
    __builtin_amdgcn_global_load_lds((const __attribute__((address_space(1))) void*)g,
                                     (__attribute__((address_space(3))) void*)l, 16, 0, 0);
}
__device__ __forceinline__ uint32_t cvtpk_bf16(float lo, float hi) {
    uint32_t r;
    asm("v_cvt_pk_bf16_f32 %0, %1, %2" : "=v"(r) : "v"(lo), "v"(hi));
    return r;
}
// v_permlane32_swap_b32 (vdst-hi <-> vsrc-lo):
//   a'[l<32]=a[l], a'[l>=32]=b[l-32];  b'[l<32]=a[l+32], b'[l>=32]=b[l].
// SAFE ONLY on distinct-valued registers (same-value operands may be
// register-coalesced by the compiler -> vdst==vsrc -> wrong result; this
// was r4/r11's xhalf_* failure mode).
__device__ __forceinline__ void plswap(uint32_t &a, uint32_t &b) {
    asm("v_permlane32_swap_b32 %0, %1" : "+v"(a), "+v"(b));
}

// ---------------------------------------------------------------------------
// fp32 -> bf16 convert, 8 elems/thread
// ---------------------------------------------------------------------------
__global__ __launch_bounds__(256)
void cvt_kernel(const float* __restrict__ in, ushort* __restrict__ out, int n8)
{
    int i = blockIdx.x * 256 + threadIdx.x;
    if (i >= n8) return;
    const float4* p = (const float4*)in + (size_t)i * 2;
    float4 a = p[0], b = p[1];
    uint4 r;
    r.x = (uint32_t)f2bf(a.x) | ((uint32_t)f2bf(a.y) << 16);
    r.y = (uint32_t)f2bf(a.z) | ((uint32_t)f2bf(a.w) << 16);
    r.z = (uint32_t)f2bf(b.x) | ((uint32_t)f2bf(b.y) << 16);
    r.w = (uint32_t)f2bf(b.z) | ((uint32_t)f2bf(b.w) << 16);
    ((uint4*)out)[i] = r;
}

// 4 weight tensors in one dispatch (blockIdx.y selects)
__global__ __launch_bounds__(256)
void cvt4_kernel(const float* __restrict__ s0, const float* __restrict__ s1,
                 const float* __restrict__ s2, const float* __restrict__ s3,
                 ushort* __restrict__ d0, ushort* __restrict__ d1,
                 ushort* __restrict__ d2, ushort* __restrict__ d3, int n8)
{
    int i = blockIdx.x * 256 + threadIdx.x;
    if (i >= n8) return;
    const float* in; ushort* out;
    switch (blockIdx.y) {
        case 0: in = s0; out = d0; break;
        case 1: in = s1; out = d1; break;
        case 2: in = s2; out = d2; break;
        default: in = s3; out = d3; break;
    }
    const float4* p = (const float4*)in + (size_t)i * 2;
    float4 a = p[0], b = p[1];
    uint4 r;
    r.x = (uint32_t)f2bf(a.x) | ((uint32_t)f2bf(a.y) << 16);
    r.y = (uint32_t)f2bf(a.z) | ((uint32_t)f2bf(a.w) << 16);
    r.z = (uint32_t)f2bf(b.x) | ((uint32_t)f2bf(b.y) << 16);
    r.w = (uint32_t)f2bf(b.z) | ((uint32_t)f2bf(b.w) << 16);
    ((uint4*)out)[i] = r;
}

// concat bq|bk|bv -> biasqkv[4608]; also precompute cos/sin table for RoPE:
// cstab[pos*64+c] = {cos, sin}(freqs[pos*64+c]) for pos < 64.
__global__ __launch_bounds__(256)
void prep_kernel(const float* __restrict__ bq, const float* __restrict__ bk,
                 const float* __restrict__ bv, const float* __restrict__ freqs,
                 float* __restrict__ biasqkv, float2* __restrict__ cstab)
{
    int i = blockIdx.x * 256 + threadIdx.x;
    if (i < kQKV) {
        float v = (i < kDim) ? bq[i] : (i < 2*kDim) ? bk[i - kDim] : bv[i - 2*kDim];
        biasqkv[i] = v;
    }
    if (i < kTabRows * 64) {
        float sn, cs;
        sincosf(freqs[i], &sn, &cs);
        cstab[i] = make_float2(cs, sn);
    }
}

// ---------------------------------------------------------------------------
// bf16 MFMA GEMM: C[M][N] = A[M][K] @ B[N][K]^T + bias   (m97-style 128^2, BK=32)
// ---------------------------------------------------------------------------
template<typename OutT>
__global__ __launch_bounds__(256)
void gemm_bf16(const ushort* __restrict__ A, const ushort* __restrict__ B,
               const float* __restrict__ bias, OutT* __restrict__ C,
               int M, int N, int K)
{
    __shared__ ushort As[128 * 32];
    __shared__ ushort Bs[128 * 32];
    const int t    = threadIdx.x;
    const int lane = t & 63;
    const int w    = t >> 6;
    const int wm = (w >> 1) * 64, wn = (w & 1) * 64;
    const int m0 = blockIdx.y * 128, n0 = blockIdx.x * 128;

    const int srow = t >> 2;
    const int skc  = (t & 3) * 8;
    const ushort* Ag = A + (size_t)(m0 + srow) * K + skc;
    const ushort* Bg = B + (size_t)(n0 + srow) * K + skc;
    const size_t half = (size_t)64 * K;

    f32x4 acc[4][4];
    #pragma unroll
    for (int m = 0; m < 4; ++m)
        #pragma unroll
        for (int n = 0; n < 4; ++n)
            #pragma unroll
            for (int i = 0; i < 4; ++i) acc[m][n][i] = 0.f;

    const int kk  = (lane >> 4) * 8;
    const int l15 = lane & 15;

    for (int k0 = 0; k0 < K; k0 += 32) {
        __syncthreads();
        gload_lds16(Ag + k0,        &As[t * 8]);
        gload_lds16(Ag + half + k0, &As[t * 8 + 2048]);
        gload_lds16(Bg + k0,        &Bs[t * 8]);
        gload_lds16(Bg + half + k0, &Bs[t * 8 + 2048]);
        __syncthreads();
        short8 af[4], bf[4];
        #pragma unroll
        for (int m = 0; m < 4; ++m) af[m] = *(const short8*)&As[(wm + m*16 + l15) * 32 + kk];
        #pragma unroll
        for (int n = 0; n < 4; ++n) bf[n] = *(const short8*)&Bs[(wn + n*16 + l15) * 32 + kk];
        #pragma unroll
        for (int m = 0; m < 4; ++m)
            #pragma unroll
            for (int n = 0; n < 4; ++n)
                acc[m][n] = __builtin_amdgcn_mfma_f32_16x16x32_bf16(af[m], bf[n], acc[m][n], 0, 0, 0);
    }

    const int r0 = (lane >> 4) * 4;
    #pragma unroll
    for (int m = 0; m < 4; ++m) {
        #pragma unroll
        for (int r = 0; r < 4; ++r) {
            const size_t row = (size_t)(m0 + wm + m*16 + r0 + r);
            #pragma unroll
            for (int n = 0; n < 4; ++n) {
                const int col = n0 + wn + n*16 + l15;
                float val = acc[m][n][r] + bias[col];
                if constexpr (sizeof(OutT) == 4) C[row * N + col] = val;
                else                             C[row * N + col] = f2bf(val);
            }
        }
    }
}

// ---------------------------------------------------------------------------
// V transpose from fused qkv: vt[b][h][d][s] = qkv[b][s][3072 + h*128 + d]
// LDS layout swizzled: phys_col = d ^ ((s>>4 & 3)<<4).
// ---------------------------------------------------------------------------
__global__ __launch_bounds__(256)
void vtrans_kernel(const ushort* __restrict__ qkv, ushort* __restrict__ vt)
{
    __shared__ ushort Ts[64][72];
    const int t  = threadIdx.x;
    const int s0 = blockIdx.x * 64;
    const int d0 = blockIdx.y * 64;
    const int bh = blockIdx.z;
    const int b = bh / kHeads, h = bh % kHeads;

    const int r = t >> 2, cc = (t & 3) * 16;
    const int wsw = ((r >> 4) & 3) << 4;           // swizzle key of this thread's s-row
    const ushort* src = qkv + ((size_t)(b * kS) + s0 + r) * kQKV + 2*kDim + h * kHd + d0 + cc;
    uint4 a0 = *(const uint4*)src;
    uint4 a1 = *(const uint4*)(src + 8);
    *(uint4*)&Ts[r][(cc ^ wsw)]     = a0;
    *(uint4*)&Ts[r][(cc ^ wsw) + 8] = a1;
    __syncthreads();
    const int rsw = (t & 3) << 4;                  // = ((cc+j)>>4)<<4 for j<16
    ushort tmp[16];
    #pragma unroll
    for (int j = 0; j < 16; ++j) tmp[j] = Ts[cc + j][r ^ rsw];
    ushort* dst = vt + ((size_t)(bh * kHd) + d0 + r) * kS + s0 + cc;
    *(uint4*)dst       = *(uint4*)&tmp[0];
    *(uint4*)(dst + 8) = *(uint4*)&tmp[8];
}

// ---------------------------------------------------------------------------
// RMSNorm + RoPE on q/k sections of fused qkv. 192 thr, 8 elems each.
// cos/sin from precomputed table instead of 4x sincosf per thread.
// ---------------------------------------------------------------------------
__global__ __launch_bounds__(192)
void rmsrope_kernel(ushort* __restrict__ qkv,
                    const float* __restrict__ gq, const float* __restrict__ gk,
                    const float2* __restrict__ cstab, const int* __restrict__ grid_sizes)
{
    __shared__ float red[4];
    const int row   = blockIdx.x;
    const int which = blockIdx.y;
    ushort* ptr = qkv + (size_t)row * kQKV + which * kDim;
    const float* g = which ? gk : gq;
    const float outmul = which ? 1.0f : kQMul;
    const int t = threadIdx.x;

    uint4 raw = ((const uint4*)ptr)[t];
    float v[8];
    v[0] = bf2f(raw.x & 0xffff); v[1] = bf2f(raw.x >> 16);
    v[2] = bf2f(raw.y & 0xffff); v[3] = bf2f(raw.y >> 16);
    v[4] = bf2f(raw.z & 0xffff); v[5] = bf2f(raw.z >> 16);
    v[6] = bf2f(raw.w & 0xffff); v[7] = bf2f(raw.w >> 16);

    float ss = 0.f;
    #pragma unroll
    for (int i = 0; i < 8; ++i) ss += v[i] * v[i];
    #pragma unroll
    for (int off = 32; off >= 1; off >>= 1) ss += __shfl_xor(ss, off);
    if ((t & 63) == 0) red[t >> 6] = ss;
    __syncthreads();
    const float scale = rsqrtf((red[0] + red[1] + red[2]) * (1.f / kDim) + kEps);

    const int b = row / kS, s = row % kS;
    const int gh = grid_sizes[b*3 + 1], gw = grid_sizes[b*3 + 2];
    const int hw  = gh * gw;
    const int fi  = s / hw;
    const int rem = s - fi * hw;
    const int hi  = rem / gw;
    const int wi  = rem - hi * gw;

    const float4 g0 = *(const float4*)(g + t*8);
    const float4 g1 = *(const float4*)(g + t*8 + 4);
    const float gv[8] = {g0.x, g0.y, g0.z, g0.w, g1.x, g1.y, g1.z, g1.w};

    uint32_t out[4];
    #pragma unroll
    for (int jj = 0; jj < 4; ++jj) {
        const int p = t*4 + jj;
        const int c = p & 63;
        const int pos = (c < 22) ? fi : (c < 43 ? hi : wi);
        const float2 cs2 = cstab[pos * 64 + c];
        const float cs = cs2.x, sn = cs2.y;
        const float e0 = v[2*jj]   * scale * gv[2*jj];
        const float e1 = v[2*jj+1] * scale * gv[2*jj+1];
        const float o0 = (e0 * cs - e1 * sn) * outmul;
        const float o1 = (e0 * sn + e1 * cs) * outmul;
        out[jj] = (uint32_t)f2bf(o0) | ((uint32_t)f2bf(o1) << 16);
    }
    uint4 ov; ov.x = out[0]; ov.y = out[1]; ov.z = out[2]; ov.w = out[3];
    ((uint4*)ptr)[t] = ov;
}

// ---------------------------------------------------------------------------
// Flash attention, split-K (2 halves), swapped-QK^T 32x32x16 MFMA.
// r18 delta vs r17: P half-exchange via v_permlane32_swap_b32 on DISTINCT
// registers (u0<->u2 etc.) -- one swap fills both fragment words, replacing
// 4 ds_bpermute + 8 cndmask per half. Verified vs the r5 HW-proven select
// table under vdst-hi<->vsrc-lo semantics:
//   pa0.d[0]=u0' (lo:u0, hi:partner u2)   pa0.d[2]=u2' (lo:partner u0, hi:u2)
// mx/rs reductions keep shfl_xor (same-value permlane operands would be
// register-coalesced -> vdst==vsrc -> r4/r11 failure mode).
// ---------------------------------------------------------------------------
__global__ __launch_bounds__(256, 3)
void attn_kernel(const ushort* __restrict__ qkv, const ushort* __restrict__ vtb,
                 ushort* __restrict__ pA, ushort* __restrict__ pB,
                 float* __restrict__ ml, const int* __restrict__ seq_lens)
{
    __shared__ ushort Ks[64 * 128];
    __shared__ ushort VT[128 * 64];

    // bijective XCD remap: consecutive logical ids (sharing (h,b) K/V) land on
    // the same XCD's L2.  1152 % 8 == 0 -> L = (lin&7)*144 + (lin>>3).
    const int lin = blockIdx.x;
    const int L   = (lin & 7) * 144 + (lin >> 3);
    const int bh   = L / 48;
    const int rem  = L - bh * 48;
    const int half = rem / 24;
    const int qtile= rem - half * 24;
    const int h = bh % kHeads, b = bh / kHeads;
    const int seq = seq_lens[b];
    const int kbeg = half * (kS / 2);

    const int t = threadIdx.x, lane = t & 63, w = t >> 6;
    const int l31 = lane & 31, hi = lane >> 5;
    const int qrow = qtile * 128 + w * 32 + l31;

    const ushort* qbase = qkv + ((size_t)b * kS) * kQKV + h * kHd;
    const ushort* kbase = qkv + ((size_t)b * kS) * kQKV + kDim + h * kHd;
    const ushort* vtbase = vtb + ((size_t)(b * kHeads + h) * kHd) * kS;

    // Q fragments (B-operand): qf[kb][j] = Q[qrow][kb*16 + hi*8 + j]
    short8 qf[8];
    #pragma unroll
    for (int kb = 0; kb < 8; ++kb)
        qf[kb] = *(const short8*)(qbase + (size_t)qrow * kQKV + kb*16 + hi*8);

    f32x16 oacc[4];
    #pragma unroll
    for (int n = 0; n < 4; ++n)
        #pragma unroll
        for (int i = 0; i < 16; ++i) oacc[n][i] = 0.f;

    float m_run = -1e30f, l_run = 0.f;

    const int srow = t >> 4;                      // 0..15
    const int scol = (t & 15) * 8;
    const int kl   = scol ^ (srow << 3);          // 4-bit pre-swizzled K source col
    const int vd0  = t >> 3;                      // 0..31
    const int vscol = ((t & 7) * 8) ^ ((vd0 & 7) << 3);  // pre-swizzled V^T col (3-bit, 64-wide rows)

    for (int kt = 0; kt < kS/2; kt += 64) {
        const int k0 = kbeg + kt;
        __syncthreads();
        #pragma unroll
        for (int c = 0; c < 4; ++c) {
            gload_lds16(kbase + (size_t)(k0 + srow + c*16) * kQKV + kl, &Ks[t*8 + c*2048]);
            gload_lds16(vtbase + (size_t)(vd0 + c*32) * kS + k0 + vscol, &VT[t*8 + c*2048]);
        }
        __syncthreads();

        // ---- two sequential 32-key halves (register-lean) ----
        #pragma unroll
        for (int hb = 0; hb < 2; ++hb) {
            // S^T = K . Q^T for rows hb*32 + l31; reg r -> key (r&3)+8*(r>>2)+4*hi
            f32x16 s;
            #pragma unroll
            for (int i = 0; i < 16; ++i) s[i] = 0.f;
            __builtin_amdgcn_s_setprio(1);
            #pragma unroll
            for (int kb = 0; kb < 8; ++kb) {
                const int col = (kb*16 + hi*8) ^ ((l31 & 15) << 3);
                short8 kf = *(const short8*)&Ks[(hb*32 + l31) * 128 + col];
                s = __builtin_amdgcn_mfma_f32_32x32x16_bf16(kf, qf[kb], s, 0, 0, 0);
            }
            __builtin_amdgcn_s_setprio(0);

            // mask (scores already in log2 domain via kQMul)
            const int kb0 = k0 + hb*32;
            if (kb0 + 32 > seq) {
                #pragma unroll
                for (int r = 0; r < 16; ++r)
                    if (kb0 + (r&3) + 8*(r>>2) + 4*hi >= seq) s[r] = -1e30f;
            }
            // tree max (v_max3-fusable triples, depth 3-4)
            const float a0 = fmaxf(fmaxf(s[0],  s[1]),  s[2]);
            const float a1 = fmaxf(fmaxf(s[3],  s[4]),  s[5]);
            const float a2 = fmaxf(fmaxf(s[6],  s[7]),  s[8]);
            const float a3 = fmaxf(fmaxf(s[9],  s[10]), s[11]);
            const float a4 = fmaxf(fmaxf(s[12], s[13]), s[14]);
            const float b0 = fmaxf(fmaxf(a0, a1), a2);
            const float b1 = fmaxf(fmaxf(a3, a4), s[15]);
            float mx = fmaxf(b0, b1);
            mx = fmaxf(mx, __shfl_xor(mx, 32));

            // defer-max online softmax (T13)
            const bool skip = (mx <= m_run + 11.0f);
            if (!__all(skip)) {
                const float mnew = fmaxf(m_run, mx);
                const float alpha = exp2f(m_run - mnew);
                m_run = mnew;
                l_run *= alpha;
                #pragma unroll
                for (int r = 0; r < 16; ++r) {
                    const float ar = __shfl(alpha, (r&3) + 8*(r>>2) + 4*hi);
                    #pragma unroll
                    for (int n = 0; n < 4; ++n) oacc[n][r] *= ar;
                }
            }

            #pragma unroll
            for (int r = 0; r < 16; ++r) s[r] = exp2f(s[r] - m_run);
            // pairwise add tree (depth 4)
            const float t0 = (s[0] + s[1]) + (s[2]  + s[3]);
            const float t1 = (s[4] + s[5]) + (s[6]  + s[7]);
            const float t2 = (s[8] + s[9]) + (s[10] + s[11]);
            const float t3 = (s[12]+ s[13])+ (s[14] + s[15]);
            float rs = (t0 + t1) + (t2 + t3);
            rs += __shfl_xor(rs, 32);
            l_run += rs;

            // pack P -> bf16 dwords (cvt_pk); half-exchange via permlane32_swap
            // on distinct registers: after swaps, pa0={u0,u1,u2,u3},
            // pa1={u4,u5,u6,u7} directly (no selects).
            uint32_t u[8];
            #pragma unroll
            for (int i = 0; i < 8; ++i) u[i] = cvtpk_bf16(s[2*i], s[2*i+1]);
            plswap(u[0], u[2]); plswap(u[1], u[3]);
            plswap(u[4], u[6]); plswap(u[5], u[7]);
            union PF { uint32_t d[4]; short8 s8; };
            PF pa0, pa1;
            pa0.d[0] = u[0]; pa0.d[1] = u[1]; pa0.d[2] = u[2]; pa0.d[3] = u[3];
            pa1.d[0] = u[4]; pa1.d[1] = u[5]; pa1.d[2] = u[6]; pa1.d[3] = u[7];

            // PV for this half: k-slots hb*2 + {0,1}
            __builtin_amdgcn_s_setprio(1);
            #pragma unroll
            for (int kss = 0; kss < 2; ++kss) {
                const int ks = hb*2 + kss;
                #pragma unroll
                for (int n = 0; n < 4; ++n) {
                    const int d = n*32 + l31;
                    const int colv = (ks*16 + hi*8) ^ ((l31 & 7) << 3);
                    short8 vf = *(const short8*)&VT[d * 64 + colv];
                    oacc[n] = __builtin_amdgcn_mfma_f32_32x32x16_bf16(
                        (kss ? pa1 : pa0).s8, vf, oacc[n], 0, 0, 0);
                }
            }
            __builtin_amdgcn_s_setprio(0);
        }
    }

    // ---- epilogue: partial O' = O~/l (bf16) + per-row (m,l) ----
    ushort* pOut = half ? pB : pA;
    const float linv = 1.f / l_run;
    #pragma unroll
    for (int r = 0; r < 16; ++r) {
        const int qr = (r&3) + 8*(r>>2) + 4*hi;
        const float lr = __shfl(linv, qr);
        const size_t row = (size_t)(b * kS) + qtile * 128 + w * 32 + qr;
        #pragma unroll
        for (int n = 0; n < 4; ++n)
            pOut[row * kDim + h * kHd + n*32 + l31] = f2bf(oacc[n][r] * lr);
    }
    if (lane < 32) {
        const int s = qtile * 128 + w * 32 + l31;
        const size_t idx = ((((size_t)(b * kHeads + h)) * 2 + half) * kS + s) * 2;
        ml[idx]     = m_run;
        ml[idx + 1] = l_run;
    }
}

// ---------------------------------------------------------------------------
// Combine split-K partials: O = (a0*O'0 + a1*O'1)/(a0+a1), a_i = l_i*2^(m_i-m)
// ---------------------------------------------------------------------------
__global__ __launch_bounds__(256)
void combine_kernel(const ushort* __restrict__ pA, const ushort* __restrict__ pB,
                    const float* __restrict__ ml, ushort* __restrict__ out, int n8)
{
    int i = blockIdx.x * 256 + threadIdx.x;
    if (i >= n8) return;
    const int row = i / 192;               // 192 = kDim/8
    const int within = (i - row * 192) * 8;
    const int h = within >> 7;
    const int b = row / kS;
    const int s = row - b * kS;
    const size_t base = (((size_t)(b * kHeads + h)) * 2) * kS;
    const float m0 = ml[(base + s) * 2],        l0 = ml[(base + s) * 2 + 1];
    const float m1 = ml[(base + kS + s) * 2],   l1 = ml[(base + kS + s) * 2 + 1];
    const float m  = fmaxf(m0, m1);
    const float a0 = l0 * exp2f(m0 - m);
    const float a1 = l1 * exp2f(m1 - m);
    const float inv = 1.f / (a0 + a1);
    const float f0 = a0 * inv, f1 = a1 * inv;

    uint4 ua = ((const uint4*)pA)[i];
    uint4 ub = ((const uint4*)pB)[i];
    const uint32_t* da = (const uint32_t*)&ua;
    const uint32_t* db = (const uint32_t*)&ub;
    uint32_t rv[4];
    #pragma unroll
    for (int j = 0; j < 4; ++j) {
        float o0 = f0 * bf2f(da[j] & 0xffff) + f1 * bf2f(db[j] & 0xffff);
        float o1 = f0 * bf2f(da[j] >> 16)    + f1 * bf2f(db[j] >> 16);
        rv[j] = (uint32_t)f2bf(o0) | ((uint32_t)f2bf(o1) << 16);
    }
    uint4 r; r.x = rv[0]; r.y = rv[1]; r.z = rv[2]; r.w = rv[3];
    ((uint4*)out)[i] = r;
}

// ---------------------------------------------------------------------------
extern "C" void kernel_launch(void* const* d_in, const int* in_sizes, int n_in,
                              void* d_out, int out_size, void* d_ws, size_t ws_size,
                              hipStream_t stream)
{
    (void)in_sizes; (void)n_in; (void)out_size; (void)ws_size;
    const float* x          = (const float*)d_in[0];
    const int*   seq_lens   = (const int*)  d_in[1];
    const int*   grid_sizes = (const int*)  d_in[2];
    const float* freqs      = (const float*)d_in[3];
    const float* Wq = (const float*)d_in[4];
    const float* bq = (const float*)d_in[5];
    const float* Wk = (const float*)d_in[6];
    const float* bk = (const float*)d_in[7];
    const float* Wv = (const float*)d_in[8];
    const float* bv = (const float*)d_in[9];
    const float* Wo = (const float*)d_in[10];
    const float* bo = (const float*)d_in[11];
    const float* gq = (const float*)d_in[12];
    const float* gk = (const float*)d_in[13];
    float* out = (float*)d_out;

    const int M = kB * kS;                       // 6144
    const size_t szX = (size_t)M * kDim;         // 9.44M elems
    const size_t szW = (size_t)kDim * kDim;

    ushort* xb   = (ushort*)d_ws;                // GEMM-A input, then partial A
    ushort* wqb  = xb   + szX;                   // wq|wk|wv contiguous = fused B
    ushort* wkb  = wqb  + szW;
    ushort* wvb  = wkb  + szW;
    ushort* wob  = wvb  + szW;
    ushort* qkvb = wob  + szW;                   // [6144][4608]
    ushort* ab   = qkvb + 3*szX;
    ushort* vtb  = ab   + szX;
    ushort* pBuf = vtb  + szX;                   // partial B (bf16, szX)
    float*  biasqkv = (float*)(pBuf + szX);      // 4608 f32
    float*  ml   = biasqkv + kQKV;               // 2*12*2*3072*2 f32
    float2* cstab = (float2*)(ml + (size_t)2 * kHeads * 2 * kS * 2);  // 4096 float2

    dim3 blk(256);
    cvt_kernel<<<dim3((int)(szX/8/256)), blk, 0, stream>>>(x, xb, (int)(szX/8));
    cvt4_kernel<<<dim3((int)(szW/8/256), 4), blk, 0, stream>>>(
        Wq, Wk, Wv, Wo, wqb, wkb, wvb, wob, (int)(szW/8));
    prep_kernel<<<dim3(18), blk, 0, stream>>>(bq, bk, bv, freqs, biasqkv, cstab);

    // fused QKV projection: N = 4608
    gemm_bf16<ushort><<<dim3(kQKV/128, M/128), blk, 0, stream>>>(
        xb, wqb, biasqkv, qkvb, M, kQKV, kDim);

    rmsrope_kernel<<<dim3(M, 2), dim3(192), 0, stream>>>(qkvb, gq, gk, cstab, grid_sizes);
    vtrans_kernel<<<dim3(kS/64, 2, kB*kHeads), blk, 0, stream>>>(qkvb, vtb);

    // split-K flash attention: 48 x 24 = 1152 blocks (xb reused as partial A)
    attn_kernel<<<dim3(48 * kHeads * kB), blk, 0, stream>>>(
        qkvb, vtb, xb, pBuf, ml, seq_lens);
    combine_kernel<<<dim3((int)(szX/8/256)), blk, 0, stream>>>(
        xb, pBuf, ml, ab, (int)(szX/8));

    gemm_bf16<float><<<dim3(kDim/128, M/128), blk, 0, stream>>>(
        ab, wob, bo, out, M, kDim, kDim);
}

// Round 19
// 396.042 us; speedup vs baseline: 1.1030x; 1.0201x over previous
//
#include <hip/hip_runtime.h>
#include <hip/hip_bf16.h>
#include <stdint.h>

typedef __attribute__((ext_vector_type(8))) short short8;
typedef __attribute__((ext_vector_type(4))) float f32x4;
typedef __attribute__((ext_vector_type(16))) float f32x16;

constexpr int kDim   = 1536;
constexpr int kHeads = 12;
constexpr int kHd    = 128;
constexpr int kS     = 3072;
constexpr int kB     = 2;
constexpr int kQKV   = 3 * kDim;               // 4608 fused row width
constexpr int kTabRows = 64;                   // cos/sin table rows (>= max grid dim)
constexpr float kEps   = 1e-6f;
constexpr float kQMul  = 0.08838834764831845f * 1.44269504089f; // 1/sqrt(128)*log2(e)

__device__ __forceinline__ ushort f2bf(float f) {
    union { float f; uint32_t u; } c; c.f = f;
    uint32_t u = c.u;
    return (ushort)((u + 0x7fffu + ((u >> 16) & 1u)) >> 16);
}
__device__ __forceinline__ float bf2f(uint32_t h) {
    union { uint32_t u; float f; } c; c.u = h << 16;
    return c.f;
}
__device__ __forceinline__ void gload_lds16(const void* g, void* l) {
    __builtin_amdgcn_global_load_lds((const __attribute__((address_space(1))) void*)g,
                                     (__attribute__((address_space(3))) void*)l, 16, 0, 0);
}
__device__ __forceinline__ uint32_t cvtpk_bf16(float lo, float hi) {
    uint32_t r;
    asm("v_cvt_pk_bf16_f32 %0, %1, %2" : "=v"(r) : "v"(lo), "v"(hi));
    return r;
}
// v_permlane32_swap_b32 (vdst-hi <-> vsrc-lo), HW-verified r18:
//   a'[l<32]=a[l], a'[l>=32]=b[l-32];  b'[l<32]=a[l+32], b'[l>=32]=b[l].
// SAFE ONLY on distinct registers (same-value C-level copies get
// register-coalesced -> vdst==vsrc -> r4/r11 failure mode).
__device__ __forceinline__ void plswap(uint32_t &a, uint32_t &b) {
    asm("v_permlane32_swap_b32 %0, %1" : "+v"(a), "+v"(b));
}
// cross-half reduce via permlane: partner copy materialized with an
// EARLY-CLOBBER asm mov ("=&v" forces a register distinct from the live
// source) -> swap is on distinct registers by construction.  Operand
// order matches the shfl_xor version exactly -> bit-identical results.
__device__ __forceinline__ float xhalf_max(float x) {
    uint32_t a = __builtin_bit_cast(uint32_t, x), b;
    asm("v_mov_b32 %0, %1" : "=&v"(b) : "v"(a));
    plswap(a, b);
    return fmaxf(__builtin_bit_cast(float, a), __builtin_bit_cast(float, b));
}
__device__ __forceinline__ float xhalf_add(float x) {
    uint32_t a = __builtin_bit_cast(uint32_t, x), b;
    asm("v_mov_b32 %0, %1" : "=&v"(b) : "v"(a));
    plswap(a, b);
    return __builtin_bit_cast(float, a) + __builtin_bit_cast(float, b);
}

// ---------------------------------------------------------------------------
// fp32 -> bf16 convert, 8 elems/thread
// ---------------------------------------------------------------------------
__global__ __launch_bounds__(256)
void cvt_kernel(const float* __restrict__ in, ushort* __restrict__ out, int n8)
{
    int i = blockIdx.x * 256 + threadIdx.x;
    if (i >= n8) return;
    const float4* p = (const float4*)in + (size_t)i * 2;
    float4 a = p[0], b = p[1];
    uint4 r;
    r.x = (uint32_t)f2bf(a.x) | ((uint32_t)f2bf(a.y) << 16);
    r.y = (uint32_t)f2bf(a.z) | ((uint32_t)f2bf(a.w) << 16);
    r.z = (uint32_t)f2bf(b.x) | ((uint32_t)f2bf(b.y) << 16);
    r.w = (uint32_t)f2bf(b.z) | ((uint32_t)f2bf(b.w) << 16);
    ((uint4*)out)[i] = r;
}

// 4 weight tensors in one dispatch (blockIdx.y selects)
__global__ __launch_bounds__(256)
void cvt4_kernel(const float* __restrict__ s0, const float* __restrict__ s1,
                 const float* __restrict__ s2, const float* __restrict__ s3,
                 ushort* __restrict__ d0, ushort* __restrict__ d1,
                 ushort* __restrict__ d2, ushort* __restrict__ d3, int n8)
{
    int i = blockIdx.x * 256 + threadIdx.x;
    if (i >= n8) return;
    const float* in; ushort* out;
    switch (blockIdx.y) {
        case 0: in = s0; out = d0; break;
        case 1: in = s1; out = d1; break;
        case 2: in = s2; out = d2; break;
        default: in = s3; out = d3; break;
    }
    const float4* p = (const float4*)in + (size_t)i * 2;
    float4 a = p[0], b = p[1];
    uint4 r;
    r.x = (uint32_t)f2bf(a.x) | ((uint32_t)f2bf(a.y) << 16);
    r.y = (uint32_t)f2bf(a.z) | ((uint32_t)f2bf(a.w) << 16);
    r.z = (uint32_t)f2bf(b.x) | ((uint32_t)f2bf(b.y) << 16);
    r.w = (uint32_t)f2bf(b.z) | ((uint32_t)f2bf(b.w) << 16);
    ((uint4*)out)[i] = r;
}

// concat bq|bk|bv -> biasqkv[4608]; also precompute cos/sin table for RoPE:
// cstab[pos*64+c] = {cos, sin}(freqs[pos*64+c]) for pos < 64.
__global__ __launch_bounds__(256)
void prep_kernel(const float* __restrict__ bq, const float* __restrict__ bk,
                 const float* __restrict__ bv, const float* __restrict__ freqs,
                 float* __restrict__ biasqkv, float2* __restrict__ cstab)
{
    int i = blockIdx.x * 256 + threadIdx.x;
    if (i < kQKV) {
        float v = (i < kDim) ? bq[i] : (i < 2*kDim) ? bk[i - kDim] : bv[i - 2*kDim];
        biasqkv[i] = v;
    }
    if (i < kTabRows * 64) {
        float sn, cs;
        sincosf(freqs[i], &sn, &cs);
        cstab[i] = make_float2(cs, sn);
    }
}

// ---------------------------------------------------------------------------
// bf16 MFMA GEMM: C[M][N] = A[M][K] @ B[N][K]^T + bias   (m97-style 128^2, BK=32)
// ---------------------------------------------------------------------------
template<typename OutT>
__global__ __launch_bounds__(256)
void gemm_bf16(const ushort* __restrict__ A, const ushort* __restrict__ B,
               const float* __restrict__ bias, OutT* __restrict__ C,
               int M, int N, int K)
{
    __shared__ ushort As[128 * 32];
    __shared__ ushort Bs[128 * 32];
    const int t    = threadIdx.x;
    const int lane = t & 63;
    const int w    = t >> 6;
    const int wm = (w >> 1) * 64, wn = (w & 1) * 64;
    const int m0 = blockIdx.y * 128, n0 = blockIdx.x * 128;

    const int srow = t >> 2;
    const int skc  = (t & 3) * 8;
    const ushort* Ag = A + (size_t)(m0 + srow) * K + skc;
    const ushort* Bg = B + (size_t)(n0 + srow) * K + skc;
    const size_t half = (size_t)64 * K;

    f32x4 acc[4][4];
    #pragma unroll
    for (int m = 0; m < 4; ++m)
        #pragma unroll
        for (int n = 0; n < 4; ++n)
            #pragma unroll
            for (int i = 0; i < 4; ++i) acc[m][n][i] = 0.f;

    const int kk  = (lane >> 4) * 8;
    const int l15 = lane & 15;

    for (int k0 = 0; k0 < K; k0 += 32) {
        __syncthreads();
        gload_lds16(Ag + k0,        &As[t * 8]);
        gload_lds16(Ag + half + k0, &As[t * 8 + 2048]);
        gload_lds16(Bg + k0,        &Bs[t * 8]);
        gload_lds16(Bg + half + k0, &Bs[t * 8 + 2048]);
        __syncthreads();
        short8 af[4], bf[4];
        #pragma unroll
        for (int m = 0; m < 4; ++m) af[m] = *(const short8*)&As[(wm + m*16 + l15) * 32 + kk];
        #pragma unroll
        for (int n = 0; n < 4; ++n) bf[n] = *(const short8*)&Bs[(wn + n*16 + l15) * 32 + kk];
        #pragma unroll
        for (int m = 0; m < 4; ++m)
            #pragma unroll
            for (int n = 0; n < 4; ++n)
                acc[m][n] = __builtin_amdgcn_mfma_f32_16x16x32_bf16(af[m], bf[n], acc[m][n], 0, 0, 0);
    }

    const int r0 = (lane >> 4) * 4;
    #pragma unroll
    for (int m = 0; m < 4; ++m) {
        #pragma unroll
        for (int r = 0; r < 4; ++r) {
            const size_t row = (size_t)(m0 + wm + m*16 + r0 + r);
            #pragma unroll
            for (int n = 0; n < 4; ++n) {
                const int col = n0 + wn + n*16 + l15;
                float val = acc[m][n][r] + bias[col];
                if constexpr (sizeof(OutT) == 4) C[row * N + col] = val;
                else                             C[row * N + col] = f2bf(val);
            }
        }
    }
}

// ---------------------------------------------------------------------------
// V transpose from fused qkv: vt[b][h][d][s] = qkv[b][s][3072 + h*128 + d]
// LDS layout swizzled: phys_col = d ^ ((s>>4 & 3)<<4).
// ---------------------------------------------------------------------------
__global__ __launch_bounds__(256)
void vtrans_kernel(const ushort* __restrict__ qkv, ushort* __restrict__ vt)
{
    __shared__ ushort Ts[64][72];
    const int t  = threadIdx.x;
    const int s0 = blockIdx.x * 64;
    const int d0 = blockIdx.y * 64;
    const int bh = blockIdx.z;
    const int b = bh / kHeads, h = bh % kHeads;

    const int r = t >> 2, cc = (t & 3) * 16;
    const int wsw = ((r >> 4) & 3) << 4;           // swizzle key of this thread's s-row
    const ushort* src = qkv + ((size_t)(b * kS) + s0 + r) * kQKV + 2*kDim + h * kHd + d0 + cc;
    uint4 a0 = *(const uint4*)src;
    uint4 a1 = *(const uint4*)(src + 8);
    *(uint4*)&Ts[r][(cc ^ wsw)]     = a0;
    *(uint4*)&Ts[r][(cc ^ wsw) + 8] = a1;
    __syncthreads();
    const int rsw = (t & 3) << 4;                  // = ((cc+j)>>4)<<4 for j<16
    ushort tmp[16];
    #pragma unroll
    for (int j = 0; j < 16; ++j) tmp[j] = Ts[cc + j][r ^ rsw];
    ushort* dst = vt + ((size_t)(bh * kHd) + d0 + r) * kS + s0 + cc;
    *(uint4*)dst       = *(uint4*)&tmp[0];
    *(uint4*)(dst + 8) = *(uint4*)&tmp[8];
}

// ---------------------------------------------------------------------------
// RMSNorm + RoPE on q/k sections of fused qkv. 192 thr, 8 elems each.
// cos/sin from precomputed table instead of 4x sincosf per thread.
// ---------------------------------------------------------------------------
__global__ __launch_bounds__(192)
void rmsrope_kernel(ushort* __restrict__ qkv,
                    const float* __restrict__ gq, const float* __restrict__ gk,
                    const float2* __restrict__ cstab, const int* __restrict__ grid_sizes)
{
    __shared__ float red[4];
    const int row   = blockIdx.x;
    const int which = blockIdx.y;
    ushort* ptr = qkv + (size_t)row * kQKV + which * kDim;
    const float* g = which ? gk : gq;
    const float outmul = which ? 1.0f : kQMul;
    const int t = threadIdx.x;

    uint4 raw = ((const uint4*)ptr)[t];
    float v[8];
    v[0] = bf2f(raw.x & 0xffff); v[1] = bf2f(raw.x >> 16);
    v[2] = bf2f(raw.y & 0xffff); v[3] = bf2f(raw.y >> 16);
    v[4] = bf2f(raw.z & 0xffff); v[5] = bf2f(raw.z >> 16);
    v[6] = bf2f(raw.w & 0xffff); v[7] = bf2f(raw.w >> 16);

    float ss = 0.f;
    #pragma unroll
    for (int i = 0; i < 8; ++i) ss += v[i] * v[i];
    #pragma unroll
    for (int off = 32; off >= 1; off >>= 1) ss += __shfl_xor(ss, off);
    if ((t & 63) == 0) red[t >> 6] = ss;
    __syncthreads();
    const float scale = rsqrtf((red[0] + red[1] + red[2]) * (1.f / kDim) + kEps);

    const int b = row / kS, s = row % kS;
    const int gh = grid_sizes[b*3 + 1], gw = grid_sizes[b*3 + 2];
    const int hw  = gh * gw;
    const int fi  = s / hw;
    const int rem = s - fi * hw;
    const int hi  = rem / gw;
    const int wi  = rem - hi * gw;

    const float4 g0 = *(const float4*)(g + t*8);
    const float4 g1 = *(const float4*)(g + t*8 + 4);
    const float gv[8] = {g0.x, g0.y, g0.z, g0.w, g1.x, g1.y, g1.z, g1.w};

    uint32_t out[4];
    #pragma unroll
    for (int jj = 0; jj < 4; ++jj) {
        const int p = t*4 + jj;
        const int c = p & 63;
        const int pos = (c < 22) ? fi : (c < 43 ? hi : wi);
        const float2 cs2 = cstab[pos * 64 + c];
        const float cs = cs2.x, sn = cs2.y;
        const float e0 = v[2*jj]   * scale * gv[2*jj];
        const float e1 = v[2*jj+1] * scale * gv[2*jj+1];
        const float o0 = (e0 * cs - e1 * sn) * outmul;
        const float o1 = (e0 * sn + e1 * cs) * outmul;
        out[jj] = (uint32_t)f2bf(o0) | ((uint32_t)f2bf(o1) << 16);
    }
    uint4 ov; ov.x = out[0]; ov.y = out[1]; ov.z = out[2]; ov.w = out[3];
    ((uint4*)ptr)[t] = ov;
}

// ---------------------------------------------------------------------------
// Flash attention, split-K (2 halves), swapped-QK^T 32x32x16 MFMA.
// r19 delta vs r18: mx/rs cross-half reductions via permlane32_swap with a
// forced-distinct partner copy (asm v_mov "=&v") -- removes the last
// ds_bpermutes from the softmax critical path. Bit-identical operand order.
// ---------------------------------------------------------------------------
__global__ __launch_bounds__(256, 3)
void attn_kernel(const ushort* __restrict__ qkv, const ushort* __restrict__ vtb,
                 ushort* __restrict__ pA, ushort* __restrict__ pB,
                 float* __restrict__ ml, const int* __restrict__ seq_lens)
{
    __shared__ ushort Ks[64 * 128];
    __shared__ ushort VT[128 * 64];

    // bijective XCD remap: consecutive logical ids (sharing (h,b) K/V) land on
    // the same XCD's L2.  1152 % 8 == 0 -> L = (lin&7)*144 + (lin>>3).
    const int lin = blockIdx.x;
    const int L   = (lin & 7) * 144 + (lin >> 3);
    const int bh   = L / 48;
    const int rem  = L - bh * 48;
    const int half = rem / 24;
    const int qtile= rem - half * 24;
    const int h = bh % kHeads, b = bh / kHeads;
    const int seq = seq_lens[b];
    const int kbeg = half * (kS / 2);

    const int t = threadIdx.x, lane = t & 63, w = t >> 6;
    const int l31 = lane & 31, hi = lane >> 5;
    const int qrow = qtile * 128 + w * 32 + l31;

    const ushort* qbase = qkv + ((size_t)b * kS) * kQKV + h * kHd;
    const ushort* kbase = qkv + ((size_t)b * kS) * kQKV + kDim + h * kHd;
    const ushort* vtbase = vtb + ((size_t)(b * kHeads + h) * kHd) * kS;

    // Q fragments (B-operand): qf[kb][j] = Q[qrow][kb*16 + hi*8 + j]
    short8 qf[8];
    #pragma unroll
    for (int kb = 0; kb < 8; ++kb)
        qf[kb] = *(const short8*)(qbase + (size_t)qrow * kQKV + kb*16 + hi*8);

    f32x16 oacc[4];
    #pragma unroll
    for (int n = 0; n < 4; ++n)
        #pragma unroll
        for (int i = 0; i < 16; ++i) oacc[n][i] = 0.f;

    float m_run = -1e30f, l_run = 0.f;

    const int srow = t >> 4;                      // 0..15
    const int scol = (t & 15) * 8;
    const int kl   = scol ^ (srow << 3);          // 4-bit pre-swizzled K source col
    const int vd0  = t >> 3;                      // 0..31
    const int vscol = ((t & 7) * 8) ^ ((vd0 & 7) << 3);  // pre-swizzled V^T col (3-bit, 64-wide rows)

    for (int kt = 0; kt < kS/2; kt += 64) {
        const int k0 = kbeg + kt;
        __syncthreads();
        #pragma unroll
        for (int c = 0; c < 4; ++c) {
            gload_lds16(kbase + (size_t)(k0 + srow + c*16) * kQKV + kl, &Ks[t*8 + c*2048]);
            gload_lds16(vtbase + (size_t)(vd0 + c*32) * kS + k0 + vscol, &VT[t*8 + c*2048]);
        }
        __syncthreads();

        // ---- two sequential 32-key halves (register-lean) ----
        #pragma unroll
        for (int hb = 0; hb < 2; ++hb) {
            // S^T = K . Q^T for rows hb*32 + l31; reg r -> key (r&3)+8*(r>>2)+4*hi
            f32x16 s;
            #pragma unroll
            for (int i = 0; i < 16; ++i) s[i] = 0.f;
            __builtin_amdgcn_s_setprio(1);
            #pragma unroll
            for (int kb = 0; kb < 8; ++kb) {
                const int col = (kb*16 + hi*8) ^ ((l31 & 15) << 3);
                short8 kf = *(const short8*)&Ks[(hb*32 + l31) * 128 + col];
                s = __builtin_amdgcn_mfma_f32_32x32x16_bf16(kf, qf[kb], s, 0, 0, 0);
            }
            __builtin_amdgcn_s_setprio(0);

            // mask (scores already in log2 domain via kQMul)
            const int kb0 = k0 + hb*32;
            if (kb0 + 32 > seq) {
                #pragma unroll
                for (int r = 0; r < 16; ++r)
                    if (kb0 + (r&3) + 8*(r>>2) + 4*hi >= seq) s[r] = -1e30f;
            }
            // tree max (v_max3-fusable triples, depth 3-4)
            const float a0 = fmaxf(fmaxf(s[0],  s[1]),  s[2]);
            const float a1 = fmaxf(fmaxf(s[3],  s[4]),  s[5]);
            const float a2 = fmaxf(fmaxf(s[6],  s[7]),  s[8]);
            const float a3 = fmaxf(fmaxf(s[9],  s[10]), s[11]);
            const float a4 = fmaxf(fmaxf(s[12], s[13]), s[14]);
            const float b0 = fmaxf(fmaxf(a0, a1), a2);
            const float b1 = fmaxf(fmaxf(a3, a4), s[15]);
            float mx = xhalf_max(fmaxf(b0, b1));

            // defer-max online softmax (T13)
            const bool skip = (mx <= m_run + 11.0f);
            if (!__all(skip)) {
                const float mnew = fmaxf(m_run, mx);
                const float alpha = exp2f(m_run - mnew);
                m_run = mnew;
                l_run *= alpha;
                #pragma unroll
                for (int r = 0; r < 16; ++r) {
                    const float ar = __shfl(alpha, (r&3) + 8*(r>>2) + 4*hi);
                    #pragma unroll
                    for (int n = 0; n < 4; ++n) oacc[n][r] *= ar;
                }
            }

            #pragma unroll
            for (int r = 0; r < 16; ++r) s[r] = exp2f(s[r] - m_run);
            // pairwise add tree (depth 4)
            const float t0 = (s[0] + s[1]) + (s[2]  + s[3]);
            const float t1 = (s[4] + s[5]) + (s[6]  + s[7]);
            const float t2 = (s[8] + s[9]) + (s[10] + s[11]);
            const float t3 = (s[12]+ s[13])+ (s[14] + s[15]);
            l_run += xhalf_add((t0 + t1) + (t2 + t3));

            // pack P -> bf16 dwords (cvt_pk); half-exchange via permlane32_swap
            // on distinct registers: after swaps, pa0={u0,u1,u2,u3},
            // pa1={u4,u5,u6,u7} directly (no selects).
            uint32_t u[8];
            #pragma unroll
            for (int i = 0; i < 8; ++i) u[i] = cvtpk_bf16(s[2*i], s[2*i+1]);
            plswap(u[0], u[2]); plswap(u[1], u[3]);
            plswap(u[4], u[6]); plswap(u[5], u[7]);
            union PF { uint32_t d[4]; short8 s8; };
            PF pa0, pa1;
            pa0.d[0] = u[0]; pa0.d[1] = u[1]; pa0.d[2] = u[2]; pa0.d[3] = u[3];
            pa1.d[0] = u[4]; pa1.d[1] = u[5]; pa1.d[2] = u[6]; pa1.d[3] = u[7];

            // PV for this half: k-slots hb*2 + {0,1}
            __builtin_amdgcn_s_setprio(1);
            #pragma unroll
            for (int kss = 0; kss < 2; ++kss) {
                const int ks = hb*2 + kss;
                #pragma unroll
                for (int n = 0; n < 4; ++n) {
                    const int d = n*32 + l31;
                    const int colv = (ks*16 + hi*8) ^ ((l31 & 7) << 3);
                    short8 vf = *(const short8*)&VT[d * 64 + colv];
                    oacc[n] = __builtin_amdgcn_mfma_f32_32x32x16_bf16(
                        (kss ? pa1 : pa0).s8, vf, oacc[n], 0, 0, 0);
                }
            }
            __builtin_amdgcn_s_setprio(0);
        }
    }

    // ---- epilogue: partial O' = O~/l (bf16) + per-row (m,l) ----
    ushort* pOut = half ? pB : pA;
    const float linv = 1.f / l_run;
    #pragma unroll
    for (int r = 0; r < 16; ++r) {
        const int qr = (r&3) + 8*(r>>2) + 4*hi;
        const float lr = __shfl(linv, qr);
        const size_t row = (size_t)(b * kS) + qtile * 128 + w * 32 + qr;
        #pragma unroll
        for (int n = 0; n < 4; ++n)
            pOut[row * kDim + h * kHd + n*32 + l31] = f2bf(oacc[n][r] * lr);
    }
    if (lane < 32) {
        const int s = qtile * 128 + w * 32 + l31;
        const size_t idx = ((((size_t)(b * kHeads + h)) * 2 + half) * kS + s) * 2;
        ml[idx]     = m_run;
        ml[idx + 1] = l_run;
    }
}

// ---------------------------------------------------------------------------
// Combine split-K partials: O = (a0*O'0 + a1*O'1)/(a0+a1), a_i = l_i*2^(m_i-m)
// ---------------------------------------------------------------------------
__global__ __launch_bounds__(256)
void combine_kernel(const ushort* __restrict__ pA, const ushort* __restrict__ pB,
                    const float* __restrict__ ml, ushort* __restrict__ out, int n8)
{
    int i = blockIdx.x * 256 + threadIdx.x;
    if (i >= n8) return;
    const int row = i / 192;               // 192 = kDim/8
    const int within = (i - row * 192) * 8;
    const int h = within >> 7;
    const int b = row / kS;
    const int s = row - b * kS;
    const size_t base = (((size_t)(b * kHeads + h)) * 2) * kS;
    const float m0 = ml[(base + s) * 2],        l0 = ml[(base + s) * 2 + 1];
    const float m1 = ml[(base + kS + s) * 2],   l1 = ml[(base + kS + s) * 2 + 1];
    const float m  = fmaxf(m0, m1);
    const float a0 = l0 * exp2f(m0 - m);
    const float a1 = l1 * exp2f(m1 - m);
    const float inv = 1.f / (a0 + a1);
    const float f0 = a0 * inv, f1 = a1 * inv;

    uint4 ua = ((const uint4*)pA)[i];
    uint4 ub = ((const uint4*)pB)[i];
    const uint32_t* da = (const uint32_t*)&ua;
    const uint32_t* db = (const uint32_t*)&ub;
    uint32_t rv[4];
    #pragma unroll
    for (int j = 0; j < 4; ++j) {
        float o0 = f0 * bf2f(da[j] & 0xffff) + f1 * bf2f(db[j] & 0xffff);
        float o1 = f0 * bf2f(da[j] >> 16)    + f1 * bf2f(db[j] >> 16);
        rv[j] = (uint32_t)f2bf(o0) | ((uint32_t)f2bf(o1) << 16);
    }
    uint4 r; r.x = rv[0]; r.y = rv[1]; r.z = rv[2]; r.w = rv[3];
    ((uint4*)out)[i] = r;
}

// ---------------------------------------------------------------------------
extern "C" void kernel_launch(void* const* d_in, const int* in_sizes, int n_in,
                              void* d_out, int out_size, void* d_ws, size_t ws_size,
                              hipStream_t stream)
{
    (void)in_sizes; (void)n_in; (void)out_size; (void)ws_size;
    const float* x          = (const float*)d_in[0];
    const int*   seq_lens   = (const int*)  d_in[1];
    const int*   grid_sizes = (const int*)  d_in[2];
    const float* freqs      = (const float*)d_in[3];
    const float* Wq = (const float*)d_in[4];
    const float* bq = (const float*)d_in[5];
    const float* Wk = (const float*)d_in[6];
    const float* bk = (const float*)d_in[7];
    const float* Wv = (const float*)d_in[8];
    const float* bv = (const float*)d_in[9];
    const float* Wo = (const float*)d_in[10];
    const float* bo = (const float*)d_in[11];
    const float* gq = (const float*)d_in[12];
    const float* gk = (const float*)d_in[13];
    float* out = (float*)d_out;

    const int M = kB * kS;                       // 6144
    const size_t szX = (size_t)M * kDim;         // 9.44M elems
    const size_t szW = (size_t)kDim * kDim;

    ushort* xb   = (ushort*)d_ws;                // GEMM-A input, then partial A
    ushort* wqb  = xb   + szX;                   // wq|wk|wv contiguous = fused B
    ushort* wkb  = wqb  + szW;
    ushort* wvb  = wkb  + szW;
    ushort* wob  = wvb  + szW;
    ushort* qkvb = wob  + szW;                   // [6144][4608]
    ushort* ab   = qkvb + 3*szX;
    ushort* vtb  = ab   + szX;
    ushort* pBuf = vtb  + szX;                   // partial B (bf16, szX)
    float*  biasqkv = (float*)(pBuf + szX);      // 4608 f32
    float*  ml   = biasqkv + kQKV;               // 2*12*2*3072*2 f32
    float2* cstab = (float2*)(ml + (size_t)2 * kHeads * 2 * kS * 2);  // 4096 float2

    dim3 blk(256);
    cvt_kernel<<<dim3((int)(szX/8/256)), blk, 0, stream>>>(x, xb, (int)(szX/8));
    cvt4_kernel<<<dim3((int)(szW/8/256), 4), blk, 0, stream>>>(
        Wq, Wk, Wv, Wo, wqb, wkb, wvb, wob, (int)(szW/8));
    prep_kernel<<<dim3(18), blk, 0, stream>>>(bq, bk, bv, freqs, biasqkv, cstab);

    // fused QKV projection: N = 4608
    gemm_bf16<ushort><<<dim3(kQKV/128, M/128), blk, 0, stream>>>(
        xb, wqb, biasqkv, qkvb, M, kQKV, kDim);

    rmsrope_kernel<<<dim3(M, 2), dim3(192), 0, stream>>>(qkvb, gq, gk, cstab, grid_sizes);
    vtrans_kernel<<<dim3(kS/64, 2, kB*kHeads), blk, 0, stream>>>(qkvb, vtb);

    // split-K flash attention: 48 x 24 = 1152 blocks (xb reused as partial A)
    attn_kernel<<<dim3(48 * kHeads * kB), blk, 0, stream>>>(
        qkvb, vtb, xb, pBuf, ml, seq_lens);
    combine_kernel<<<dim3((int)(szX/8/256)), blk, 0, stream>>>(
        xb, pBuf, ml, ab, (int)(szX/8));

    gemm_bf16<float><<<dim3(kDim/128, M/128), blk, 0, stream>>>(
        ab, wob, bo, out, M, kDim, kDim);
}